// Round 14
// baseline (209.005 us; speedup 1.0000x reference)
//
#include <hip/hip_runtime.h>

typedef short short8 __attribute__((ext_vector_type(8)));
typedef float f32x4 __attribute__((ext_vector_type(4)));
typedef unsigned short u16;
typedef unsigned int u32;

__device__ __forceinline__ u16 f2bf(float f) {
  union { float f; u32 u; } x; x.f = f;
  u32 u = x.u;
  u32 r = (u + 0x7FFFu + ((u >> 16) & 1u)) >> 16;
  return (u16)r;
}

__device__ __forceinline__ u32 cvtpk(float lo, float hi) {
  u32 r;
  asm("v_cvt_pk_bf16_f32 %0, %1, %2" : "=v"(r) : "v"(lo), "v"(hi));
  return r;
}

// ---- WB bf16-region offsets (u16 units) — decoder + bond weights only ----
#define OW2T   0        // bond W2^T      [256][256]
#define OW3TX  65536    // bond W3 padT   [16][256]
#define ODW1A  69632    // dW1[0:64]^T    [256][64]
#define ODW2   86016    // dW2^T          [256][256]
#define ODW3   151552   // dW3^T          [64][256]
#define OBPA   167936   // bpW1[0:64]^T   [256][64]  x0.125
#define OBPB   184320   // bpW1[64:128]^T [256][64]  x0.125
#define OREW1  200704   // reW1^T         [256][64]
#define OREW2  217088   // reW2 padT      [16][256]

// ====== k_prep (PROVEN r12): cond c2+ctf+ctv (blocks 0..63) + transposes (64..117) ====
__global__ void __launch_bounds__(512) k_prep(
    const float* __restrict__ cnd, const float* __restrict__ ceW1,
    const float* __restrict__ ceb1, const float* __restrict__ ceW2,
    const float* __restrict__ ceb2, const float* __restrict__ bpW1,
    const float* __restrict__ bpb1, const float* __restrict__ dW1,
    const float* __restrict__ db1, const float* __restrict__ dW2,
    const float* __restrict__ dW3, const float* __restrict__ bpW2,
    const float* __restrict__ bpW3, const float* __restrict__ reW1,
    const float* __restrict__ reW2, float* __restrict__ ctf,
    float* __restrict__ ctv, u16* __restrict__ WB) {
  __shared__ float h[256], c2s[256], prf[256], prv[256];
  __shared__ float T[64][65];
  int bid = blockIdx.x, t = threadIdx.x;
  if (bid < 64) {
    int b = bid;
    if (t < 256) {
      float c0 = cnd[b * 2 + 0], c1 = cnd[b * 2 + 1];
      h[t] = fmaxf(c0 * ceW1[t] + c1 * ceW1[256 + t] + ceb1[t], 0.f);
    }
    __syncthreads();
    int col = t & 255, g = t >> 8;
    {
      float acc = 0.f;
      #pragma unroll 8
      for (int k = g * 128; k < g * 128 + 128; k++) acc += h[k] * ceW2[k * 256 + col];
      if (g) prf[col] = acc;
      __syncthreads();
      if (!g) c2s[col] = acc + prf[col] + ceb2[col];
    }
    __syncthreads();
    float af = 0.f, av = 0.f;
    #pragma unroll 4
    for (int k = g * 128; k < g * 128 + 128; k++) {
      float cv = c2s[k];
      af += cv * bpW1[(128 + k) * 256 + col];
      av += cv * dW1[(64 + k) * 256 + col];
    }
    if (g) { prf[col] = af; prv[col] = av; }
    __syncthreads();
    if (!g) {
      ctf[b * 256 + col] = af + prf[col] + bpb1[col];
      ctv[b * 256 + col] = av + prv[col] + db1[col];
    }
    return;
  }
  int mb = bid - 64;  // 0..53
  if (mb >= 52) {
    if (t < 256) {
      const float* s = (mb == 52) ? reW2 : bpW3;
      u16* d = WB + ((mb == 52) ? OREW2 : OW3TX);
      #pragma unroll
      for (int c = 0; c < 16; c++) {
        float v = (c < 4) ? s[t * 4 + c] : 0.f;
        d[c * 256 + t] = f2bf(v);
      }
    }
    return;
  }
  const float* src; u16* dst; int sld, dld, tr, tc; float sc = 1.f;
  if (mb < 4)       { src = dW1;           dst = WB + ODW1A; sld = 256; dld = 64;  tr = 0;            tc = mb;          }
  else if (mb < 20) { int e = mb - 4;  src = dW2;  dst = WB + ODW2; sld = 256; dld = 256; tr = e >> 2; tc = e & 3; }
  else if (mb < 24) { int e = mb - 20; src = dW3;  dst = WB + ODW3; sld = 64;  dld = 256; tr = e;      tc = 0;     }
  else if (mb < 28) { int e = mb - 24; src = bpW1; dst = WB + OBPA; sld = 256; dld = 64;  tr = 0;      tc = e; sc = 0.125f; }
  else if (mb < 32) { int e = mb - 28; src = bpW1 + 64 * 256; dst = WB + OBPB; sld = 256; dld = 64; tr = 0; tc = e; sc = 0.125f; }
  else if (mb < 36) { int e = mb - 32; src = reW1; dst = WB + OREW1; sld = 256; dld = 64; tr = 0;      tc = e;     }
  else              { int e = mb - 36; src = bpW2; dst = WB + OW2T; sld = 256; dld = 256; tr = e >> 2; tc = e & 3; }
  int rl = t >> 6, cl = t & 63;
  #pragma unroll
  for (int it = 0; it < 8; it++) {
    int r = it * 8 + rl;
    T[r][cl] = src[(tr * 64 + r) * sld + tc * 64 + cl] * sc;
  }
  __syncthreads();
  #pragma unroll
  for (int it = 0; it < 8; it++) {
    int c2_ = it * 8 + rl;
    dst[(tc * 64 + c2_) * dld + tr * 64 + cl] = f2bf(T[cl][c2_]);
  }
}

// ====== k_gc1 v2 (PROVEN r11): fused ah1; float4 LDS reads ============================
__global__ void __launch_bounds__(512) k_gc1(
    const float* __restrict__ adj, const float* __restrict__ x,
    const float* __restrict__ W1, const float* __restrict__ b1,
    float* __restrict__ out) {
  __shared__ float adj_s[64 * 64];
  __shared__ float x_s[64 * 64];
  __shared__ float ax_s[64 * 64];
  __shared__ float h_s[64 * 64];
  int cg = blockIdx.x, b = blockIdx.y, t = threadIdx.x;
  const float* A = adj + b * 4096;
  const float* X = x + b * 4096;
  for (int e = t; e < 4096; e += 512) { adj_s[e] = A[e]; x_s[e] = X[e]; }
  __syncthreads();
  int c = t & 63, rg = t >> 6;
  {
    float acc[8];
    #pragma unroll
    for (int m = 0; m < 8; m++) acc[m] = 0.f;
    #pragma unroll 4
    for (int j4 = 0; j4 < 16; j4++) {
      float xv0 = x_s[(j4 * 4 + 0) * 64 + c];
      float xv1 = x_s[(j4 * 4 + 1) * 64 + c];
      float xv2 = x_s[(j4 * 4 + 2) * 64 + c];
      float xv3 = x_s[(j4 * 4 + 3) * 64 + c];
      #pragma unroll
      for (int m = 0; m < 8; m++) {
        float4 a4 = *(const float4*)&adj_s[(m * 8 + rg) * 64 + j4 * 4];
        acc[m] += a4.x * xv0 + a4.y * xv1 + a4.z * xv2 + a4.w * xv3;
      }
    }
    #pragma unroll
    for (int m = 0; m < 8; m++) ax_s[(m * 8 + rg) * 64 + c] = acc[m];
  }
  __syncthreads();
  {
    float bv = b1[cg * 64 + c];
    float acc[8];
    #pragma unroll
    for (int m = 0; m < 8; m++) acc[m] = bv;
    #pragma unroll 4
    for (int k4 = 0; k4 < 16; k4++) {
      float w0 = W1[(k4 * 4 + 0) * 256 + cg * 64 + c];
      float w1 = W1[(k4 * 4 + 1) * 256 + cg * 64 + c];
      float w2 = W1[(k4 * 4 + 2) * 256 + cg * 64 + c];
      float w3 = W1[(k4 * 4 + 3) * 256 + cg * 64 + c];
      #pragma unroll
      for (int m = 0; m < 8; m++) {
        float4 a4 = *(const float4*)&ax_s[(m * 8 + rg) * 64 + k4 * 4];
        acc[m] += a4.x * w0 + a4.y * w1 + a4.z * w2 + a4.w * w3;
      }
    }
    #pragma unroll
    for (int m = 0; m < 8; m++) h_s[(m * 8 + rg) * 64 + c] = fmaxf(acc[m], 0.f);
  }
  __syncthreads();
  {
    float acc[8];
    #pragma unroll
    for (int m = 0; m < 8; m++) acc[m] = 0.f;
    #pragma unroll 4
    for (int j4 = 0; j4 < 16; j4++) {
      float h0 = h_s[(j4 * 4 + 0) * 64 + c];
      float h1 = h_s[(j4 * 4 + 1) * 64 + c];
      float h2 = h_s[(j4 * 4 + 2) * 64 + c];
      float h3 = h_s[(j4 * 4 + 3) * 64 + c];
      #pragma unroll
      for (int m = 0; m < 8; m++) {
        float4 a4 = *(const float4*)&adj_s[(m * 8 + rg) * 64 + j4 * 4];
        acc[m] += a4.x * h0 + a4.y * h1 + a4.z * h2 + a4.w * h3;
      }
    }
    float* O = out + b * 64 * 256 + cg * 64;
    #pragma unroll
    for (int m = 0; m < 8; m++) O[(m * 8 + rg) * 256 + c] = acc[m];
  }
}

// ====== k_linadj v2 (PROVEN r11): fused ah2; float4 LDS reads =========================
__global__ void __launch_bounds__(512) k_linadj(
    const float* __restrict__ adj, const float* __restrict__ in,
    const float* __restrict__ W, const float* __restrict__ bias,
    float* __restrict__ out) {
  __shared__ float adj_s[64 * 64];
  __shared__ float in_s[32 * 256];
  __shared__ float h_s[64 * 64];
  int cg = blockIdx.x, b = blockIdx.y, t = threadIdx.x;
  const float* A = adj + b * 4096;
  for (int e = t; e < 4096; e += 512) adj_s[e] = A[e];
  int c = t & 63, rg = t >> 6;
  float bv = bias[cg * 64 + c];
  #pragma unroll
  for (int half = 0; half < 2; half++) {
    if (half) __syncthreads();
    const float* I = in + (b * 64 + half * 32) * 256;
    for (int e = t; e < 32 * 256; e += 512) in_s[e] = I[e];
    __syncthreads();
    float acc[4];
    #pragma unroll
    for (int m = 0; m < 4; m++) acc[m] = bv;
    #pragma unroll 4
    for (int k4 = 0; k4 < 64; k4++) {
      float w0 = W[(k4 * 4 + 0) * 256 + cg * 64 + c];
      float w1 = W[(k4 * 4 + 1) * 256 + cg * 64 + c];
      float w2 = W[(k4 * 4 + 2) * 256 + cg * 64 + c];
      float w3 = W[(k4 * 4 + 3) * 256 + cg * 64 + c];
      #pragma unroll
      for (int m = 0; m < 4; m++) {
        float4 i4 = *(const float4*)&in_s[(m * 8 + rg) * 256 + k4 * 4];
        acc[m] += i4.x * w0 + i4.y * w1 + i4.z * w2 + i4.w * w3;
      }
    }
    #pragma unroll
    for (int m = 0; m < 4; m++)
      h_s[(half * 32 + m * 8 + rg) * 64 + c] = fmaxf(acc[m], 0.f);
  }
  __syncthreads();
  {
    float acc[8];
    #pragma unroll
    for (int m = 0; m < 8; m++) acc[m] = 0.f;
    #pragma unroll 4
    for (int j4 = 0; j4 < 16; j4++) {
      float h0 = h_s[(j4 * 4 + 0) * 64 + c];
      float h1 = h_s[(j4 * 4 + 1) * 64 + c];
      float h2 = h_s[(j4 * 4 + 2) * 64 + c];
      float h3 = h_s[(j4 * 4 + 3) * 64 + c];
      #pragma unroll
      for (int m = 0; m < 8; m++) {
        float4 a4 = *(const float4*)&adj_s[(m * 8 + rg) * 64 + j4 * 4];
        acc[m] += a4.x * h0 + a4.y * h1 + a4.z * h2 + a4.w * h3;
      }
    }
    float* O = out + b * 64 * 256 + cg * 64;
    #pragma unroll
    for (int m = 0; m < 8; m++) O[(m * 8 + rg) * 256 + c] = acc[m];
  }
}

// ---------------- mu / logvar heads v2 (PROVEN r11): float4 LDS reads -----------------
__global__ void k_mulv(const float* __restrict__ in, const float* __restrict__ Wmu,
                       const float* __restrict__ bmu, const float* __restrict__ Wlv,
                       const float* __restrict__ blv, float* __restrict__ mu_out,
                       float* __restrict__ lv_out) {
  __shared__ float in_s[16 * 256];
  __shared__ float part[8 * 16 * 64];
  int t = threadIdx.x, r0 = blockIdx.x * 16;
  for (int e = t; e < 4096; e += 512) in_s[e] = in[r0 * 256 + e];
  __syncthreads();
  int c = t & 63, g = t >> 6;
  int sel = g >> 2, kq = g & 3;
  const float* W = sel ? Wlv : Wmu;
  float acc[16];
  #pragma unroll
  for (int r = 0; r < 16; r++) acc[r] = 0.f;
  #pragma unroll 2
  for (int k4 = kq * 16; k4 < kq * 16 + 16; k4++) {
    float w0 = W[(k4 * 4 + 0) * 64 + c];
    float w1 = W[(k4 * 4 + 1) * 64 + c];
    float w2 = W[(k4 * 4 + 2) * 64 + c];
    float w3 = W[(k4 * 4 + 3) * 64 + c];
    #pragma unroll
    for (int r = 0; r < 16; r++) {
      float4 i4 = *(const float4*)&in_s[r * 256 + k4 * 4];
      acc[r] += i4.x * w0 + i4.y * w1 + i4.z * w2 + i4.w * w3;
    }
  }
  #pragma unroll
  for (int r = 0; r < 16; r++) part[(g * 16 + r) * 64 + c] = acc[r];
  __syncthreads();
  if (t < 128) {
    int cc = t & 63, s2 = t >> 6;
    const float* bb = s2 ? blv : bmu;
    float* O = s2 ? lv_out : mu_out;
    float bv = bb[cc];
    #pragma unroll
    for (int r = 0; r < 16; r++) {
      float v = bv;
      #pragma unroll
      for (int q = 0; q < 4; q++) v += part[((s2 * 4 + q) * 16 + r) * 64 + cc];
      O[(r0 + r) * 64 + cc] = v;
    }
  }
}

// =============== NT GEMM core (PROVEN r6-r11) =========================================
template <int KK, int WU, int WV, bool UG, bool VG, int ULEN, int VLEN>
__device__ __forceinline__ void mmrun(const u16* __restrict__ Up, int Uoff,
                                      const u16* __restrict__ Vp, int Voff,
                                      const char* lds, int ut0, int vt0, int lr, int lk,
                                      f32x4 (&acc)[WU][WV]) {
  #pragma unroll
  for (int kk = 0; kk < KK; kk++) {
    short8 uf[WU], vf[WV];
    #pragma unroll
    for (int i = 0; i < WU; i++) {
      int row = (ut0 + i) * 16 + lr;
      if constexpr (UG) {
        uf[i] = *(const short8*)(Up + row * ULEN + kk * 32 + lk * 8);
      } else {
        int byt = Uoff + row * (ULEN * 2) + kk * 64 + lk * 16;
        byt ^= (row & 7) << 4;
        uf[i] = *(const short8*)(lds + byt);
      }
    }
    #pragma unroll
    for (int j = 0; j < WV; j++) {
      int row = (vt0 + j) * 16 + lr;
      if constexpr (VG) {
        vf[j] = *(const short8*)(Vp + row * VLEN + kk * 32 + lk * 8);
      } else {
        int byt = Voff + row * (VLEN * 2) + kk * 64 + lk * 16;
        byt ^= (row & 7) << 4;
        vf[j] = *(const short8*)(lds + byt);
      }
    }
    #pragma unroll
    for (int i = 0; i < WU; i++)
      #pragma unroll
      for (int j = 0; j < WV; j++)
        acc[i][j] = __builtin_amdgcn_mfma_f32_16x16x32_bf16(uf[i], vf[j], acc[i][j], 0, 0, 0);
  }
}

__device__ __forceinline__ void st64(char* lds, int off, int rowlen, int crow, int ccol0,
                                     float a0, float a1, float a2, float a3) {
  uint2 pk; pk.x = cvtpk(a0, a1); pk.y = cvtpk(a2, a3);
  int byt = off + crow * (rowlen * 2) + ccol0 * 2;
  byt ^= (crow & 7) << 4;
  *(uint2*)(lds + byt) = pk;
}

template <int WU, int WV>
__device__ __forceinline__ void zacc(f32x4 (&acc)[WU][WV]) {
  #pragma unroll
  for (int i = 0; i < WU; i++)
    #pragma unroll
    for (int j = 0; j < WV; j++) acc[i][j] = (f32x4){0.f, 0.f, 0.f, 0.f};
}

// =============== k_chain2 (PROVEN r6): decoder, bf16 MFMA =============================
__global__ void __launch_bounds__(1024) k_chain2(
    const u16* __restrict__ WB, const float* __restrict__ mu_g,
    const float* __restrict__ ctv, const float* __restrict__ ctf,
    const float* __restrict__ db2, const float* __restrict__ db3,
    const float* __restrict__ reb1, const float* __restrict__ reb2,
    float* __restrict__ af_out, float* __restrict__ val_out,
    float* __restrict__ P, float* __restrict__ Q) {
  __shared__ char L[65536];
  constexpr int S2 = 0, S3 = 32768;
  int b = blockIdx.x, t = threadIdx.x;
  int w = t >> 6, lane = t & 63, lr = lane & 15, lk = lane >> 4;

  {
    int r = t >> 4, c0 = (t & 15) * 4;
    float4 v = *(const float4*)(mu_g + ((b * 64 + r) * 64 + c0));
    st64(L, S3, 64, r, c0, v.x, v.y, v.z, v.w);
  }
  __syncthreads();
  {
    f32x4 a[2][2]; zacc(a);
    int ut0 = (w & 7) * 2, vt0 = (w >> 3) * 2;
    mmrun<2, 2, 2, true, false, 64, 64>(WB + ODW1A, 0, WB, S3, L, ut0, vt0, lr, lk, a);
    #pragma unroll
    for (int j = 0; j < 2; j++) {
      int crow = (vt0 + j) * 16 + lr;
      #pragma unroll
      for (int i = 0; i < 2; i++) {
        int cc = (ut0 + i) * 16 + lk * 4;
        float4 cv = *(const float4*)(ctv + b * 256 + cc);
        st64(L, S2, 256, crow, cc, fmaxf(a[i][j][0] + cv.x, 0.f), fmaxf(a[i][j][1] + cv.y, 0.f),
             fmaxf(a[i][j][2] + cv.z, 0.f), fmaxf(a[i][j][3] + cv.w, 0.f));
      }
    }
  }
  __syncthreads();
  {
    f32x4 a[2][2]; zacc(a);
    int ut0 = (w & 7) * 2, vt0 = (w >> 3) * 2;
    mmrun<8, 2, 2, true, false, 256, 256>(WB + ODW2, 0, WB, S2, L, ut0, vt0, lr, lk, a);
    #pragma unroll
    for (int j = 0; j < 2; j++) {
      int crow = (vt0 + j) * 16 + lr;
      #pragma unroll
      for (int i = 0; i < 2; i++) {
        int cc = (ut0 + i) * 16 + lk * 4;
        float4 bv = *(const float4*)(db2 + cc);
        st64(L, S3, 256, crow, cc, fmaxf(a[i][j][0] + bv.x, 0.f), fmaxf(a[i][j][1] + bv.y, 0.f),
             fmaxf(a[i][j][2] + bv.z, 0.f), fmaxf(a[i][j][3] + bv.w, 0.f));
      }
    }
  }
  __syncthreads();
  {
    f32x4 a[1][1]; zacc(a);
    int ut = w & 3, vt = w >> 2;
    mmrun<8, 1, 1, true, false, 256, 256>(WB + ODW3, 0, WB, S3, L, ut, vt, lr, lk, a);
    int crow = vt * 16 + lr, cc = ut * 16 + lk * 4;
    float4 bv = *(const float4*)(db3 + cc);
    float s0 = 1.f / (1.f + expf(-(a[0][0][0] + bv.x)));
    float s1 = 1.f / (1.f + expf(-(a[0][0][1] + bv.y)));
    float s2 = 1.f / (1.f + expf(-(a[0][0][2] + bv.z)));
    float s3 = 1.f / (1.f + expf(-(a[0][0][3] + bv.w)));
    *(float4*)(af_out + ((b * 64 + crow) * 64 + cc)) =
        make_float4(s0 * 0.125f, s1 * 0.125f, s2 * 0.125f, s3 * 0.125f);
    st64(L, S2, 64, crow, cc, s0, s1, s2, s3);
  }
  __syncthreads();
  {
    f32x4 a[2][4]; zacc(a);
    int ut0 = (w & 7) * 2;
    int sel = w >> 3;
    const u16* Up = WB + (sel ? OBPB : OBPA);
    mmrun<2, 2, 4, true, false, 64, 64>(Up, 0, WB, S2, L, ut0, 0, lr, lk, a);
    float* out = sel ? Q : P;
    #pragma unroll
    for (int i = 0; i < 2; i++) {
      int cc = (ut0 + i) * 16 + lk * 4;
      float4 cv = make_float4(0.f, 0.f, 0.f, 0.f);
      if (sel == 0) cv = *(const float4*)(ctf + b * 256 + cc);
      #pragma unroll
      for (int j = 0; j < 4; j++) {
        int crow = j * 16 + lr;
        *(float4*)(out + ((b * 64 + crow) * 256 + cc)) =
            make_float4(a[i][j][0] + cv.x, a[i][j][1] + cv.y, a[i][j][2] + cv.z, a[i][j][3] + cv.w);
      }
    }
  }
  {
    f32x4 a[2][2]; zacc(a);
    int ut0 = (w & 7) * 2, vt0 = (w >> 3) * 2;
    mmrun<2, 2, 2, true, false, 64, 64>(WB + OREW1, 0, WB, S2, L, ut0, vt0, lr, lk, a);
    #pragma unroll
    for (int j = 0; j < 2; j++) {
      int crow = (vt0 + j) * 16 + lr;
      #pragma unroll
      for (int i = 0; i < 2; i++) {
        int cc = (ut0 + i) * 16 + lk * 4;
        float4 bv = *(const float4*)(reb1 + cc);
        st64(L, S3, 256, crow, cc, fmaxf(a[i][j][0] + bv.x, 0.f), fmaxf(a[i][j][1] + bv.y, 0.f),
             fmaxf(a[i][j][2] + bv.z, 0.f), fmaxf(a[i][j][3] + bv.w, 0.f));
      }
    }
  }
  __syncthreads();
  if (w < 4) {
    f32x4 a[1][1]; zacc(a);
    mmrun<8, 1, 1, true, false, 256, 256>(WB + OREW2, 0, WB, S3, L, 0, w, lr, lk, a);
    if (lk == 0) {
      float4 rb = *(const float4*)reb2;
      float v0 = 4.f / (1.f + expf(-(a[0][0][0] + rb.x)));
      float v1 = 4.f / (1.f + expf(-(a[0][0][1] + rb.y)));
      float v2 = 4.f / (1.f + expf(-(a[0][0][2] + rb.z)));
      float v3 = 4.f / (1.f + expf(-(a[0][0][3] + rb.w)));
      *(float4*)(val_out + (b * 64 + w * 16 + lr) * 4) = make_float4(v0, v1, v2, v3);
    }
  }
}

// ===== k_bond v10: 1 block/CU, 8 pairs/block, Q hoisted, build(p+1) ∥ GEMM1(p) ========
__global__ void __launch_bounds__(512, 2) k_bond(
    const float* __restrict__ P, const float* __restrict__ Q,
    const u16* __restrict__ W2T, const float* __restrict__ b2,
    const u16* __restrict__ W3Tx, const float* __restrict__ b3,
    float* __restrict__ bp_out) {
  __shared__ char Gb[2][65536];        // double-buffered: 2 tiles x 32KB each
  __shared__ float pf[2 * 4 * 64 * 4]; // 8KB partials
  int flat = blockIdx.x;               // 256 blocks
  int xcd = flat & 7, rest = flat >> 3;
  int b = xcd * 8 + (rest >> 2);
  int ibase = (rest & 3) * 16;
  int t = threadIdx.x;
  int lane = t & 63, w = t >> 6;       // 8 waves
  int lr = lane & 15, lk = lane >> 4;
  int tl = w & 1, wq = w >> 1;         // wave -> (tile, 64-col group)
  int colg = t & 63, rq = t >> 6;      // build decomposition

  // ---- hoist Q rows once (pair-independent): qst[s] = Q[b][rq*8+s][colg*4..+4) ----
  const float* Qb = Q + b * 64 * 256;
  float4 qst[8];
  #pragma unroll
  for (int s = 0; s < 8; s++) qst[s] = *(const float4*)(Qb + (rq * 8 + s) * 256 + colg * 4);

  // ---- prologue: build pair 0 into Gb[0] ----
  {
    const float* Pb = P + (b * 64 + ibase) * 256 + colg * 4;
    float4 p0 = *(const float4*)(Pb);
    float4 p1 = *(const float4*)(Pb + 256);
    #pragma unroll
    for (int s = 0; s < 8; s++) {
      int r = rq * 8 + s;
      float4 q4 = qst[s];
      int byt = (r * 512 + colg * 8) ^ ((r & 7) << 4);
      uint2 pk0, pk1;
      pk0.x = cvtpk(fmaxf(p0.x + q4.x, 0.f), fmaxf(p0.y + q4.y, 0.f));
      pk0.y = cvtpk(fmaxf(p0.z + q4.z, 0.f), fmaxf(p0.w + q4.w, 0.f));
      pk1.x = cvtpk(fmaxf(p1.x + q4.x, 0.f), fmaxf(p1.y + q4.y, 0.f));
      pk1.y = cvtpk(fmaxf(p1.z + q4.z, 0.f), fmaxf(p1.w + q4.w, 0.f));
      *(uint2*)(Gb[0] + byt) = pk0;
      *(uint2*)(Gb[0] + 32768 + byt) = pk1;
    }
  }
  __syncthreads();

  const u16* Wl = W2T + (wq * 64 + lr) * 256 + lk * 8;

  for (int p = 0; p < 8; p++) {
    char* cur = Gb[p & 1];
    char* nxt = Gb[(p & 1) ^ 1];
    int i0 = ibase + 2 * p;
    // stage next pair's P rows (clamped; redundant last build is harmless)
    int pn = (p < 7) ? p + 1 : 7;
    const float* Pn = P + (b * 64 + ibase + 2 * pn) * 256 + colg * 4;
    float4 p0n = *(const float4*)(Pn);
    float4 p1n = *(const float4*)(Pn + 256);

    // ---- GEMM1(p) from cur, interleaved with build(p+1) into nxt ----
    f32x4 acc[4][4];  // [ni][jt]
    #pragma unroll
    for (int ni = 0; ni < 4; ni++)
      #pragma unroll
      for (int jt = 0; jt < 4; jt++) acc[ni][jt] = (f32x4){0.f, 0.f, 0.f, 0.f};
    short8 bwc[4];
    #pragma unroll
    for (int ni = 0; ni < 4; ni++) bwc[ni] = *(const short8*)(Wl + ni * 16 * 256);
    for (int s = 0; s < 8; s++) {
      int kn = (s + 1) & 7;
      short8 bwn[4];
      #pragma unroll
      for (int ni = 0; ni < 4; ni++) bwn[ni] = *(const short8*)(Wl + ni * 16 * 256 + kn * 32);
      // build one row of next pair (register-sourced)
      {
        int r = rq * 8 + s;
        float4 q4 = qst[s];
        int byt = (r * 512 + colg * 8) ^ ((r & 7) << 4);
        uint2 pk0, pk1;
        pk0.x = cvtpk(fmaxf(p0n.x + q4.x, 0.f), fmaxf(p0n.y + q4.y, 0.f));
        pk0.y = cvtpk(fmaxf(p0n.z + q4.z, 0.f), fmaxf(p0n.w + q4.w, 0.f));
        pk1.x = cvtpk(fmaxf(p1n.x + q4.x, 0.f), fmaxf(p1n.y + q4.y, 0.f));
        pk1.y = cvtpk(fmaxf(p1n.z + q4.z, 0.f), fmaxf(p1n.w + q4.w, 0.f));
        *(uint2*)(nxt + byt) = pk0;
        *(uint2*)(nxt + 32768 + byt) = pk1;
      }
      __builtin_amdgcn_s_setprio(1);
      #pragma unroll
      for (int jt = 0; jt < 4; jt++) {
        int row = jt * 16 + lr;
        int byt = ((row * 512 + s * 64 + lk * 16) ^ ((row & 7) << 4)) + tl * 32768;
        short8 a = *(const short8*)(cur + byt);
        #pragma unroll
        for (int ni = 0; ni < 4; ni++)
          acc[ni][jt] = __builtin_amdgcn_mfma_f32_16x16x32_bf16(bwc[ni], a, acc[ni][jt], 0, 0, 0);
      }
      __builtin_amdgcn_s_setprio(0);
      #pragma unroll
      for (int ni = 0; ni < 4; ni++) bwc[ni] = bwn[ni];
    }
    __syncthreads();

    // ---- writeback g2(p) (bias+relu) into cur ----
    #pragma unroll
    for (int ni = 0; ni < 4; ni++) {
      int col0 = wq * 64 + ni * 16 + lk * 4;
      float4 bb = *(const float4*)(b2 + col0);
      #pragma unroll
      for (int jt = 0; jt < 4; jt++) {
        int grow = jt * 16 + lr;
        uint2 pk;
        pk.x = cvtpk(fmaxf(acc[ni][jt][0] + bb.x, 0.f), fmaxf(acc[ni][jt][1] + bb.y, 0.f));
        pk.y = cvtpk(fmaxf(acc[ni][jt][2] + bb.z, 0.f), fmaxf(acc[ni][jt][3] + bb.w, 0.f));
        int byt = ((grow * 512 + col0 * 2) ^ ((grow & 7) << 4)) + tl * 32768;
        *(uint2*)(cur + byt) = pk;
      }
    }
    __syncthreads();

    // ---- GEMM2(p): wave (tl, wq) does K-slice [wq*64, wq*64+64) + partials ----
    f32x4 acc2[4];
    #pragma unroll
    for (int mi = 0; mi < 4; mi++) acc2[mi] = (f32x4){0.f, 0.f, 0.f, 0.f};
    #pragma unroll
    for (int kk2 = 0; kk2 < 2; kk2++) {
      short8 bw2 = *(const short8*)(W3Tx + lr * 256 + wq * 64 + kk2 * 32 + lk * 8);
      #pragma unroll
      for (int mi = 0; mi < 4; mi++) {
        int row = mi * 16 + lr;
        int kb = (wq * 64 + kk2 * 32 + lk * 8) * 2;
        int byt = ((row * 512 + kb) ^ ((row & 7) << 4)) + tl * 32768;
        short8 a = *(const short8*)(cur + byt);
        acc2[mi] = __builtin_amdgcn_mfma_f32_16x16x32_bf16(a, bw2, acc2[mi], 0, 0, 0);
      }
    }
    if (lr < 4) {
      #pragma unroll
      for (int mi = 0; mi < 4; mi++)
        #pragma unroll
        for (int rg = 0; rg < 4; rg++) {
          int row = mi * 16 + lk * 4 + rg;
          pf[((tl * 4 + wq) * 64 + row) * 4 + lr] = acc2[mi][rg];
        }
    }
    __syncthreads();

    // ---- softmax(p): 512 threads = 2 tiles x 64 rows x 4 cols; sum 4 partials ----
    {
      int tl2 = t >> 8, idx = t & 255;
      int r = idx >> 2, c = idx & 3;
      float lv = b3[c];
      #pragma unroll
      for (int cq = 0; cq < 4; cq++) lv += pf[((tl2 * 4 + cq) * 64 + r) * 4 + c];
      float m = fmaxf(lv, __shfl_xor(lv, 1));
      m = fmaxf(m, __shfl_xor(m, 2));
      float e = expf(lv - m);
      float sum = e + __shfl_xor(e, 1);
      sum += __shfl_xor(sum, 2);
      bp_out[((b * 64 + i0 + tl2) * 64 + r) * 4 + c] = e / sum;
    }
    __syncthreads();
  }
}

extern "C" void kernel_launch(void* const* d_in, const int* in_sizes, int n_in,
                              void* d_out, int out_size, void* d_ws, size_t ws_size,
                              hipStream_t stream) {
  const float* x    = (const float*)d_in[0];
  const float* adj  = (const float*)d_in[1];
  const float* cnd  = (const float*)d_in[2];
  const float* gc1W = (const float*)d_in[3];
  const float* gc1b = (const float*)d_in[4];
  const float* gc2W = (const float*)d_in[5];
  const float* gc2b = (const float*)d_in[6];
  const float* gmuW = (const float*)d_in[7];
  const float* gmub = (const float*)d_in[8];
  const float* glvW = (const float*)d_in[9];
  const float* glvb = (const float*)d_in[10];
  const float* ceW1 = (const float*)d_in[11];
  const float* ceb1 = (const float*)d_in[12];
  const float* ceW2 = (const float*)d_in[13];
  const float* ceb2 = (const float*)d_in[14];
  const float* dW1  = (const float*)d_in[15];
  const float* db1  = (const float*)d_in[16];
  const float* dW2  = (const float*)d_in[17];
  const float* db2  = (const float*)d_in[18];
  const float* dW3  = (const float*)d_in[19];
  const float* db3  = (const float*)d_in[20];
  // d_in[21..24] (at_*) are dead: mean(softmax) == 1/8 exactly
  const float* bpW1 = (const float*)d_in[25];
  const float* bpb1 = (const float*)d_in[26];
  const float* bpW2 = (const float*)d_in[27];
  const float* bpb2 = (const float*)d_in[28];
  const float* bpW3 = (const float*)d_in[29];
  const float* bpb3 = (const float*)d_in[30];
  const float* reW1 = (const float*)d_in[31];
  const float* reb1 = (const float*)d_in[32];
  const float* reW2 = (const float*)d_in[33];
  const float* reb2 = (const float*)d_in[34];

  float* out = (float*)d_out;
  float* af_out  = out;            // [64,64,64]
  float* bp_out  = out + 262144;   // [64,64,64,4]
  float* val_out = out + 1310720;  // [64,64,4]
  float* mu_out  = out + 1327104;  // [64,64,64]
  float* lv_out  = out + 1589248;  // [64,64,64]

  float* ws   = (float*)d_ws;
  float* ctf  = ws;                 // 16384
  float* ctv  = ws + 16384;         // 16384
  float* buf1 = ws + 49152;         // 1048576  (ah1)
  float* buf2 = buf1 + 1048576;     // 1048576  (P)
  float* buf3 = buf2 + 1048576;     // 1048576  (ah2; later Q)
  u16*   WB   = (u16*)(buf3 + 1048576);  // 221184 u16

  k_prep<<<118, 512, 0, stream>>>(cnd, ceW1, ceb1, ceW2, ceb2, bpW1, bpb1, dW1, db1,
                                  dW2, dW3, bpW2, bpW3, reW1, reW2, ctf, ctv, WB);
  k_gc1<<<dim3(4, 64), 512, 0, stream>>>(adj, x, gc1W, gc1b, buf1);        // ah1
  k_linadj<<<dim3(4, 64), 512, 0, stream>>>(adj, buf1, gc2W, gc2b, buf3);  // ah2
  k_mulv<<<256, 512, 0, stream>>>(buf3, gmuW, gmub, glvW, glvb, mu_out, lv_out);
  k_chain2<<<64, 1024, 0, stream>>>(WB, mu_out, ctv, ctf, db2, db3, reb1, reb2,
                                    af_out, val_out, buf2, buf3);          // P=buf2 Q=buf3
  k_bond<<<256, 512, 0, stream>>>(buf2, buf3, WB + OW2T, bpb2, WB + OW3TX, bpb3, bp_out);
}

// Round 15
// 153.424 us; speedup vs baseline: 1.3623x; 1.3623x over previous
//
#include <hip/hip_runtime.h>

typedef short short8 __attribute__((ext_vector_type(8)));
typedef float f32x4 __attribute__((ext_vector_type(4)));
typedef unsigned short u16;
typedef unsigned int u32;

__device__ __forceinline__ u16 f2bf(float f) {
  union { float f; u32 u; } x; x.f = f;
  u32 u = x.u;
  u32 r = (u + 0x7FFFu + ((u >> 16) & 1u)) >> 16;
  return (u16)r;
}

__device__ __forceinline__ u32 cvtpk(float lo, float hi) {
  u32 r;
  asm("v_cvt_pk_bf16_f32 %0, %1, %2" : "=v"(r) : "v"(lo), "v"(hi));
  return r;
}

// ---- WB bf16-region offsets (u16 units) ----
#define OW2T   0        // bond W2^T      [256][256]
#define OW3TX  65536    // bond W3 padT   [16][256]
#define ODW1A  69632    // dW1[0:64]^T    [256][64]
#define ODW2   86016    // dW2^T          [256][256]
#define ODW3   151552   // dW3^T          [64][256]
#define OBPA   167936   // bpW1[0:64]^T   [256][64]  x0.125
#define OBPB   184320   // bpW1[64:128]^T [256][64]  x0.125
#define OREW1  200704   // reW1^T         [256][64]
#define OREW2  217088   // reW2 padT      [16][256]
#define OWMU   221184   // gmuW^T         [64][256]
#define OWLV   237568   // glvW^T         [64][256]
// total 253952 u16

// ====== k_prep: cond c2+ctf+ctv (blocks 0..63) + transposes (64..125) =================
__global__ void __launch_bounds__(512) k_prep(
    const float* __restrict__ cnd, const float* __restrict__ ceW1,
    const float* __restrict__ ceb1, const float* __restrict__ ceW2,
    const float* __restrict__ ceb2, const float* __restrict__ bpW1,
    const float* __restrict__ bpb1, const float* __restrict__ dW1,
    const float* __restrict__ db1, const float* __restrict__ dW2,
    const float* __restrict__ dW3, const float* __restrict__ bpW2,
    const float* __restrict__ bpW3, const float* __restrict__ reW1,
    const float* __restrict__ reW2, const float* __restrict__ gmuW,
    const float* __restrict__ glvW, float* __restrict__ ctf,
    float* __restrict__ ctv, u16* __restrict__ WB) {
  __shared__ float h[256], c2s[256], prf[256], prv[256];
  __shared__ float T[64][65];
  int bid = blockIdx.x, t = threadIdx.x;
  if (bid < 64) {
    int b = bid;
    if (t < 256) {
      float c0 = cnd[b * 2 + 0], c1 = cnd[b * 2 + 1];
      h[t] = fmaxf(c0 * ceW1[t] + c1 * ceW1[256 + t] + ceb1[t], 0.f);
    }
    __syncthreads();
    int col = t & 255, g = t >> 8;
    {
      float acc = 0.f;
      #pragma unroll 8
      for (int k = g * 128; k < g * 128 + 128; k++) acc += h[k] * ceW2[k * 256 + col];
      if (g) prf[col] = acc;
      __syncthreads();
      if (!g) c2s[col] = acc + prf[col] + ceb2[col];
    }
    __syncthreads();
    float af = 0.f, av = 0.f;
    #pragma unroll 4
    for (int k = g * 128; k < g * 128 + 128; k++) {
      float cv = c2s[k];
      af += cv * bpW1[(128 + k) * 256 + col];
      av += cv * dW1[(64 + k) * 256 + col];
    }
    if (g) { prf[col] = af; prv[col] = av; }
    __syncthreads();
    if (!g) {
      ctf[b * 256 + col] = af + prf[col] + bpb1[col];
      ctv[b * 256 + col] = av + prv[col] + db1[col];
    }
    return;
  }
  int mb = bid - 64;  // 0..61
  if (mb >= 60) {
    if (t < 256) {
      const float* s = (mb == 60) ? reW2 : bpW3;
      u16* d = WB + ((mb == 60) ? OREW2 : OW3TX);
      #pragma unroll
      for (int c = 0; c < 16; c++) {
        float v = (c < 4) ? s[t * 4 + c] : 0.f;
        d[c * 256 + t] = f2bf(v);
      }
    }
    return;
  }
  const float* src; u16* dst; int sld, dld, tr, tc; float sc = 1.f;
  if (mb < 4)       { src = dW1;           dst = WB + ODW1A; sld = 256; dld = 64;  tr = 0;            tc = mb;          }
  else if (mb < 20) { int e = mb - 4;  src = dW2;  dst = WB + ODW2; sld = 256; dld = 256; tr = e >> 2; tc = e & 3; }
  else if (mb < 24) { int e = mb - 20; src = dW3;  dst = WB + ODW3; sld = 64;  dld = 256; tr = e;      tc = 0;     }
  else if (mb < 28) { int e = mb - 24; src = bpW1; dst = WB + OBPA; sld = 256; dld = 64;  tr = 0;      tc = e; sc = 0.125f; }
  else if (mb < 32) { int e = mb - 28; src = bpW1 + 64 * 256; dst = WB + OBPB; sld = 256; dld = 64; tr = 0; tc = e; sc = 0.125f; }
  else if (mb < 36) { int e = mb - 32; src = reW1; dst = WB + OREW1; sld = 256; dld = 64; tr = 0;      tc = e;     }
  else if (mb < 40) { int e = mb - 36; src = gmuW; dst = WB + OWMU; sld = 64;  dld = 256; tr = e;      tc = 0;     }
  else if (mb < 44) { int e = mb - 40; src = glvW; dst = WB + OWLV; sld = 64;  dld = 256; tr = e;      tc = 0;     }
  else              { int e = mb - 44; src = bpW2; dst = WB + OW2T; sld = 256; dld = 256; tr = e >> 2; tc = e & 3; }
  int rl = t >> 6, cl = t & 63;
  #pragma unroll
  for (int it = 0; it < 8; it++) {
    int r = it * 8 + rl;
    T[r][cl] = src[(tr * 64 + r) * sld + tc * 64 + cl] * sc;
  }
  __syncthreads();
  #pragma unroll
  for (int it = 0; it < 8; it++) {
    int c2_ = it * 8 + rl;
    dst[(tc * 64 + c2_) * dld + tr * 64 + cl] = f2bf(T[cl][c2_]);
  }
}

// ====== k_gc1 v2 (PROVEN r11): fused ah1; float4 LDS reads ============================
__global__ void __launch_bounds__(512) k_gc1(
    const float* __restrict__ adj, const float* __restrict__ x,
    const float* __restrict__ W1, const float* __restrict__ b1,
    float* __restrict__ out) {
  __shared__ float adj_s[64 * 64];
  __shared__ float x_s[64 * 64];
  __shared__ float ax_s[64 * 64];
  __shared__ float h_s[64 * 64];
  int cg = blockIdx.x, b = blockIdx.y, t = threadIdx.x;
  const float* A = adj + b * 4096;
  const float* X = x + b * 4096;
  for (int e = t; e < 4096; e += 512) { adj_s[e] = A[e]; x_s[e] = X[e]; }
  __syncthreads();
  int c = t & 63, rg = t >> 6;
  {
    float acc[8];
    #pragma unroll
    for (int m = 0; m < 8; m++) acc[m] = 0.f;
    #pragma unroll 4
    for (int j4 = 0; j4 < 16; j4++) {
      float xv0 = x_s[(j4 * 4 + 0) * 64 + c];
      float xv1 = x_s[(j4 * 4 + 1) * 64 + c];
      float xv2 = x_s[(j4 * 4 + 2) * 64 + c];
      float xv3 = x_s[(j4 * 4 + 3) * 64 + c];
      #pragma unroll
      for (int m = 0; m < 8; m++) {
        float4 a4 = *(const float4*)&adj_s[(m * 8 + rg) * 64 + j4 * 4];
        acc[m] += a4.x * xv0 + a4.y * xv1 + a4.z * xv2 + a4.w * xv3;
      }
    }
    #pragma unroll
    for (int m = 0; m < 8; m++) ax_s[(m * 8 + rg) * 64 + c] = acc[m];
  }
  __syncthreads();
  {
    float bv = b1[cg * 64 + c];
    float acc[8];
    #pragma unroll
    for (int m = 0; m < 8; m++) acc[m] = bv;
    #pragma unroll 4
    for (int k4 = 0; k4 < 16; k4++) {
      float w0 = W1[(k4 * 4 + 0) * 256 + cg * 64 + c];
      float w1 = W1[(k4 * 4 + 1) * 256 + cg * 64 + c];
      float w2 = W1[(k4 * 4 + 2) * 256 + cg * 64 + c];
      float w3 = W1[(k4 * 4 + 3) * 256 + cg * 64 + c];
      #pragma unroll
      for (int m = 0; m < 8; m++) {
        float4 a4 = *(const float4*)&ax_s[(m * 8 + rg) * 64 + k4 * 4];
        acc[m] += a4.x * w0 + a4.y * w1 + a4.z * w2 + a4.w * w3;
      }
    }
    #pragma unroll
    for (int m = 0; m < 8; m++) h_s[(m * 8 + rg) * 64 + c] = fmaxf(acc[m], 0.f);
  }
  __syncthreads();
  {
    float acc[8];
    #pragma unroll
    for (int m = 0; m < 8; m++) acc[m] = 0.f;
    #pragma unroll 4
    for (int j4 = 0; j4 < 16; j4++) {
      float h0 = h_s[(j4 * 4 + 0) * 64 + c];
      float h1 = h_s[(j4 * 4 + 1) * 64 + c];
      float h2 = h_s[(j4 * 4 + 2) * 64 + c];
      float h3 = h_s[(j4 * 4 + 3) * 64 + c];
      #pragma unroll
      for (int m = 0; m < 8; m++) {
        float4 a4 = *(const float4*)&adj_s[(m * 8 + rg) * 64 + j4 * 4];
        acc[m] += a4.x * h0 + a4.y * h1 + a4.z * h2 + a4.w * h3;
      }
    }
    float* O = out + b * 64 * 256 + cg * 64;
    #pragma unroll
    for (int m = 0; m < 8; m++) O[(m * 8 + rg) * 256 + c] = acc[m];
  }
}

// ====== k_linadj v2 (PROVEN r11): fused ah2; float4 LDS reads =========================
__global__ void __launch_bounds__(512) k_linadj(
    const float* __restrict__ adj, const float* __restrict__ in,
    const float* __restrict__ W, const float* __restrict__ bias,
    float* __restrict__ out) {
  __shared__ float adj_s[64 * 64];
  __shared__ float in_s[32 * 256];
  __shared__ float h_s[64 * 64];
  int cg = blockIdx.x, b = blockIdx.y, t = threadIdx.x;
  const float* A = adj + b * 4096;
  for (int e = t; e < 4096; e += 512) adj_s[e] = A[e];
  int c = t & 63, rg = t >> 6;
  float bv = bias[cg * 64 + c];
  #pragma unroll
  for (int half = 0; half < 2; half++) {
    if (half) __syncthreads();
    const float* I = in + (b * 64 + half * 32) * 256;
    for (int e = t; e < 32 * 256; e += 512) in_s[e] = I[e];
    __syncthreads();
    float acc[4];
    #pragma unroll
    for (int m = 0; m < 4; m++) acc[m] = bv;
    #pragma unroll 4
    for (int k4 = 0; k4 < 64; k4++) {
      float w0 = W[(k4 * 4 + 0) * 256 + cg * 64 + c];
      float w1 = W[(k4 * 4 + 1) * 256 + cg * 64 + c];
      float w2 = W[(k4 * 4 + 2) * 256 + cg * 64 + c];
      float w3 = W[(k4 * 4 + 3) * 256 + cg * 64 + c];
      #pragma unroll
      for (int m = 0; m < 4; m++) {
        float4 i4 = *(const float4*)&in_s[(m * 8 + rg) * 256 + k4 * 4];
        acc[m] += i4.x * w0 + i4.y * w1 + i4.z * w2 + i4.w * w3;
      }
    }
    #pragma unroll
    for (int m = 0; m < 4; m++)
      h_s[(half * 32 + m * 8 + rg) * 64 + c] = fmaxf(acc[m], 0.f);
  }
  __syncthreads();
  {
    float acc[8];
    #pragma unroll
    for (int m = 0; m < 8; m++) acc[m] = 0.f;
    #pragma unroll 4
    for (int j4 = 0; j4 < 16; j4++) {
      float h0 = h_s[(j4 * 4 + 0) * 64 + c];
      float h1 = h_s[(j4 * 4 + 1) * 64 + c];
      float h2 = h_s[(j4 * 4 + 2) * 64 + c];
      float h3 = h_s[(j4 * 4 + 3) * 64 + c];
      #pragma unroll
      for (int m = 0; m < 8; m++) {
        float4 a4 = *(const float4*)&adj_s[(m * 8 + rg) * 64 + j4 * 4];
        acc[m] += a4.x * h0 + a4.y * h1 + a4.z * h2 + a4.w * h3;
      }
    }
    float* O = out + b * 64 * 256 + cg * 64;
    #pragma unroll
    for (int m = 0; m < 8; m++) O[(m * 8 + rg) * 256 + c] = acc[m];
  }
}

// =============== NT GEMM core (PROVEN r6-r13) =========================================
template <int KK, int WU, int WV, bool UG, bool VG, int ULEN, int VLEN>
__device__ __forceinline__ void mmrun(const u16* __restrict__ Up, int Uoff,
                                      const u16* __restrict__ Vp, int Voff,
                                      const char* lds, int ut0, int vt0, int lr, int lk,
                                      f32x4 (&acc)[WU][WV]) {
  #pragma unroll
  for (int kk = 0; kk < KK; kk++) {
    short8 uf[WU], vf[WV];
    #pragma unroll
    for (int i = 0; i < WU; i++) {
      int row = (ut0 + i) * 16 + lr;
      if constexpr (UG) {
        uf[i] = *(const short8*)(Up + row * ULEN + kk * 32 + lk * 8);
      } else {
        int byt = Uoff + row * (ULEN * 2) + kk * 64 + lk * 16;
        byt ^= (row & 7) << 4;
        uf[i] = *(const short8*)(lds + byt);
      }
    }
    #pragma unroll
    for (int j = 0; j < WV; j++) {
      int row = (vt0 + j) * 16 + lr;
      if constexpr (VG) {
        vf[j] = *(const short8*)(Vp + row * VLEN + kk * 32 + lk * 8);
      } else {
        int byt = Voff + row * (VLEN * 2) + kk * 64 + lk * 16;
        byt ^= (row & 7) << 4;
        vf[j] = *(const short8*)(lds + byt);
      }
    }
    #pragma unroll
    for (int i = 0; i < WU; i++)
      #pragma unroll
      for (int j = 0; j < WV; j++)
        acc[i][j] = __builtin_amdgcn_mfma_f32_16x16x32_bf16(uf[i], vf[j], acc[i][j], 0, 0, 0);
  }
}

__device__ __forceinline__ void st64(char* lds, int off, int rowlen, int crow, int ccol0,
                                     float a0, float a1, float a2, float a3) {
  uint2 pk; pk.x = cvtpk(a0, a1); pk.y = cvtpk(a2, a3);
  int byt = off + crow * (rowlen * 2) + ccol0 * 2;
  byt ^= (crow & 7) << 4;
  *(uint2*)(lds + byt) = pk;
}

template <int WU, int WV>
__device__ __forceinline__ void zacc(f32x4 (&acc)[WU][WV]) {
  #pragma unroll
  for (int i = 0; i < WU; i++)
    #pragma unroll
    for (int j = 0; j < WV; j++) acc[i][j] = (f32x4){0.f, 0.f, 0.f, 0.f};
}

// ====== k_chain2 v2: ah2 -> mu/lv (MFMA) -> decoder -> P/Q/val, bf16 ==================
__global__ void __launch_bounds__(1024) k_chain2(
    const u16* __restrict__ WB, const float* __restrict__ ah2_g,
    const float* __restrict__ ctv, const float* __restrict__ ctf,
    const float* __restrict__ gmub, const float* __restrict__ glvb,
    const float* __restrict__ db2, const float* __restrict__ db3,
    const float* __restrict__ reb1, const float* __restrict__ reb2,
    float* __restrict__ mu_out, float* __restrict__ lv_out,
    float* __restrict__ af_out, float* __restrict__ val_out,
    float* __restrict__ P, float* __restrict__ Q) {
  __shared__ char L[65536];
  constexpr int S2 = 0, S3 = 32768;
  int b = blockIdx.x, t = threadIdx.x;
  int w = t >> 6, lane = t & 63, lr = lane & 15, lk = lane >> 4;

  // ---- stage ah2 (global fp32) -> S2 bf16 [64][256] swizzled ----
  {
    int r = t >> 4, cb = (t & 15) * 16;
    #pragma unroll
    for (int q = 0; q < 4; q++) {
      float4 v = *(const float4*)(ah2_g + ((b * 64 + r) * 256 + cb + q * 4));
      st64(L, S2, 256, r, cb + q * 4, v.x, v.y, v.z, v.w);
    }
  }
  __syncthreads();
  // ---- mu/lv = ah2 @ Wmu/Wlv + b -> global fp32; mu also -> S3 bf16 [64][64] ----
  {
    f32x4 a[2][1]; zacc(a);
    int sel = w >> 3, wq = w & 7;
    int ut0 = (wq & 1) * 2, vt = wq >> 1;
    const u16* Up = WB + (sel ? OWLV : OWMU);
    mmrun<8, 2, 1, true, false, 256, 256>(Up, 0, WB, S2, L, ut0, vt, lr, lk, a);
    int crow = vt * 16 + lr;
    const float* bb = sel ? glvb : gmub;
    float* gout = sel ? lv_out : mu_out;
    #pragma unroll
    for (int i = 0; i < 2; i++) {
      int cc = (ut0 + i) * 16 + lk * 4;
      float4 bv = *(const float4*)(bb + cc);
      float o0 = a[i][0][0] + bv.x, o1 = a[i][0][1] + bv.y;
      float o2 = a[i][0][2] + bv.z, o3 = a[i][0][3] + bv.w;
      *(float4*)(gout + ((b * 64 + crow) * 64 + cc)) = make_float4(o0, o1, o2, o3);
      if (sel == 0) st64(L, S3, 64, crow, cc, o0, o1, o2, o3);
    }
  }
  __syncthreads();
  // ---- f1 = relu(mu@dW1a + ctv) -> S2 [64i][256n] ----
  {
    f32x4 a[2][2]; zacc(a);
    int ut0 = (w & 7) * 2, vt0 = (w >> 3) * 2;
    mmrun<2, 2, 2, true, false, 64, 64>(WB + ODW1A, 0, WB, S3, L, ut0, vt0, lr, lk, a);
    #pragma unroll
    for (int j = 0; j < 2; j++) {
      int crow = (vt0 + j) * 16 + lr;
      #pragma unroll
      for (int i = 0; i < 2; i++) {
        int cc = (ut0 + i) * 16 + lk * 4;
        float4 cv = *(const float4*)(ctv + b * 256 + cc);
        st64(L, S2, 256, crow, cc, fmaxf(a[i][j][0] + cv.x, 0.f), fmaxf(a[i][j][1] + cv.y, 0.f),
             fmaxf(a[i][j][2] + cv.z, 0.f), fmaxf(a[i][j][3] + cv.w, 0.f));
      }
    }
  }
  __syncthreads();
  // ---- f2 = relu(f1@dW2 + db2) -> S3 [64i][256n] ----
  {
    f32x4 a[2][2]; zacc(a);
    int ut0 = (w & 7) * 2, vt0 = (w >> 3) * 2;
    mmrun<8, 2, 2, true, false, 256, 256>(WB + ODW2, 0, WB, S2, L, ut0, vt0, lr, lk, a);
    #pragma unroll
    for (int j = 0; j < 2; j++) {
      int crow = (vt0 + j) * 16 + lr;
      #pragma unroll
      for (int i = 0; i < 2; i++) {
        int cc = (ut0 + i) * 16 + lk * 4;
        float4 bv = *(const float4*)(db2 + cc);
        st64(L, S3, 256, crow, cc, fmaxf(a[i][j][0] + bv.x, 0.f), fmaxf(a[i][j][1] + bv.y, 0.f),
             fmaxf(a[i][j][2] + bv.z, 0.f), fmaxf(a[i][j][3] + bv.w, 0.f));
      }
    }
  }
  __syncthreads();
  // ---- feat = sigmoid(f2@dW3 + db3) -> S2 bf16 [64i][64d]; af_out = feat*0.125 ----
  {
    f32x4 a[1][1]; zacc(a);
    int ut = w & 3, vt = w >> 2;
    mmrun<8, 1, 1, true, false, 256, 256>(WB + ODW3, 0, WB, S3, L, ut, vt, lr, lk, a);
    int crow = vt * 16 + lr, cc = ut * 16 + lk * 4;
    float4 bv = *(const float4*)(db3 + cc);
    float s0 = 1.f / (1.f + expf(-(a[0][0][0] + bv.x)));
    float s1 = 1.f / (1.f + expf(-(a[0][0][1] + bv.y)));
    float s2 = 1.f / (1.f + expf(-(a[0][0][2] + bv.z)));
    float s3 = 1.f / (1.f + expf(-(a[0][0][3] + bv.w)));
    *(float4*)(af_out + ((b * 64 + crow) * 64 + cc)) =
        make_float4(s0 * 0.125f, s1 * 0.125f, s2 * 0.125f, s3 * 0.125f);
    st64(L, S2, 64, crow, cc, s0, s1, s2, s3);
  }
  __syncthreads();
  // ---- P = 0.125*feat@bpW1a + ct ; Q = 0.125*feat@bpW1b -> global fp32 ----
  {
    f32x4 a[2][4]; zacc(a);
    int ut0 = (w & 7) * 2;
    int sel = w >> 3;
    const u16* Up = WB + (sel ? OBPB : OBPA);
    mmrun<2, 2, 4, true, false, 64, 64>(Up, 0, WB, S2, L, ut0, 0, lr, lk, a);
    float* out = sel ? Q : P;
    #pragma unroll
    for (int i = 0; i < 2; i++) {
      int cc = (ut0 + i) * 16 + lk * 4;
      float4 cv = make_float4(0.f, 0.f, 0.f, 0.f);
      if (sel == 0) cv = *(const float4*)(ctf + b * 256 + cc);
      #pragma unroll
      for (int j = 0; j < 4; j++) {
        int crow = j * 16 + lr;
        *(float4*)(out + ((b * 64 + crow) * 256 + cc)) =
            make_float4(a[i][j][0] + cv.x, a[i][j][1] + cv.y, a[i][j][2] + cv.z, a[i][j][3] + cv.w);
      }
    }
  }
  // ---- rh = relu(feat@reW1 + reb1) -> S3 [64i][256n] ----
  {
    f32x4 a[2][2]; zacc(a);
    int ut0 = (w & 7) * 2, vt0 = (w >> 3) * 2;
    mmrun<2, 2, 2, true, false, 64, 64>(WB + OREW1, 0, WB, S2, L, ut0, vt0, lr, lk, a);
    #pragma unroll
    for (int j = 0; j < 2; j++) {
      int crow = (vt0 + j) * 16 + lr;
      #pragma unroll
      for (int i = 0; i < 2; i++) {
        int cc = (ut0 + i) * 16 + lk * 4;
        float4 bv = *(const float4*)(reb1 + cc);
        st64(L, S3, 256, crow, cc, fmaxf(a[i][j][0] + bv.x, 0.f), fmaxf(a[i][j][1] + bv.y, 0.f),
             fmaxf(a[i][j][2] + bv.z, 0.f), fmaxf(a[i][j][3] + bv.w, 0.f));
      }
    }
  }
  __syncthreads();
  // ---- val = 4*sigmoid(rh@reW2 + reb2) -> global fp32 ----
  if (w < 4) {
    f32x4 a[1][1]; zacc(a);
    mmrun<8, 1, 1, true, false, 256, 256>(WB + OREW2, 0, WB, S3, L, 0, w, lr, lk, a);
    if (lk == 0) {
      float4 rb = *(const float4*)reb2;
      float v0 = 4.f / (1.f + expf(-(a[0][0][0] + rb.x)));
      float v1 = 4.f / (1.f + expf(-(a[0][0][1] + rb.y)));
      float v2 = 4.f / (1.f + expf(-(a[0][0][2] + rb.z)));
      float v3 = 4.f / (1.f + expf(-(a[0][0][3] + rb.w)));
      *(float4*)(val_out + (b * 64 + w * 16 + lr) * 4) = make_float4(v0, v1, v2, v3);
    }
  }
}

// =============== fused bond MLP v5 (PROVEN r8/r9/r11, 54us) ===========================
__global__ void __launch_bounds__(512, 4) k_bond(
    const float* __restrict__ P, const float* __restrict__ Q,
    const u16* __restrict__ W2T, const float* __restrict__ b2,
    const u16* __restrict__ W3Tx, const float* __restrict__ b3,
    float* __restrict__ bp_out) {
  __shared__ u16 G[2 * 64 * 256];  // 64 KB: two XOR-swizzled 64x256 bf16 tiles
  int flat = blockIdx.x;
  int xcd = flat & 7, rest = flat >> 3;
  int b = xcd * 8 + (rest >> 5);
  int i0 = (rest & 31) * 2;
  int t = threadIdx.x;
  int lane = t & 63, w = t >> 6;
  int lr = lane & 15, lk = lane >> 4;

  {
    int colg = t & 63, rq = t >> 6;
    const float* Pb = P + (b * 64 + i0) * 256 + colg * 4;
    float4 p0 = *(const float4*)(Pb);
    float4 p1 = *(const float4*)(Pb + 256);
    const float* Qb = Q + b * 64 * 256;
    #pragma unroll
    for (int r = rq * 8; r < rq * 8 + 8; r++) {
      float4 q4 = *(const float4*)(Qb + r * 256 + colg * 4);
      int byt = (r * 512 + colg * 8) ^ ((r & 7) << 4);
      uint2 pk0, pk1;
      pk0.x = cvtpk(fmaxf(p0.x + q4.x, 0.f), fmaxf(p0.y + q4.y, 0.f));
      pk0.y = cvtpk(fmaxf(p0.z + q4.z, 0.f), fmaxf(p0.w + q4.w, 0.f));
      pk1.x = cvtpk(fmaxf(p1.x + q4.x, 0.f), fmaxf(p1.y + q4.y, 0.f));
      pk1.y = cvtpk(fmaxf(p1.z + q4.z, 0.f), fmaxf(p1.w + q4.w, 0.f));
      *(uint2*)((char*)G + byt) = pk0;
      *(uint2*)((char*)G + 32768 + byt) = pk1;
    }
  }
  __syncthreads();

  f32x4 acc[2][2][4];
  #pragma unroll
  for (int tl = 0; tl < 2; tl++)
    #pragma unroll
    for (int ni = 0; ni < 2; ni++)
      #pragma unroll
      for (int mi = 0; mi < 4; mi++) acc[tl][ni][mi] = (f32x4){0.f, 0.f, 0.f, 0.f};

  const u16* Wl = W2T + (w * 32 + lr) * 256 + lk * 8;
  short8 bwc0 = *(const short8*)(Wl);
  short8 bwc1 = *(const short8*)(Wl + 16 * 256);
  for (int kk = 0; kk < 8; kk++) {
    int kn = (kk + 1) & 7;
    short8 bwn0 = *(const short8*)(Wl + kn * 32);
    short8 bwn1 = *(const short8*)(Wl + 16 * 256 + kn * 32);
    __builtin_amdgcn_s_setprio(1);
    #pragma unroll
    for (int mi = 0; mi < 4; mi++) {
      int row = mi * 16 + lr;
      int byt = (row * 512 + kk * 64 + lk * 16) ^ ((row & 7) << 4);
      short8 a0 = *(const short8*)((const char*)G + byt);
      short8 a1 = *(const short8*)((const char*)G + 32768 + byt);
      acc[0][0][mi] = __builtin_amdgcn_mfma_f32_16x16x32_bf16(bwc0, a0, acc[0][0][mi], 0, 0, 0);
      acc[1][0][mi] = __builtin_amdgcn_mfma_f32_16x16x32_bf16(bwc0, a1, acc[1][0][mi], 0, 0, 0);
      acc[0][1][mi] = __builtin_amdgcn_mfma_f32_16x16x32_bf16(bwc1, a0, acc[0][1][mi], 0, 0, 0);
      acc[1][1][mi] = __builtin_amdgcn_mfma_f32_16x16x32_bf16(bwc1, a1, acc[1][1][mi], 0, 0, 0);
    }
    __builtin_amdgcn_s_setprio(0);
    bwc0 = bwn0;
    bwc1 = bwn1;
  }
  __syncthreads();

  #pragma unroll
  for (int tl = 0; tl < 2; tl++)
    #pragma unroll
    for (int ni = 0; ni < 2; ni++) {
      int col0 = w * 32 + ni * 16 + lk * 4;
      float4 bb = *(const float4*)(b2 + col0);
      #pragma unroll
      for (int mi = 0; mi < 4; mi++) {
        int grow = mi * 16 + lr;
        uint2 pk;
        pk.x = cvtpk(fmaxf(acc[tl][ni][mi][0] + bb.x, 0.f), fmaxf(acc[tl][ni][mi][1] + bb.y, 0.f));
        pk.y = cvtpk(fmaxf(acc[tl][ni][mi][2] + bb.z, 0.f), fmaxf(acc[tl][ni][mi][3] + bb.w, 0.f));
        int byt = ((grow * 512 + col0 * 2) ^ ((grow & 7) << 4)) + tl * 32768;
        *(uint2*)((char*)G + byt) = pk;
      }
    }
  __syncthreads();

  f32x4 acc2[2][4];
  #pragma unroll
  for (int tl = 0; tl < 2; tl++)
    #pragma unroll
    for (int mi = 0; mi < 4; mi++) acc2[tl][mi] = (f32x4){0.f, 0.f, 0.f, 0.f};
  {
    short8 bw2 = *(const short8*)(W3Tx + lr * 256 + w * 32 + lk * 8);
    #pragma unroll
    for (int tl = 0; tl < 2; tl++)
      #pragma unroll
      for (int mi = 0; mi < 4; mi++) {
        int row = mi * 16 + lr;
        int byt = ((row * 512 + (w * 32 + lk * 8) * 2) ^ ((row & 7) << 4)) + tl * 32768;
        short8 a = *(const short8*)((const char*)G + byt);
        acc2[tl][mi] = __builtin_amdgcn_mfma_f32_16x16x32_bf16(a, bw2, acc2[tl][mi], 0, 0, 0);
      }
  }
  __syncthreads();
  float* pf = (float*)G;
  if (lr < 4) {
    #pragma unroll
    for (int tl = 0; tl < 2; tl++)
      #pragma unroll
      for (int mi = 0; mi < 4; mi++)
        #pragma unroll
        for (int rg = 0; rg < 4; rg++) {
          int row = mi * 16 + lk * 4 + rg;
          pf[tl * 8192 + (w * 64 + row) * 4 + lr] = acc2[tl][mi][rg];
        }
  }
  __syncthreads();

  {
    int tl = t >> 8, idx = t & 255;
    int r = idx >> 2, c = idx & 3;
    float lv = b3[c];
    #pragma unroll
    for (int wq = 0; wq < 8; wq++) lv += pf[tl * 8192 + (wq * 64 + r) * 4 + c];
    float m = fmaxf(lv, __shfl_xor(lv, 1));
    m = fmaxf(m, __shfl_xor(m, 2));
    float e = expf(lv - m);
    float s = e + __shfl_xor(e, 1);
    s += __shfl_xor(s, 2);
    bp_out[((b * 64 + i0 + tl) * 64 + r) * 4 + c] = e / s;
  }
}

extern "C" void kernel_launch(void* const* d_in, const int* in_sizes, int n_in,
                              void* d_out, int out_size, void* d_ws, size_t ws_size,
                              hipStream_t stream) {
  const float* x    = (const float*)d_in[0];
  const float* adj  = (const float*)d_in[1];
  const float* cnd  = (const float*)d_in[2];
  const float* gc1W = (const float*)d_in[3];
  const float* gc1b = (const float*)d_in[4];
  const float* gc2W = (const float*)d_in[5];
  const float* gc2b = (const float*)d_in[6];
  const float* gmuW = (const float*)d_in[7];
  const float* gmub = (const float*)d_in[8];
  const float* glvW = (const float*)d_in[9];
  const float* glvb = (const float*)d_in[10];
  const float* ceW1 = (const float*)d_in[11];
  const float* ceb1 = (const float*)d_in[12];
  const float* ceW2 = (const float*)d_in[13];
  const float* ceb2 = (const float*)d_in[14];
  const float* dW1  = (const float*)d_in[15];
  const float* db1  = (const float*)d_in[16];
  const float* dW2  = (const float*)d_in[17];
  const float* db2  = (const float*)d_in[18];
  const float* dW3  = (const float*)d_in[19];
  const float* db3  = (const float*)d_in[20];
  // d_in[21..24] (at_*) are dead: mean(softmax) == 1/8 exactly
  const float* bpW1 = (const float*)d_in[25];
  const float* bpb1 = (const float*)d_in[26];
  const float* bpW2 = (const float*)d_in[27];
  const float* bpb2 = (const float*)d_in[28];
  const float* bpW3 = (const float*)d_in[29];
  const float* bpb3 = (const float*)d_in[30];
  const float* reW1 = (const float*)d_in[31];
  const float* reb1 = (const float*)d_in[32];
  const float* reW2 = (const float*)d_in[33];
  const float* reb2 = (const float*)d_in[34];

  float* out = (float*)d_out;
  float* af_out  = out;            // [64,64,64]
  float* bp_out  = out + 262144;   // [64,64,64,4]
  float* val_out = out + 1310720;  // [64,64,4]
  float* mu_out  = out + 1327104;  // [64,64,64]
  float* lv_out  = out + 1589248;  // [64,64,64]

  float* ws   = (float*)d_ws;
  float* ctf  = ws;                 // 16384
  float* ctv  = ws + 16384;         // 16384
  float* buf1 = ws + 49152;         // 1048576  (ah2; later P? no: ah2)
  float* buf2 = buf1 + 1048576;     // 1048576  (P)
  float* buf3 = buf2 + 1048576;     // 1048576  (ah1; later Q)
  u16*   WB   = (u16*)(buf3 + 1048576);  // 253952 u16

  k_prep<<<126, 512, 0, stream>>>(cnd, ceW1, ceb1, ceW2, ceb2, bpW1, bpb1, dW1, db1,
                                  dW2, dW3, bpW2, bpW3, reW1, reW2, gmuW, glvW,
                                  ctf, ctv, WB);
  k_gc1<<<dim3(4, 64), 512, 0, stream>>>(adj, x, gc1W, gc1b, buf3);        // ah1
  k_linadj<<<dim3(4, 64), 512, 0, stream>>>(adj, buf3, gc2W, gc2b, buf1);  // ah2
  k_chain2<<<64, 1024, 0, stream>>>(WB, buf1, ctv, ctf, gmub, glvb, db2, db3,
                                    reb1, reb2, mu_out, lv_out, af_out, val_out,
                                    buf2, buf3);                            // P=buf2 Q=buf3
  k_bond<<<2048, 512, 0, stream>>>(buf2, buf3, WB + OW2T, bpb2, WB + OW3TX, bpb3, bp_out);
}

// Round 16
// 152.621 us; speedup vs baseline: 1.3694x; 1.0053x over previous
//
#include <hip/hip_runtime.h>

typedef short short8 __attribute__((ext_vector_type(8)));
typedef float f32x4 __attribute__((ext_vector_type(4)));
typedef unsigned short u16;
typedef unsigned int u32;

__device__ __forceinline__ u16 f2bf(float f) {
  union { float f; u32 u; } x; x.f = f;
  u32 u = x.u;
  u32 r = (u + 0x7FFFu + ((u >> 16) & 1u)) >> 16;
  return (u16)r;
}

__device__ __forceinline__ u32 cvtpk(float lo, float hi) {
  u32 r;
  asm("v_cvt_pk_bf16_f32 %0, %1, %2" : "=v"(r) : "v"(lo), "v"(hi));
  return r;
}

// ---- WB bf16-region offsets (u16 units) ----
#define OW2T   0        // bond W2^T      [256][256]
#define OW3TX  65536    // bond W3 padT   [16][256]
#define ODW1A  69632    // dW1[0:64]^T    [256][64]
#define ODW2   86016    // dW2^T          [256][256]
#define ODW3   151552   // dW3^T          [64][256]
#define OBPA   167936   // bpW1[0:64]^T   [256][64]  x0.125
#define OBPB   184320   // bpW1[64:128]^T [256][64]  x0.125
#define OREW1  200704   // reW1^T         [256][64]
#define OREW2  217088   // reW2 padT      [16][256]
#define OWMU   221184   // gmuW^T         [64][256]
#define OWLV   237568   // glvW^T         [64][256]
// total 253952 u16

// ====== k_pg: merged prep (blocks 0..125) + fused gc1 (blocks 126..381) ===============
__global__ void __launch_bounds__(512) k_pg(
    const float* __restrict__ cnd, const float* __restrict__ ceW1,
    const float* __restrict__ ceb1, const float* __restrict__ ceW2,
    const float* __restrict__ ceb2, const float* __restrict__ bpW1,
    const float* __restrict__ bpb1, const float* __restrict__ dW1,
    const float* __restrict__ db1, const float* __restrict__ dW2,
    const float* __restrict__ dW3, const float* __restrict__ bpW2,
    const float* __restrict__ bpW3, const float* __restrict__ reW1,
    const float* __restrict__ reW2, const float* __restrict__ gmuW,
    const float* __restrict__ glvW, const float* __restrict__ adj,
    const float* __restrict__ x, const float* __restrict__ gc1W,
    const float* __restrict__ gc1b, float* __restrict__ ctf,
    float* __restrict__ ctv, u16* __restrict__ WB, float* __restrict__ ah1_out) {
  __shared__ char SM[65536];
  int bid = blockIdx.x, t = threadIdx.x;
  if (bid < 126) {
    // ---------------- prep path (PROVEN r12/r15 logic; LDS re-pointed) ----------------
    float* h   = (float*)SM;         // 256
    float* c2s = h + 256;            // 256
    float* prf = h + 512;            // 256
    float* prv = h + 768;            // 256
    float (*T)[65] = (float(*)[65])(SM + 4096);
    if (bid < 64) {
      int b = bid;
      if (t < 256) {
        float c0 = cnd[b * 2 + 0], c1 = cnd[b * 2 + 1];
        h[t] = fmaxf(c0 * ceW1[t] + c1 * ceW1[256 + t] + ceb1[t], 0.f);
      }
      __syncthreads();
      int col = t & 255, g = t >> 8;
      {
        float acc = 0.f;
        #pragma unroll 8
        for (int k = g * 128; k < g * 128 + 128; k++) acc += h[k] * ceW2[k * 256 + col];
        if (g) prf[col] = acc;
        __syncthreads();
        if (!g) c2s[col] = acc + prf[col] + ceb2[col];
      }
      __syncthreads();
      float af = 0.f, av = 0.f;
      #pragma unroll 4
      for (int k = g * 128; k < g * 128 + 128; k++) {
        float cv = c2s[k];
        af += cv * bpW1[(128 + k) * 256 + col];
        av += cv * dW1[(64 + k) * 256 + col];
      }
      if (g) { prf[col] = af; prv[col] = av; }
      __syncthreads();
      if (!g) {
        ctf[b * 256 + col] = af + prf[col] + bpb1[col];
        ctv[b * 256 + col] = av + prv[col] + db1[col];
      }
      return;
    }
    int mb = bid - 64;  // 0..61
    if (mb >= 60) {
      if (t < 256) {
        const float* s = (mb == 60) ? reW2 : bpW3;
        u16* d = WB + ((mb == 60) ? OREW2 : OW3TX);
        #pragma unroll
        for (int c = 0; c < 16; c++) {
          float v = (c < 4) ? s[t * 4 + c] : 0.f;
          d[c * 256 + t] = f2bf(v);
        }
      }
      return;
    }
    const float* src; u16* dst; int sld, dld, tr, tc; float sc = 1.f;
    if (mb < 4)       { src = dW1;           dst = WB + ODW1A; sld = 256; dld = 64;  tr = 0;            tc = mb;          }
    else if (mb < 20) { int e = mb - 4;  src = dW2;  dst = WB + ODW2; sld = 256; dld = 256; tr = e >> 2; tc = e & 3; }
    else if (mb < 24) { int e = mb - 20; src = dW3;  dst = WB + ODW3; sld = 64;  dld = 256; tr = e;      tc = 0;     }
    else if (mb < 28) { int e = mb - 24; src = bpW1; dst = WB + OBPA; sld = 256; dld = 64;  tr = 0;      tc = e; sc = 0.125f; }
    else if (mb < 32) { int e = mb - 28; src = bpW1 + 64 * 256; dst = WB + OBPB; sld = 256; dld = 64; tr = 0; tc = e; sc = 0.125f; }
    else if (mb < 36) { int e = mb - 32; src = reW1; dst = WB + OREW1; sld = 256; dld = 64; tr = 0;      tc = e;     }
    else if (mb < 40) { int e = mb - 36; src = gmuW; dst = WB + OWMU; sld = 64;  dld = 256; tr = e;      tc = 0;     }
    else if (mb < 44) { int e = mb - 40; src = glvW; dst = WB + OWLV; sld = 64;  dld = 256; tr = e;      tc = 0;     }
    else              { int e = mb - 44; src = bpW2; dst = WB + OW2T; sld = 256; dld = 256; tr = e >> 2; tc = e & 3; }
    int rl = t >> 6, cl = t & 63;
    #pragma unroll
    for (int it = 0; it < 8; it++) {
      int r = it * 8 + rl;
      T[r][cl] = src[(tr * 64 + r) * sld + tc * 64 + cl] * sc;
    }
    __syncthreads();
    #pragma unroll
    for (int it = 0; it < 8; it++) {
      int c2_ = it * 8 + rl;
      dst[(tc * 64 + c2_) * dld + tr * 64 + cl] = f2bf(T[cl][c2_]);
    }
    return;
  }
  // ---------------- gc1 path (PROVEN r11 logic; LDS re-pointed) -----------------------
  int e2 = bid - 126;
  int cg = e2 & 3, b = e2 >> 2;
  float* adj_s = (float*)SM;          // 4096
  float* x_s   = adj_s + 4096;
  float* ax_s  = adj_s + 8192;
  float* h_s   = adj_s + 12288;
  const float* A = adj + b * 4096;
  const float* X = x + b * 4096;
  for (int e = t; e < 4096; e += 512) { adj_s[e] = A[e]; x_s[e] = X[e]; }
  __syncthreads();
  int c = t & 63, rg = t >> 6;
  {
    float acc[8];
    #pragma unroll
    for (int m = 0; m < 8; m++) acc[m] = 0.f;
    #pragma unroll 4
    for (int j4 = 0; j4 < 16; j4++) {
      float xv0 = x_s[(j4 * 4 + 0) * 64 + c];
      float xv1 = x_s[(j4 * 4 + 1) * 64 + c];
      float xv2 = x_s[(j4 * 4 + 2) * 64 + c];
      float xv3 = x_s[(j4 * 4 + 3) * 64 + c];
      #pragma unroll
      for (int m = 0; m < 8; m++) {
        float4 a4 = *(const float4*)&adj_s[(m * 8 + rg) * 64 + j4 * 4];
        acc[m] += a4.x * xv0 + a4.y * xv1 + a4.z * xv2 + a4.w * xv3;
      }
    }
    #pragma unroll
    for (int m = 0; m < 8; m++) ax_s[(m * 8 + rg) * 64 + c] = acc[m];
  }
  __syncthreads();
  {
    float bv = gc1b[cg * 64 + c];
    float acc[8];
    #pragma unroll
    for (int m = 0; m < 8; m++) acc[m] = bv;
    #pragma unroll 4
    for (int k4 = 0; k4 < 16; k4++) {
      float w0 = gc1W[(k4 * 4 + 0) * 256 + cg * 64 + c];
      float w1 = gc1W[(k4 * 4 + 1) * 256 + cg * 64 + c];
      float w2 = gc1W[(k4 * 4 + 2) * 256 + cg * 64 + c];
      float w3 = gc1W[(k4 * 4 + 3) * 256 + cg * 64 + c];
      #pragma unroll
      for (int m = 0; m < 8; m++) {
        float4 a4 = *(const float4*)&ax_s[(m * 8 + rg) * 64 + k4 * 4];
        acc[m] += a4.x * w0 + a4.y * w1 + a4.z * w2 + a4.w * w3;
      }
    }
    #pragma unroll
    for (int m = 0; m < 8; m++) h_s[(m * 8 + rg) * 64 + c] = fmaxf(acc[m], 0.f);
  }
  __syncthreads();
  {
    float acc[8];
    #pragma unroll
    for (int m = 0; m < 8; m++) acc[m] = 0.f;
    #pragma unroll 4
    for (int j4 = 0; j4 < 16; j4++) {
      float h0 = h_s[(j4 * 4 + 0) * 64 + c];
      float h1 = h_s[(j4 * 4 + 1) * 64 + c];
      float h2 = h_s[(j4 * 4 + 2) * 64 + c];
      float h3 = h_s[(j4 * 4 + 3) * 64 + c];
      #pragma unroll
      for (int m = 0; m < 8; m++) {
        float4 a4 = *(const float4*)&adj_s[(m * 8 + rg) * 64 + j4 * 4];
        acc[m] += a4.x * h0 + a4.y * h1 + a4.z * h2 + a4.w * h3;
      }
    }
    float* O = ah1_out + b * 64 * 256 + cg * 64;
    #pragma unroll
    for (int m = 0; m < 8; m++) O[(m * 8 + rg) * 256 + c] = acc[m];
  }
}

// ====== k_linadj v2 (PROVEN r11): fused ah2; float4 LDS reads =========================
__global__ void __launch_bounds__(512) k_linadj(
    const float* __restrict__ adj, const float* __restrict__ in,
    const float* __restrict__ W, const float* __restrict__ bias,
    float* __restrict__ out) {
  __shared__ float adj_s[64 * 64];
  __shared__ float in_s[32 * 256];
  __shared__ float h_s[64 * 64];
  int cg = blockIdx.x, b = blockIdx.y, t = threadIdx.x;
  const float* A = adj + b * 4096;
  for (int e = t; e < 4096; e += 512) adj_s[e] = A[e];
  int c = t & 63, rg = t >> 6;
  float bv = bias[cg * 64 + c];
  #pragma unroll
  for (int half = 0; half < 2; half++) {
    if (half) __syncthreads();
    const float* I = in + (b * 64 + half * 32) * 256;
    for (int e = t; e < 32 * 256; e += 512) in_s[e] = I[e];
    __syncthreads();
    float acc[4];
    #pragma unroll
    for (int m = 0; m < 4; m++) acc[m] = bv;
    #pragma unroll 4
    for (int k4 = 0; k4 < 64; k4++) {
      float w0 = W[(k4 * 4 + 0) * 256 + cg * 64 + c];
      float w1 = W[(k4 * 4 + 1) * 256 + cg * 64 + c];
      float w2 = W[(k4 * 4 + 2) * 256 + cg * 64 + c];
      float w3 = W[(k4 * 4 + 3) * 256 + cg * 64 + c];
      #pragma unroll
      for (int m = 0; m < 4; m++) {
        float4 i4 = *(const float4*)&in_s[(m * 8 + rg) * 256 + k4 * 4];
        acc[m] += i4.x * w0 + i4.y * w1 + i4.z * w2 + i4.w * w3;
      }
    }
    #pragma unroll
    for (int m = 0; m < 4; m++)
      h_s[(half * 32 + m * 8 + rg) * 64 + c] = fmaxf(acc[m], 0.f);
  }
  __syncthreads();
  {
    float acc[8];
    #pragma unroll
    for (int m = 0; m < 8; m++) acc[m] = 0.f;
    #pragma unroll 4
    for (int j4 = 0; j4 < 16; j4++) {
      float h0 = h_s[(j4 * 4 + 0) * 64 + c];
      float h1 = h_s[(j4 * 4 + 1) * 64 + c];
      float h2 = h_s[(j4 * 4 + 2) * 64 + c];
      float h3 = h_s[(j4 * 4 + 3) * 64 + c];
      #pragma unroll
      for (int m = 0; m < 8; m++) {
        float4 a4 = *(const float4*)&adj_s[(m * 8 + rg) * 64 + j4 * 4];
        acc[m] += a4.x * h0 + a4.y * h1 + a4.z * h2 + a4.w * h3;
      }
    }
    float* O = out + b * 64 * 256 + cg * 64;
    #pragma unroll
    for (int m = 0; m < 8; m++) O[(m * 8 + rg) * 256 + c] = acc[m];
  }
}

// =============== NT GEMM core (PROVEN r6-r15) =========================================
template <int KK, int WU, int WV, bool UG, bool VG, int ULEN, int VLEN>
__device__ __forceinline__ void mmrun(const u16* __restrict__ Up, int Uoff,
                                      const u16* __restrict__ Vp, int Voff,
                                      const char* lds, int ut0, int vt0, int lr, int lk,
                                      f32x4 (&acc)[WU][WV]) {
  #pragma unroll
  for (int kk = 0; kk < KK; kk++) {
    short8 uf[WU], vf[WV];
    #pragma unroll
    for (int i = 0; i < WU; i++) {
      int row = (ut0 + i) * 16 + lr;
      if constexpr (UG) {
        uf[i] = *(const short8*)(Up + row * ULEN + kk * 32 + lk * 8);
      } else {
        int byt = Uoff + row * (ULEN * 2) + kk * 64 + lk * 16;
        byt ^= (row & 7) << 4;
        uf[i] = *(const short8*)(lds + byt);
      }
    }
    #pragma unroll
    for (int j = 0; j < WV; j++) {
      int row = (vt0 + j) * 16 + lr;
      if constexpr (VG) {
        vf[j] = *(const short8*)(Vp + row * VLEN + kk * 32 + lk * 8);
      } else {
        int byt = Voff + row * (VLEN * 2) + kk * 64 + lk * 16;
        byt ^= (row & 7) << 4;
        vf[j] = *(const short8*)(lds + byt);
      }
    }
    #pragma unroll
    for (int i = 0; i < WU; i++)
      #pragma unroll
      for (int j = 0; j < WV; j++)
        acc[i][j] = __builtin_amdgcn_mfma_f32_16x16x32_bf16(uf[i], vf[j], acc[i][j], 0, 0, 0);
  }
}

__device__ __forceinline__ void st64(char* lds, int off, int rowlen, int crow, int ccol0,
                                     float a0, float a1, float a2, float a3) {
  uint2 pk; pk.x = cvtpk(a0, a1); pk.y = cvtpk(a2, a3);
  int byt = off + crow * (rowlen * 2) + ccol0 * 2;
  byt ^= (crow & 7) << 4;
  *(uint2*)(lds + byt) = pk;
}

template <int WU, int WV>
__device__ __forceinline__ void zacc(f32x4 (&acc)[WU][WV]) {
  #pragma unroll
  for (int i = 0; i < WU; i++)
    #pragma unroll
    for (int j = 0; j < WV; j++) acc[i][j] = (f32x4){0.f, 0.f, 0.f, 0.f};
}

// ====== k_chain2 v2 (PROVEN r15): ah2 -> mu/lv -> decoder -> P/Q/val, bf16 ============
__global__ void __launch_bounds__(1024) k_chain2(
    const u16* __restrict__ WB, const float* __restrict__ ah2_g,
    const float* __restrict__ ctv, const float* __restrict__ ctf,
    const float* __restrict__ gmub, const float* __restrict__ glvb,
    const float* __restrict__ db2, const float* __restrict__ db3,
    const float* __restrict__ reb1, const float* __restrict__ reb2,
    float* __restrict__ mu_out, float* __restrict__ lv_out,
    float* __restrict__ af_out, float* __restrict__ val_out,
    float* __restrict__ P, float* __restrict__ Q) {
  __shared__ char L[65536];
  constexpr int S2 = 0, S3 = 32768;
  int b = blockIdx.x, t = threadIdx.x;
  int w = t >> 6, lane = t & 63, lr = lane & 15, lk = lane >> 4;

  {
    int r = t >> 4, cb = (t & 15) * 16;
    #pragma unroll
    for (int q = 0; q < 4; q++) {
      float4 v = *(const float4*)(ah2_g + ((b * 64 + r) * 256 + cb + q * 4));
      st64(L, S2, 256, r, cb + q * 4, v.x, v.y, v.z, v.w);
    }
  }
  __syncthreads();
  {
    f32x4 a[2][1]; zacc(a);
    int sel = w >> 3, wq = w & 7;
    int ut0 = (wq & 1) * 2, vt = wq >> 1;
    const u16* Up = WB + (sel ? OWLV : OWMU);
    mmrun<8, 2, 1, true, false, 256, 256>(Up, 0, WB, S2, L, ut0, vt, lr, lk, a);
    int crow = vt * 16 + lr;
    const float* bb = sel ? glvb : gmub;
    float* gout = sel ? lv_out : mu_out;
    #pragma unroll
    for (int i = 0; i < 2; i++) {
      int cc = (ut0 + i) * 16 + lk * 4;
      float4 bv = *(const float4*)(bb + cc);
      float o0 = a[i][0][0] + bv.x, o1 = a[i][0][1] + bv.y;
      float o2 = a[i][0][2] + bv.z, o3 = a[i][0][3] + bv.w;
      *(float4*)(gout + ((b * 64 + crow) * 64 + cc)) = make_float4(o0, o1, o2, o3);
      if (sel == 0) st64(L, S3, 64, crow, cc, o0, o1, o2, o3);
    }
  }
  __syncthreads();
  {
    f32x4 a[2][2]; zacc(a);
    int ut0 = (w & 7) * 2, vt0 = (w >> 3) * 2;
    mmrun<2, 2, 2, true, false, 64, 64>(WB + ODW1A, 0, WB, S3, L, ut0, vt0, lr, lk, a);
    #pragma unroll
    for (int j = 0; j < 2; j++) {
      int crow = (vt0 + j) * 16 + lr;
      #pragma unroll
      for (int i = 0; i < 2; i++) {
        int cc = (ut0 + i) * 16 + lk * 4;
        float4 cv = *(const float4*)(ctv + b * 256 + cc);
        st64(L, S2, 256, crow, cc, fmaxf(a[i][j][0] + cv.x, 0.f), fmaxf(a[i][j][1] + cv.y, 0.f),
             fmaxf(a[i][j][2] + cv.z, 0.f), fmaxf(a[i][j][3] + cv.w, 0.f));
      }
    }
  }
  __syncthreads();
  {
    f32x4 a[2][2]; zacc(a);
    int ut0 = (w & 7) * 2, vt0 = (w >> 3) * 2;
    mmrun<8, 2, 2, true, false, 256, 256>(WB + ODW2, 0, WB, S2, L, ut0, vt0, lr, lk, a);
    #pragma unroll
    for (int j = 0; j < 2; j++) {
      int crow = (vt0 + j) * 16 + lr;
      #pragma unroll
      for (int i = 0; i < 2; i++) {
        int cc = (ut0 + i) * 16 + lk * 4;
        float4 bv = *(const float4*)(db2 + cc);
        st64(L, S3, 256, crow, cc, fmaxf(a[i][j][0] + bv.x, 0.f), fmaxf(a[i][j][1] + bv.y, 0.f),
             fmaxf(a[i][j][2] + bv.z, 0.f), fmaxf(a[i][j][3] + bv.w, 0.f));
      }
    }
  }
  __syncthreads();
  {
    f32x4 a[1][1]; zacc(a);
    int ut = w & 3, vt = w >> 2;
    mmrun<8, 1, 1, true, false, 256, 256>(WB + ODW3, 0, WB, S3, L, ut, vt, lr, lk, a);
    int crow = vt * 16 + lr, cc = ut * 16 + lk * 4;
    float4 bv = *(const float4*)(db3 + cc);
    float s0 = 1.f / (1.f + expf(-(a[0][0][0] + bv.x)));
    float s1 = 1.f / (1.f + expf(-(a[0][0][1] + bv.y)));
    float s2 = 1.f / (1.f + expf(-(a[0][0][2] + bv.z)));
    float s3 = 1.f / (1.f + expf(-(a[0][0][3] + bv.w)));
    *(float4*)(af_out + ((b * 64 + crow) * 64 + cc)) =
        make_float4(s0 * 0.125f, s1 * 0.125f, s2 * 0.125f, s3 * 0.125f);
    st64(L, S2, 64, crow, cc, s0, s1, s2, s3);
  }
  __syncthreads();
  {
    f32x4 a[2][4]; zacc(a);
    int ut0 = (w & 7) * 2;
    int sel = w >> 3;
    const u16* Up = WB + (sel ? OBPB : OBPA);
    mmrun<2, 2, 4, true, false, 64, 64>(Up, 0, WB, S2, L, ut0, 0, lr, lk, a);
    float* out = sel ? Q : P;
    #pragma unroll
    for (int i = 0; i < 2; i++) {
      int cc = (ut0 + i) * 16 + lk * 4;
      float4 cv = make_float4(0.f, 0.f, 0.f, 0.f);
      if (sel == 0) cv = *(const float4*)(ctf + b * 256 + cc);
      #pragma unroll
      for (int j = 0; j < 4; j++) {
        int crow = j * 16 + lr;
        *(float4*)(out + ((b * 64 + crow) * 256 + cc)) =
            make_float4(a[i][j][0] + cv.x, a[i][j][1] + cv.y, a[i][j][2] + cv.z, a[i][j][3] + cv.w);
      }
    }
  }
  {
    f32x4 a[2][2]; zacc(a);
    int ut0 = (w & 7) * 2, vt0 = (w >> 3) * 2;
    mmrun<2, 2, 2, true, false, 64, 64>(WB + OREW1, 0, WB, S2, L, ut0, vt0, lr, lk, a);
    #pragma unroll
    for (int j = 0; j < 2; j++) {
      int crow = (vt0 + j) * 16 + lr;
      #pragma unroll
      for (int i = 0; i < 2; i++) {
        int cc = (ut0 + i) * 16 + lk * 4;
        float4 bv = *(const float4*)(reb1 + cc);
        st64(L, S3, 256, crow, cc, fmaxf(a[i][j][0] + bv.x, 0.f), fmaxf(a[i][j][1] + bv.y, 0.f),
             fmaxf(a[i][j][2] + bv.z, 0.f), fmaxf(a[i][j][3] + bv.w, 0.f));
      }
    }
  }
  __syncthreads();
  if (w < 4) {
    f32x4 a[1][1]; zacc(a);
    mmrun<8, 1, 1, true, false, 256, 256>(WB + OREW2, 0, WB, S3, L, 0, w, lr, lk, a);
    if (lk == 0) {
      float4 rb = *(const float4*)reb2;
      float v0 = 4.f / (1.f + expf(-(a[0][0][0] + rb.x)));
      float v1 = 4.f / (1.f + expf(-(a[0][0][1] + rb.y)));
      float v2 = 4.f / (1.f + expf(-(a[0][0][2] + rb.z)));
      float v3 = 4.f / (1.f + expf(-(a[0][0][3] + rb.w)));
      *(float4*)(val_out + (b * 64 + w * 16 + lr) * 4) = make_float4(v0, v1, v2, v3);
    }
  }
}

// ====== k_bond v11: v5 core + lean epilogue (full-K GEMM2/wave, in-reg softmax) =======
__global__ void __launch_bounds__(512, 4) k_bond(
    const float* __restrict__ P, const float* __restrict__ Q,
    const u16* __restrict__ W2T, const float* __restrict__ b2,
    const u16* __restrict__ W3Tx, const float* __restrict__ b3,
    float* __restrict__ bp_out) {
  __shared__ u16 G[2 * 64 * 256];  // 64 KB: two XOR-swizzled 64x256 bf16 tiles
  int flat = blockIdx.x;
  int xcd = flat & 7, rest = flat >> 3;
  int b = xcd * 8 + (rest >> 5);
  int i0 = (rest & 31) * 2;
  int t = threadIdx.x;
  int lane = t & 63, w = t >> 6;
  int lr = lane & 15, lk = lane >> 4;

  // ---- build both G tiles (PROVEN r8) ----
  {
    int colg = t & 63, rq = t >> 6;
    const float* Pb = P + (b * 64 + i0) * 256 + colg * 4;
    float4 p0 = *(const float4*)(Pb);
    float4 p1 = *(const float4*)(Pb + 256);
    const float* Qb = Q + b * 64 * 256;
    #pragma unroll
    for (int r = rq * 8; r < rq * 8 + 8; r++) {
      float4 q4 = *(const float4*)(Qb + r * 256 + colg * 4);
      int byt = (r * 512 + colg * 8) ^ ((r & 7) << 4);
      uint2 pk0, pk1;
      pk0.x = cvtpk(fmaxf(p0.x + q4.x, 0.f), fmaxf(p0.y + q4.y, 0.f));
      pk0.y = cvtpk(fmaxf(p0.z + q4.z, 0.f), fmaxf(p0.w + q4.w, 0.f));
      pk1.x = cvtpk(fmaxf(p1.x + q4.x, 0.f), fmaxf(p1.y + q4.y, 0.f));
      pk1.y = cvtpk(fmaxf(p1.z + q4.z, 0.f), fmaxf(p1.w + q4.w, 0.f));
      *(uint2*)((char*)G + byt) = pk0;
      *(uint2*)((char*)G + 32768 + byt) = pk1;
    }
  }
  __syncthreads();

  // ---- GEMM1 (PROVEN r8): wave owns 32 cols x 2 tiles; bw prefetch; setprio ----
  f32x4 acc[2][2][4];
  #pragma unroll
  for (int tl = 0; tl < 2; tl++)
    #pragma unroll
    for (int ni = 0; ni < 2; ni++)
      #pragma unroll
      for (int mi = 0; mi < 4; mi++) acc[tl][ni][mi] = (f32x4){0.f, 0.f, 0.f, 0.f};

  const u16* Wl = W2T + (w * 32 + lr) * 256 + lk * 8;
  short8 bwc0 = *(const short8*)(Wl);
  short8 bwc1 = *(const short8*)(Wl + 16 * 256);
  for (int kk = 0; kk < 8; kk++) {
    int kn = (kk + 1) & 7;
    short8 bwn0 = *(const short8*)(Wl + kn * 32);
    short8 bwn1 = *(const short8*)(Wl + 16 * 256 + kn * 32);
    __builtin_amdgcn_s_setprio(1);
    #pragma unroll
    for (int mi = 0; mi < 4; mi++) {
      int row = mi * 16 + lr;
      int byt = (row * 512 + kk * 64 + lk * 16) ^ ((row & 7) << 4);
      short8 a0 = *(const short8*)((const char*)G + byt);
      short8 a1 = *(const short8*)((const char*)G + 32768 + byt);
      acc[0][0][mi] = __builtin_amdgcn_mfma_f32_16x16x32_bf16(bwc0, a0, acc[0][0][mi], 0, 0, 0);
      acc[1][0][mi] = __builtin_amdgcn_mfma_f32_16x16x32_bf16(bwc0, a1, acc[1][0][mi], 0, 0, 0);
      acc[0][1][mi] = __builtin_amdgcn_mfma_f32_16x16x32_bf16(bwc1, a0, acc[0][1][mi], 0, 0, 0);
      acc[1][1][mi] = __builtin_amdgcn_mfma_f32_16x16x32_bf16(bwc1, a1, acc[1][1][mi], 0, 0, 0);
    }
    __builtin_amdgcn_s_setprio(0);
    bwc0 = bwn0;
    bwc1 = bwn1;
  }
  __syncthreads();

  // ---- writeback g2 (bias+relu) bf16 (PROVEN r8) ----
  #pragma unroll
  for (int tl = 0; tl < 2; tl++)
    #pragma unroll
    for (int ni = 0; ni < 2; ni++) {
      int col0 = w * 32 + ni * 16 + lk * 4;
      float4 bb = *(const float4*)(b2 + col0);
      #pragma unroll
      for (int mi = 0; mi < 4; mi++) {
        int grow = mi * 16 + lr;
        uint2 pk;
        pk.x = cvtpk(fmaxf(acc[tl][ni][mi][0] + bb.x, 0.f), fmaxf(acc[tl][ni][mi][1] + bb.y, 0.f));
        pk.y = cvtpk(fmaxf(acc[tl][ni][mi][2] + bb.z, 0.f), fmaxf(acc[tl][ni][mi][3] + bb.w, 0.f));
        int byt = ((grow * 512 + col0 * 2) ^ ((grow & 7) << 4)) + tl * 32768;
        *(uint2*)((char*)G + byt) = pk;
      }
    }
  __syncthreads();

  // ---- GEMM2: wave -> (tl = w&1, mi = w>>1); FULL K=256; softmax in-register ----
  {
    int tl2 = w & 1, mi = w >> 1;
    f32x4 acc2 = (f32x4){0.f, 0.f, 0.f, 0.f};
    #pragma unroll
    for (int kk2 = 0; kk2 < 8; kk2++) {
      short8 bw2 = *(const short8*)(W3Tx + lr * 256 + kk2 * 32 + lk * 8);
      int row = mi * 16 + lr;
      int byt = ((row * 512 + (kk2 * 32 + lk * 8) * 2) ^ ((row & 7) << 4)) + tl2 * 32768;
      short8 a = *(const short8*)((const char*)G + byt);
      acc2 = __builtin_amdgcn_mfma_f32_16x16x32_bf16(a, bw2, acc2, 0, 0, 0);
    }
    // lane holds logits[row = mi*16 + lk*4 + rg][col = lr] (valid cols lr<4)
    float b3v = b3[lr & 3];
    float res[4];
    #pragma unroll
    for (int rg = 0; rg < 4; rg++) {
      float v = acc2[rg] + b3v;
      float m = fmaxf(v, __shfl_xor(v, 1));
      m = fmaxf(m, __shfl_xor(m, 2));
      float e = expf(v - m);
      float s = e + __shfl_xor(e, 1);
      s += __shfl_xor(s, 2);
      res[rg] = e / s;
    }
    if (lr < 4) {
      #pragma unroll
      for (int rg = 0; rg < 4; rg++) {
        int row = mi * 16 + lk * 4 + rg;
        bp_out[((b * 64 + i0 + tl2) * 64 + row) * 4 + lr] = res[rg];
      }
    }
  }
}

extern "C" void kernel_launch(void* const* d_in, const int* in_sizes, int n_in,
                              void* d_out, int out_size, void* d_ws, size_t ws_size,
                              hipStream_t stream) {
  const float* x    = (const float*)d_in[0];
  const float* adj  = (const float*)d_in[1];
  const float* cnd  = (const float*)d_in[2];
  const float* gc1W = (const float*)d_in[3];
  const float* gc1b = (const float*)d_in[4];
  const float* gc2W = (const float*)d_in[5];
  const float* gc2b = (const float*)d_in[6];
  const float* gmuW = (const float*)d_in[7];
  const float* gmub = (const float*)d_in[8];
  const float* glvW = (const float*)d_in[9];
  const float* glvb = (const float*)d_in[10];
  const float* ceW1 = (const float*)d_in[11];
  const float* ceb1 = (const float*)d_in[12];
  const float* ceW2 = (const float*)d_in[13];
  const float* ceb2 = (const float*)d_in[14];
  const float* dW1  = (const float*)d_in[15];
  const float* db1  = (const float*)d_in[16];
  const float* dW2  = (const float*)d_in[17];
  const float* db2  = (const float*)d_in[18];
  const float* dW3  = (const float*)d_in[19];
  const float* db3  = (const float*)d_in[20];
  // d_in[21..24] (at_*) are dead: mean(softmax) == 1/8 exactly
  const float* bpW1 = (const float*)d_in[25];
  const float* bpb1 = (const float*)d_in[26];
  const float* bpW2 = (const float*)d_in[27];
  const float* bpb2 = (const float*)d_in[28];
  const float* bpW3 = (const float*)d_in[29];
  const float* bpb3 = (const float*)d_in[30];
  const float* reW1 = (const float*)d_in[31];
  const float* reb1 = (const float*)d_in[32];
  const float* reW2 = (const float*)d_in[33];
  const float* reb2 = (const float*)d_in[34];

  float* out = (float*)d_out;
  float* af_out  = out;            // [64,64,64]
  float* bp_out  = out + 262144;   // [64,64,64,4]
  float* val_out = out + 1310720;  // [64,64,4]
  float* mu_out  = out + 1327104;  // [64,64,64]
  float* lv_out  = out + 1589248;  // [64,64,64]

  float* ws   = (float*)d_ws;
  float* ctf  = ws;                 // 16384
  float* ctv  = ws + 16384;         // 16384
  float* buf1 = ws + 49152;         // 1048576  (ah2)
  float* buf2 = buf1 + 1048576;     // 1048576  (P)
  float* buf3 = buf2 + 1048576;     // 1048576  (ah1; later Q)
  u16*   WB   = (u16*)(buf3 + 1048576);  // 253952 u16

  k_pg<<<382, 512, 0, stream>>>(cnd, ceW1, ceb1, ceW2, ceb2, bpW1, bpb1, dW1, db1,
                                dW2, dW3, bpW2, bpW3, reW1, reW2, gmuW, glvW,
                                adj, x, gc1W, gc1b, ctf, ctv, WB, buf3);   // ah1=buf3
  k_linadj<<<dim3(4, 64), 512, 0, stream>>>(adj, buf3, gc2W, gc2b, buf1);  // ah2
  k_chain2<<<64, 1024, 0, stream>>>(WB, buf1, ctv, ctf, gmub, glvb, db2, db3,
                                    reb1, reb2, mu_out, lv_out, af_out, val_out,
                                    buf2, buf3);                            // P=buf2 Q=buf3
  k_bond<<<2048, 512, 0, stream>>>(buf2, buf3, WB + OW2T, bpb2, WB + OW3TX, bpb3, bp_out);
}

// Round 17
// 140.819 us; speedup vs baseline: 1.4842x; 1.0838x over previous
//
#include <hip/hip_runtime.h>

typedef short short8 __attribute__((ext_vector_type(8)));
typedef float f32x4 __attribute__((ext_vector_type(4)));
typedef unsigned short u16;
typedef unsigned int u32;

__device__ __forceinline__ u16 f2bf(float f) {
  union { float f; u32 u; } x; x.f = f;
  u32 u = x.u;
  u32 r = (u + 0x7FFFu + ((u >> 16) & 1u)) >> 16;
  return (u16)r;
}

__device__ __forceinline__ u32 cvtpk(float lo, float hi) {
  u32 r;
  asm("v_cvt_pk_bf16_f32 %0, %1, %2" : "=v"(r) : "v"(lo), "v"(hi));
  return r;
}

// ---- WB bf16-region offsets (u16 units) ----
#define OW2T   0        // bond W2^T      [256][256]
#define OW3TX  65536    // bond W3 padT   [16][256]
#define ODW1A  69632    // dW1[0:64]^T    [256][64]
#define ODW2   86016    // dW2^T          [256][256]
#define ODW3   151552   // dW3^T          [64][256]
#define OBPA   167936   // bpW1[0:64]^T   [256][64]  x0.125
#define OBPB   184320   // bpW1[64:128]^T [256][64]  x0.125
#define OREW1  200704   // reW1^T         [256][64]
#define OREW2  217088   // reW2 padT      [16][256]
#define OWMU   221184   // gmuW^T         [64][256]
#define OWLV   237568   // glvW^T         [64][256]
// total 253952 u16

// ====== k_pg (PROVEN r16): merged prep (blocks 0..125) + fused gc1 (126..381) =========
__global__ void __launch_bounds__(512) k_pg(
    const float* __restrict__ cnd, const float* __restrict__ ceW1,
    const float* __restrict__ ceb1, const float* __restrict__ ceW2,
    const float* __restrict__ ceb2, const float* __restrict__ bpW1,
    const float* __restrict__ bpb1, const float* __restrict__ dW1,
    const float* __restrict__ db1, const float* __restrict__ dW2,
    const float* __restrict__ dW3, const float* __restrict__ bpW2,
    const float* __restrict__ bpW3, const float* __restrict__ reW1,
    const float* __restrict__ reW2, const float* __restrict__ gmuW,
    const float* __restrict__ glvW, const float* __restrict__ adj,
    const float* __restrict__ x, const float* __restrict__ gc1W,
    const float* __restrict__ gc1b, float* __restrict__ ctf,
    float* __restrict__ ctv, u16* __restrict__ WB, float* __restrict__ ah1_out) {
  __shared__ char SM[65536];
  int bid = blockIdx.x, t = threadIdx.x;
  if (bid < 126) {
    float* h   = (float*)SM;         // 256
    float* c2s = h + 256;            // 256
    float* prf = h + 512;            // 256
    float* prv = h + 768;            // 256
    float (*T)[65] = (float(*)[65])(SM + 4096);
    if (bid < 64) {
      int b = bid;
      if (t < 256) {
        float c0 = cnd[b * 2 + 0], c1 = cnd[b * 2 + 1];
        h[t] = fmaxf(c0 * ceW1[t] + c1 * ceW1[256 + t] + ceb1[t], 0.f);
      }
      __syncthreads();
      int col = t & 255, g = t >> 8;
      {
        float acc = 0.f;
        #pragma unroll 8
        for (int k = g * 128; k < g * 128 + 128; k++) acc += h[k] * ceW2[k * 256 + col];
        if (g) prf[col] = acc;
        __syncthreads();
        if (!g) c2s[col] = acc + prf[col] + ceb2[col];
      }
      __syncthreads();
      float af = 0.f, av = 0.f;
      #pragma unroll 4
      for (int k = g * 128; k < g * 128 + 128; k++) {
        float cv = c2s[k];
        af += cv * bpW1[(128 + k) * 256 + col];
        av += cv * dW1[(64 + k) * 256 + col];
      }
      if (g) { prf[col] = af; prv[col] = av; }
      __syncthreads();
      if (!g) {
        ctf[b * 256 + col] = af + prf[col] + bpb1[col];
        ctv[b * 256 + col] = av + prv[col] + db1[col];
      }
      return;
    }
    int mb = bid - 64;  // 0..61
    if (mb >= 60) {
      if (t < 256) {
        const float* s = (mb == 60) ? reW2 : bpW3;
        u16* d = WB + ((mb == 60) ? OREW2 : OW3TX);
        #pragma unroll
        for (int c = 0; c < 16; c++) {
          float v = (c < 4) ? s[t * 4 + c] : 0.f;
          d[c * 256 + t] = f2bf(v);
        }
      }
      return;
    }
    const float* src; u16* dst; int sld, dld, tr, tc; float sc = 1.f;
    if (mb < 4)       { src = dW1;           dst = WB + ODW1A; sld = 256; dld = 64;  tr = 0;            tc = mb;          }
    else if (mb < 20) { int e = mb - 4;  src = dW2;  dst = WB + ODW2; sld = 256; dld = 256; tr = e >> 2; tc = e & 3; }
    else if (mb < 24) { int e = mb - 20; src = dW3;  dst = WB + ODW3; sld = 64;  dld = 256; tr = e;      tc = 0;     }
    else if (mb < 28) { int e = mb - 24; src = bpW1; dst = WB + OBPA; sld = 256; dld = 64;  tr = 0;      tc = e; sc = 0.125f; }
    else if (mb < 32) { int e = mb - 28; src = bpW1 + 64 * 256; dst = WB + OBPB; sld = 256; dld = 64; tr = 0; tc = e; sc = 0.125f; }
    else if (mb < 36) { int e = mb - 32; src = reW1; dst = WB + OREW1; sld = 256; dld = 64; tr = 0;      tc = e;     }
    else if (mb < 40) { int e = mb - 36; src = gmuW; dst = WB + OWMU; sld = 64;  dld = 256; tr = e;      tc = 0;     }
    else if (mb < 44) { int e = mb - 40; src = glvW; dst = WB + OWLV; sld = 64;  dld = 256; tr = e;      tc = 0;     }
    else              { int e = mb - 44; src = bpW2; dst = WB + OW2T; sld = 256; dld = 256; tr = e >> 2; tc = e & 3; }
    int rl = t >> 6, cl = t & 63;
    #pragma unroll
    for (int it = 0; it < 8; it++) {
      int r = it * 8 + rl;
      T[r][cl] = src[(tr * 64 + r) * sld + tc * 64 + cl] * sc;
    }
    __syncthreads();
    #pragma unroll
    for (int it = 0; it < 8; it++) {
      int c2_ = it * 8 + rl;
      dst[(tc * 64 + c2_) * dld + tr * 64 + cl] = f2bf(T[cl][c2_]);
    }
    return;
  }
  // ---------------- gc1 path (PROVEN r11/r16) -----------------------------------------
  int e2 = bid - 126;
  int cg = e2 & 3, b = e2 >> 2;
  float* adj_s = (float*)SM;          // 4096
  float* x_s   = adj_s + 4096;
  float* ax_s  = adj_s + 8192;
  float* h_s   = adj_s + 12288;
  const float* A = adj + b * 4096;
  const float* X = x + b * 4096;
  for (int e = t; e < 4096; e += 512) { adj_s[e] = A[e]; x_s[e] = X[e]; }
  __syncthreads();
  int c = t & 63, rg = t >> 6;
  {
    float acc[8];
    #pragma unroll
    for (int m = 0; m < 8; m++) acc[m] = 0.f;
    #pragma unroll 4
    for (int j4 = 0; j4 < 16; j4++) {
      float xv0 = x_s[(j4 * 4 + 0) * 64 + c];
      float xv1 = x_s[(j4 * 4 + 1) * 64 + c];
      float xv2 = x_s[(j4 * 4 + 2) * 64 + c];
      float xv3 = x_s[(j4 * 4 + 3) * 64 + c];
      #pragma unroll
      for (int m = 0; m < 8; m++) {
        float4 a4 = *(const float4*)&adj_s[(m * 8 + rg) * 64 + j4 * 4];
        acc[m] += a4.x * xv0 + a4.y * xv1 + a4.z * xv2 + a4.w * xv3;
      }
    }
    #pragma unroll
    for (int m = 0; m < 8; m++) ax_s[(m * 8 + rg) * 64 + c] = acc[m];
  }
  __syncthreads();
  {
    float bv = gc1b[cg * 64 + c];
    float acc[8];
    #pragma unroll
    for (int m = 0; m < 8; m++) acc[m] = bv;
    #pragma unroll 4
    for (int k4 = 0; k4 < 16; k4++) {
      float w0 = gc1W[(k4 * 4 + 0) * 256 + cg * 64 + c];
      float w1 = gc1W[(k4 * 4 + 1) * 256 + cg * 64 + c];
      float w2 = gc1W[(k4 * 4 + 2) * 256 + cg * 64 + c];
      float w3 = gc1W[(k4 * 4 + 3) * 256 + cg * 64 + c];
      #pragma unroll
      for (int m = 0; m < 8; m++) {
        float4 a4 = *(const float4*)&ax_s[(m * 8 + rg) * 64 + k4 * 4];
        acc[m] += a4.x * w0 + a4.y * w1 + a4.z * w2 + a4.w * w3;
      }
    }
    #pragma unroll
    for (int m = 0; m < 8; m++) h_s[(m * 8 + rg) * 64 + c] = fmaxf(acc[m], 0.f);
  }
  __syncthreads();
  {
    float acc[8];
    #pragma unroll
    for (int m = 0; m < 8; m++) acc[m] = 0.f;
    #pragma unroll 4
    for (int j4 = 0; j4 < 16; j4++) {
      float h0 = h_s[(j4 * 4 + 0) * 64 + c];
      float h1 = h_s[(j4 * 4 + 1) * 64 + c];
      float h2 = h_s[(j4 * 4 + 2) * 64 + c];
      float h3 = h_s[(j4 * 4 + 3) * 64 + c];
      #pragma unroll
      for (int m = 0; m < 8; m++) {
        float4 a4 = *(const float4*)&adj_s[(m * 8 + rg) * 64 + j4 * 4];
        acc[m] += a4.x * h0 + a4.y * h1 + a4.z * h2 + a4.w * h3;
      }
    }
    float* O = ah1_out + b * 64 * 256 + cg * 64;
    #pragma unroll
    for (int m = 0; m < 8; m++) O[(m * 8 + rg) * 256 + c] = acc[m];
  }
}

// ====== k_linadj v2 (PROVEN r11): fused ah2; float4 LDS reads =========================
__global__ void __launch_bounds__(512) k_linadj(
    const float* __restrict__ adj, const float* __restrict__ in,
    const float* __restrict__ W, const float* __restrict__ bias,
    float* __restrict__ out) {
  __shared__ float adj_s[64 * 64];
  __shared__ float in_s[32 * 256];
  __shared__ float h_s[64 * 64];
  int cg = blockIdx.x, b = blockIdx.y, t = threadIdx.x;
  const float* A = adj + b * 4096;
  for (int e = t; e < 4096; e += 512) adj_s[e] = A[e];
  int c = t & 63, rg = t >> 6;
  float bv = bias[cg * 64 + c];
  #pragma unroll
  for (int half = 0; half < 2; half++) {
    if (half) __syncthreads();
    const float* I = in + (b * 64 + half * 32) * 256;
    for (int e = t; e < 32 * 256; e += 512) in_s[e] = I[e];
    __syncthreads();
    float acc[4];
    #pragma unroll
    for (int m = 0; m < 4; m++) acc[m] = bv;
    #pragma unroll 4
    for (int k4 = 0; k4 < 64; k4++) {
      float w0 = W[(k4 * 4 + 0) * 256 + cg * 64 + c];
      float w1 = W[(k4 * 4 + 1) * 256 + cg * 64 + c];
      float w2 = W[(k4 * 4 + 2) * 256 + cg * 64 + c];
      float w3 = W[(k4 * 4 + 3) * 256 + cg * 64 + c];
      #pragma unroll
      for (int m = 0; m < 4; m++) {
        float4 i4 = *(const float4*)&in_s[(m * 8 + rg) * 256 + k4 * 4];
        acc[m] += i4.x * w0 + i4.y * w1 + i4.z * w2 + i4.w * w3;
      }
    }
    #pragma unroll
    for (int m = 0; m < 4; m++)
      h_s[(half * 32 + m * 8 + rg) * 64 + c] = fmaxf(acc[m], 0.f);
  }
  __syncthreads();
  {
    float acc[8];
    #pragma unroll
    for (int m = 0; m < 8; m++) acc[m] = 0.f;
    #pragma unroll 4
    for (int j4 = 0; j4 < 16; j4++) {
      float h0 = h_s[(j4 * 4 + 0) * 64 + c];
      float h1 = h_s[(j4 * 4 + 1) * 64 + c];
      float h2 = h_s[(j4 * 4 + 2) * 64 + c];
      float h3 = h_s[(j4 * 4 + 3) * 64 + c];
      #pragma unroll
      for (int m = 0; m < 8; m++) {
        float4 a4 = *(const float4*)&adj_s[(m * 8 + rg) * 64 + j4 * 4];
        acc[m] += a4.x * h0 + a4.y * h1 + a4.z * h2 + a4.w * h3;
      }
    }
    float* O = out + b * 64 * 256 + cg * 64;
    #pragma unroll
    for (int m = 0; m < 8; m++) O[(m * 8 + rg) * 256 + c] = acc[m];
  }
}

// =============== NT GEMM core (PROVEN r6-r16) =========================================
template <int KK, int WU, int WV, bool UG, bool VG, int ULEN, int VLEN>
__device__ __forceinline__ void mmrun(const u16* __restrict__ Up, int Uoff,
                                      const u16* __restrict__ Vp, int Voff,
                                      const char* lds, int ut0, int vt0, int lr, int lk,
                                      f32x4 (&acc)[WU][WV]) {
  #pragma unroll
  for (int kk = 0; kk < KK; kk++) {
    short8 uf[WU], vf[WV];
    #pragma unroll
    for (int i = 0; i < WU; i++) {
      int row = (ut0 + i) * 16 + lr;
      if constexpr (UG) {
        uf[i] = *(const short8*)(Up + row * ULEN + kk * 32 + lk * 8);
      } else {
        int byt = Uoff + row * (ULEN * 2) + kk * 64 + lk * 16;
        byt ^= (row & 7) << 4;
        uf[i] = *(const short8*)(lds + byt);
      }
    }
    #pragma unroll
    for (int j = 0; j < WV; j++) {
      int row = (vt0 + j) * 16 + lr;
      if constexpr (VG) {
        vf[j] = *(const short8*)(Vp + row * VLEN + kk * 32 + lk * 8);
      } else {
        int byt = Voff + row * (VLEN * 2) + kk * 64 + lk * 16;
        byt ^= (row & 7) << 4;
        vf[j] = *(const short8*)(lds + byt);
      }
    }
    #pragma unroll
    for (int i = 0; i < WU; i++)
      #pragma unroll
      for (int j = 0; j < WV; j++)
        acc[i][j] = __builtin_amdgcn_mfma_f32_16x16x32_bf16(uf[i], vf[j], acc[i][j], 0, 0, 0);
  }
}

__device__ __forceinline__ void st64(char* lds, int off, int rowlen, int crow, int ccol0,
                                     float a0, float a1, float a2, float a3) {
  uint2 pk; pk.x = cvtpk(a0, a1); pk.y = cvtpk(a2, a3);
  int byt = off + crow * (rowlen * 2) + ccol0 * 2;
  byt ^= (crow & 7) << 4;
  *(uint2*)(lds + byt) = pk;
}

template <int WU, int WV>
__device__ __forceinline__ void zacc(f32x4 (&acc)[WU][WV]) {
  #pragma unroll
  for (int i = 0; i < WU; i++)
    #pragma unroll
    for (int j = 0; j < WV; j++) acc[i][j] = (f32x4){0.f, 0.f, 0.f, 0.f};
}

// ====== k_chain2 v2 (PROVEN r15): ah2 -> mu/lv -> decoder -> P/Q/val, bf16 ============
__global__ void __launch_bounds__(1024) k_chain2(
    const u16* __restrict__ WB, const float* __restrict__ ah2_g,
    const float* __restrict__ ctv, const float* __restrict__ ctf,
    const float* __restrict__ gmub, const float* __restrict__ glvb,
    const float* __restrict__ db2, const float* __restrict__ db3,
    const float* __restrict__ reb1, const float* __restrict__ reb2,
    float* __restrict__ mu_out, float* __restrict__ lv_out,
    float* __restrict__ af_out, float* __restrict__ val_out,
    float* __restrict__ P, float* __restrict__ Q) {
  __shared__ char L[65536];
  constexpr int S2 = 0, S3 = 32768;
  int b = blockIdx.x, t = threadIdx.x;
  int w = t >> 6, lane = t & 63, lr = lane & 15, lk = lane >> 4;

  {
    int r = t >> 4, cb = (t & 15) * 16;
    #pragma unroll
    for (int q = 0; q < 4; q++) {
      float4 v = *(const float4*)(ah2_g + ((b * 64 + r) * 256 + cb + q * 4));
      st64(L, S2, 256, r, cb + q * 4, v.x, v.y, v.z, v.w);
    }
  }
  __syncthreads();
  {
    f32x4 a[2][1]; zacc(a);
    int sel = w >> 3, wq = w & 7;
    int ut0 = (wq & 1) * 2, vt = wq >> 1;
    const u16* Up = WB + (sel ? OWLV : OWMU);
    mmrun<8, 2, 1, true, false, 256, 256>(Up, 0, WB, S2, L, ut0, vt, lr, lk, a);
    int crow = vt * 16 + lr;
    const float* bb = sel ? glvb : gmub;
    float* gout = sel ? lv_out : mu_out;
    #pragma unroll
    for (int i = 0; i < 2; i++) {
      int cc = (ut0 + i) * 16 + lk * 4;
      float4 bv = *(const float4*)(bb + cc);
      float o0 = a[i][0][0] + bv.x, o1 = a[i][0][1] + bv.y;
      float o2 = a[i][0][2] + bv.z, o3 = a[i][0][3] + bv.w;
      *(float4*)(gout + ((b * 64 + crow) * 64 + cc)) = make_float4(o0, o1, o2, o3);
      if (sel == 0) st64(L, S3, 64, crow, cc, o0, o1, o2, o3);
    }
  }
  __syncthreads();
  {
    f32x4 a[2][2]; zacc(a);
    int ut0 = (w & 7) * 2, vt0 = (w >> 3) * 2;
    mmrun<2, 2, 2, true, false, 64, 64>(WB + ODW1A, 0, WB, S3, L, ut0, vt0, lr, lk, a);
    #pragma unroll
    for (int j = 0; j < 2; j++) {
      int crow = (vt0 + j) * 16 + lr;
      #pragma unroll
      for (int i = 0; i < 2; i++) {
        int cc = (ut0 + i) * 16 + lk * 4;
        float4 cv = *(const float4*)(ctv + b * 256 + cc);
        st64(L, S2, 256, crow, cc, fmaxf(a[i][j][0] + cv.x, 0.f), fmaxf(a[i][j][1] + cv.y, 0.f),
             fmaxf(a[i][j][2] + cv.z, 0.f), fmaxf(a[i][j][3] + cv.w, 0.f));
      }
    }
  }
  __syncthreads();
  {
    f32x4 a[2][2]; zacc(a);
    int ut0 = (w & 7) * 2, vt0 = (w >> 3) * 2;
    mmrun<8, 2, 2, true, false, 256, 256>(WB + ODW2, 0, WB, S2, L, ut0, vt0, lr, lk, a);
    #pragma unroll
    for (int j = 0; j < 2; j++) {
      int crow = (vt0 + j) * 16 + lr;
      #pragma unroll
      for (int i = 0; i < 2; i++) {
        int cc = (ut0 + i) * 16 + lk * 4;
        float4 bv = *(const float4*)(db2 + cc);
        st64(L, S3, 256, crow, cc, fmaxf(a[i][j][0] + bv.x, 0.f), fmaxf(a[i][j][1] + bv.y, 0.f),
             fmaxf(a[i][j][2] + bv.z, 0.f), fmaxf(a[i][j][3] + bv.w, 0.f));
      }
    }
  }
  __syncthreads();
  {
    f32x4 a[1][1]; zacc(a);
    int ut = w & 3, vt = w >> 2;
    mmrun<8, 1, 1, true, false, 256, 256>(WB + ODW3, 0, WB, S3, L, ut, vt, lr, lk, a);
    int crow = vt * 16 + lr, cc = ut * 16 + lk * 4;
    float4 bv = *(const float4*)(db3 + cc);
    float s0 = 1.f / (1.f + expf(-(a[0][0][0] + bv.x)));
    float s1 = 1.f / (1.f + expf(-(a[0][0][1] + bv.y)));
    float s2 = 1.f / (1.f + expf(-(a[0][0][2] + bv.z)));
    float s3 = 1.f / (1.f + expf(-(a[0][0][3] + bv.w)));
    *(float4*)(af_out + ((b * 64 + crow) * 64 + cc)) =
        make_float4(s0 * 0.125f, s1 * 0.125f, s2 * 0.125f, s3 * 0.125f);
    st64(L, S2, 64, crow, cc, s0, s1, s2, s3);
  }
  __syncthreads();
  {
    f32x4 a[2][4]; zacc(a);
    int ut0 = (w & 7) * 2;
    int sel = w >> 3;
    const u16* Up = WB + (sel ? OBPB : OBPA);
    mmrun<2, 2, 4, true, false, 64, 64>(Up, 0, WB, S2, L, ut0, 0, lr, lk, a);
    float* out = sel ? Q : P;
    #pragma unroll
    for (int i = 0; i < 2; i++) {
      int cc = (ut0 + i) * 16 + lk * 4;
      float4 cv = make_float4(0.f, 0.f, 0.f, 0.f);
      if (sel == 0) cv = *(const float4*)(ctf + b * 256 + cc);
      #pragma unroll
      for (int j = 0; j < 4; j++) {
        int crow = j * 16 + lr;
        *(float4*)(out + ((b * 64 + crow) * 256 + cc)) =
            make_float4(a[i][j][0] + cv.x, a[i][j][1] + cv.y, a[i][j][2] + cv.z, a[i][j][3] + cv.w);
      }
    }
  }
  {
    f32x4 a[2][2]; zacc(a);
    int ut0 = (w & 7) * 2, vt0 = (w >> 3) * 2;
    mmrun<2, 2, 2, true, false, 64, 64>(WB + OREW1, 0, WB, S2, L, ut0, vt0, lr, lk, a);
    #pragma unroll
    for (int j = 0; j < 2; j++) {
      int crow = (vt0 + j) * 16 + lr;
      #pragma unroll
      for (int i = 0; i < 2; i++) {
        int cc = (ut0 + i) * 16 + lk * 4;
        float4 bv = *(const float4*)(reb1 + cc);
        st64(L, S3, 256, crow, cc, fmaxf(a[i][j][0] + bv.x, 0.f), fmaxf(a[i][j][1] + bv.y, 0.f),
             fmaxf(a[i][j][2] + bv.z, 0.f), fmaxf(a[i][j][3] + bv.w, 0.f));
      }
    }
  }
  __syncthreads();
  if (w < 4) {
    f32x4 a[1][1]; zacc(a);
    mmrun<8, 1, 1, true, false, 256, 256>(WB + OREW2, 0, WB, S3, L, 0, w, lr, lk, a);
    if (lk == 0) {
      float4 rb = *(const float4*)reb2;
      float v0 = 4.f / (1.f + expf(-(a[0][0][0] + rb.x)));
      float v1 = 4.f / (1.f + expf(-(a[0][0][1] + rb.y)));
      float v2 = 4.f / (1.f + expf(-(a[0][0][2] + rb.z)));
      float v3 = 4.f / (1.f + expf(-(a[0][0][3] + rb.w)));
      *(float4*)(val_out + (b * 64 + w * 16 + lr) * 4) = make_float4(v0, v1, v2, v3);
    }
  }
}

// =============== fused bond MLP v5 (PROVEN r8/r9/r11/r15, 54us) =======================
__global__ void __launch_bounds__(512, 4) k_bond(
    const float* __restrict__ P, const float* __restrict__ Q,
    const u16* __restrict__ W2T, const float* __restrict__ b2,
    const u16* __restrict__ W3Tx, const float* __restrict__ b3,
    float* __restrict__ bp_out) {
  __shared__ u16 G[2 * 64 * 256];  // 64 KB: two XOR-swizzled 64x256 bf16 tiles
  int flat = blockIdx.x;
  int xcd = flat & 7, rest = flat >> 3;
  int b = xcd * 8 + (rest >> 5);
  int i0 = (rest & 31) * 2;
  int t = threadIdx.x;
  int lane = t & 63, w = t >> 6;
  int lr = lane & 15, lk = lane >> 4;

  {
    int colg = t & 63, rq = t >> 6;
    const float* Pb = P + (b * 64 + i0) * 256 + colg * 4;
    float4 p0 = *(const float4*)(Pb);
    float4 p1 = *(const float4*)(Pb + 256);
    const float* Qb = Q + b * 64 * 256;
    #pragma unroll
    for (int r = rq * 8; r < rq * 8 + 8; r++) {
      float4 q4 = *(const float4*)(Qb + r * 256 + colg * 4);
      int byt = (r * 512 + colg * 8) ^ ((r & 7) << 4);
      uint2 pk0, pk1;
      pk0.x = cvtpk(fmaxf(p0.x + q4.x, 0.f), fmaxf(p0.y + q4.y, 0.f));
      pk0.y = cvtpk(fmaxf(p0.z + q4.z, 0.f), fmaxf(p0.w + q4.w, 0.f));
      pk1.x = cvtpk(fmaxf(p1.x + q4.x, 0.f), fmaxf(p1.y + q4.y, 0.f));
      pk1.y = cvtpk(fmaxf(p1.z + q4.z, 0.f), fmaxf(p1.w + q4.w, 0.f));
      *(uint2*)((char*)G + byt) = pk0;
      *(uint2*)((char*)G + 32768 + byt) = pk1;
    }
  }
  __syncthreads();

  f32x4 acc[2][2][4];
  #pragma unroll
  for (int tl = 0; tl < 2; tl++)
    #pragma unroll
    for (int ni = 0; ni < 2; ni++)
      #pragma unroll
      for (int mi = 0; mi < 4; mi++) acc[tl][ni][mi] = (f32x4){0.f, 0.f, 0.f, 0.f};

  const u16* Wl = W2T + (w * 32 + lr) * 256 + lk * 8;
  short8 bwc0 = *(const short8*)(Wl);
  short8 bwc1 = *(const short8*)(Wl + 16 * 256);
  for (int kk = 0; kk < 8; kk++) {
    int kn = (kk + 1) & 7;
    short8 bwn0 = *(const short8*)(Wl + kn * 32);
    short8 bwn1 = *(const short8*)(Wl + 16 * 256 + kn * 32);
    __builtin_amdgcn_s_setprio(1);
    #pragma unroll
    for (int mi = 0; mi < 4; mi++) {
      int row = mi * 16 + lr;
      int byt = (row * 512 + kk * 64 + lk * 16) ^ ((row & 7) << 4);
      short8 a0 = *(const short8*)((const char*)G + byt);
      short8 a1 = *(const short8*)((const char*)G + 32768 + byt);
      acc[0][0][mi] = __builtin_amdgcn_mfma_f32_16x16x32_bf16(bwc0, a0, acc[0][0][mi], 0, 0, 0);
      acc[1][0][mi] = __builtin_amdgcn_mfma_f32_16x16x32_bf16(bwc0, a1, acc[1][0][mi], 0, 0, 0);
      acc[0][1][mi] = __builtin_amdgcn_mfma_f32_16x16x32_bf16(bwc1, a0, acc[0][1][mi], 0, 0, 0);
      acc[1][1][mi] = __builtin_amdgcn_mfma_f32_16x16x32_bf16(bwc1, a1, acc[1][1][mi], 0, 0, 0);
    }
    __builtin_amdgcn_s_setprio(0);
    bwc0 = bwn0;
    bwc1 = bwn1;
  }
  __syncthreads();

  #pragma unroll
  for (int tl = 0; tl < 2; tl++)
    #pragma unroll
    for (int ni = 0; ni < 2; ni++) {
      int col0 = w * 32 + ni * 16 + lk * 4;
      float4 bb = *(const float4*)(b2 + col0);
      #pragma unroll
      for (int mi = 0; mi < 4; mi++) {
        int grow = mi * 16 + lr;
        uint2 pk;
        pk.x = cvtpk(fmaxf(acc[tl][ni][mi][0] + bb.x, 0.f), fmaxf(acc[tl][ni][mi][1] + bb.y, 0.f));
        pk.y = cvtpk(fmaxf(acc[tl][ni][mi][2] + bb.z, 0.f), fmaxf(acc[tl][ni][mi][3] + bb.w, 0.f));
        int byt = ((grow * 512 + col0 * 2) ^ ((grow & 7) << 4)) + tl * 32768;
        *(uint2*)((char*)G + byt) = pk;
      }
    }
  __syncthreads();

  f32x4 acc2[2][4];
  #pragma unroll
  for (int tl = 0; tl < 2; tl++)
    #pragma unroll
    for (int mi = 0; mi < 4; mi++) acc2[tl][mi] = (f32x4){0.f, 0.f, 0.f, 0.f};
  {
    short8 bw2 = *(const short8*)(W3Tx + lr * 256 + w * 32 + lk * 8);
    #pragma unroll
    for (int tl = 0; tl < 2; tl++)
      #pragma unroll
      for (int mi = 0; mi < 4; mi++) {
        int row = mi * 16 + lr;
        int byt = ((row * 512 + (w * 32 + lk * 8) * 2) ^ ((row & 7) << 4)) + tl * 32768;
        short8 a = *(const short8*)((const char*)G + byt);
        acc2[tl][mi] = __builtin_amdgcn_mfma_f32_16x16x32_bf16(a, bw2, acc2[tl][mi], 0, 0, 0);
      }
  }
  __syncthreads();
  float* pf = (float*)G;
  if (lr < 4) {
    #pragma unroll
    for (int tl = 0; tl < 2; tl++)
      #pragma unroll
      for (int mi = 0; mi < 4; mi++)
        #pragma unroll
        for (int rg = 0; rg < 4; rg++) {
          int row = mi * 16 + lk * 4 + rg;
          pf[tl * 8192 + (w * 64 + row) * 4 + lr] = acc2[tl][mi][rg];
        }
  }
  __syncthreads();

  {
    int tl = t >> 8, idx = t & 255;
    int r = idx >> 2, c = idx & 3;
    float lv = b3[c];
    #pragma unroll
    for (int wq = 0; wq < 8; wq++) lv += pf[tl * 8192 + (wq * 64 + r) * 4 + c];
    float m = fmaxf(lv, __shfl_xor(lv, 1));
    m = fmaxf(m, __shfl_xor(m, 2));
    float e = expf(lv - m);
    float s = e + __shfl_xor(e, 1);
    s += __shfl_xor(s, 2);
    bp_out[((b * 64 + i0 + tl) * 64 + r) * 4 + c] = e / s;
  }
}

extern "C" void kernel_launch(void* const* d_in, const int* in_sizes, int n_in,
                              void* d_out, int out_size, void* d_ws, size_t ws_size,
                              hipStream_t stream) {
  const float* x    = (const float*)d_in[0];
  const float* adj  = (const float*)d_in[1];
  const float* cnd  = (const float*)d_in[2];
  const float* gc1W = (const float*)d_in[3];
  const float* gc1b = (const float*)d_in[4];
  const float* gc2W = (const float*)d_in[5];
  const float* gc2b = (const float*)d_in[6];
  const float* gmuW = (const float*)d_in[7];
  const float* gmub = (const float*)d_in[8];
  const float* glvW = (const float*)d_in[9];
  const float* glvb = (const float*)d_in[10];
  const float* ceW1 = (const float*)d_in[11];
  const float* ceb1 = (const float*)d_in[12];
  const float* ceW2 = (const float*)d_in[13];
  const float* ceb2 = (const float*)d_in[14];
  const float* dW1  = (const float*)d_in[15];
  const float* db1  = (const float*)d_in[16];
  const float* dW2  = (const float*)d_in[17];
  const float* db2  = (const float*)d_in[18];
  const float* dW3  = (const float*)d_in[19];
  const float* db3  = (const float*)d_in[20];
  // d_in[21..24] (at_*) are dead: mean(softmax) == 1/8 exactly
  const float* bpW1 = (const float*)d_in[25];
  const float* bpb1 = (const float*)d_in[26];
  const float* bpW2 = (const float*)d_in[27];
  const float* bpb2 = (const float*)d_in[28];
  const float* bpW3 = (const float*)d_in[29];
  const float* bpb3 = (const float*)d_in[30];
  const float* reW1 = (const float*)d_in[31];
  const float* reb1 = (const float*)d_in[32];
  const float* reW2 = (const float*)d_in[33];
  const float* reb2 = (const float*)d_in[34];

  float* out = (float*)d_out;
  float* af_out  = out;            // [64,64,64]
  float* bp_out  = out + 262144;   // [64,64,64,4]
  float* val_out = out + 1310720;  // [64,64,4]
  float* mu_out  = out + 1327104;  // [64,64,64]
  float* lv_out  = out + 1589248;  // [64,64,64]

  float* ws   = (float*)d_ws;
  float* ctf  = ws;                 // 16384
  float* ctv  = ws + 16384;         // 16384
  float* buf1 = ws + 49152;         // 1048576  (ah2)
  float* buf2 = buf1 + 1048576;     // 1048576  (P)
  float* buf3 = buf2 + 1048576;     // 1048576  (ah1; later Q)
  u16*   WB   = (u16*)(buf3 + 1048576);  // 253952 u16

  k_pg<<<382, 512, 0, stream>>>(cnd, ceW1, ceb1, ceW2, ceb2, bpW1, bpb1, dW1, db1,
                                dW2, dW3, bpW2, bpW3, reW1, reW2, gmuW, glvW,
                                adj, x, gc1W, gc1b, ctf, ctv, WB, buf3);   // ah1=buf3
  k_linadj<<<dim3(4, 64), 512, 0, stream>>>(adj, buf3, gc2W, gc2b, buf1);  // ah2
  k_chain2<<<64, 1024, 0, stream>>>(WB, buf1, ctv, ctf, gmub, glvb, db2, db3,
                                    reb1, reb2, mu_out, lv_out, af_out, val_out,
                                    buf2, buf3);                            // P=buf2 Q=buf3
  k_bond<<<2048, 512, 0, stream>>>(buf2, buf3, WB + OW2T, bpb2, WB + OW3TX, bpb3, bp_out);
}

// Round 18
// 124.979 us; speedup vs baseline: 1.6723x; 1.1267x over previous
//
#include <hip/hip_runtime.h>

typedef short short8 __attribute__((ext_vector_type(8)));
typedef float f32x4 __attribute__((ext_vector_type(4)));
typedef unsigned short u16;
typedef unsigned int u32;

__device__ __forceinline__ u16 f2bf(float f) {
  union { float f; u32 u; } x; x.f = f;
  u32 u = x.u;
  u32 r = (u + 0x7FFFu + ((u >> 16) & 1u)) >> 16;
  return (u16)r;
}

__device__ __forceinline__ u32 cvtpk(float lo, float hi) {
  u32 r;
  asm("v_cvt_pk_bf16_f32 %0, %1, %2" : "=v"(r) : "v"(lo), "v"(hi));
  return r;
}

// ---- WB bf16-region offsets (u16 units) ----
#define OW2T   0        // bond W2^T      [256][256]
#define OW3TX  65536    // bond W3 padT   [16][256]
#define ODW1A  69632    // dW1[0:64]^T    [256][64]
#define ODW2   86016    // dW2^T          [256][256]
#define ODW3   151552   // dW3^T          [64][256]
#define OBPA   167936   // bpW1[0:64]^T   [256][64]  x0.125
#define OBPB   184320   // bpW1[64:128]^T [256][64]  x0.125
#define OREW1  200704   // reW1^T         [256][64]
#define OREW2  217088   // reW2 padT      [16][256]
#define OWMU   221184   // gmuW^T         [64][256]
#define OWLV   237568   // glvW^T         [64][256]
// total 253952 u16

// ====== k_pg (PROVEN r16/r17): merged prep (blocks 0..125) + fused gc1 (126..381) =====
__global__ void __launch_bounds__(512) k_pg(
    const float* __restrict__ cnd, const float* __restrict__ ceW1,
    const float* __restrict__ ceb1, const float* __restrict__ ceW2,
    const float* __restrict__ ceb2, const float* __restrict__ bpW1,
    const float* __restrict__ bpb1, const float* __restrict__ dW1,
    const float* __restrict__ db1, const float* __restrict__ dW2,
    const float* __restrict__ dW3, const float* __restrict__ bpW2,
    const float* __restrict__ bpW3, const float* __restrict__ reW1,
    const float* __restrict__ reW2, const float* __restrict__ gmuW,
    const float* __restrict__ glvW, const float* __restrict__ adj,
    const float* __restrict__ x, const float* __restrict__ gc1W,
    const float* __restrict__ gc1b, float* __restrict__ ctf,
    float* __restrict__ ctv, u16* __restrict__ WB, float* __restrict__ ah1_out) {
  __shared__ char SM[65536];
  int bid = blockIdx.x, t = threadIdx.x;
  if (bid < 126) {
    float* h   = (float*)SM;
    float* c2s = h + 256;
    float* prf = h + 512;
    float* prv = h + 768;
    float (*T)[65] = (float(*)[65])(SM + 4096);
    if (bid < 64) {
      int b = bid;
      if (t < 256) {
        float c0 = cnd[b * 2 + 0], c1 = cnd[b * 2 + 1];
        h[t] = fmaxf(c0 * ceW1[t] + c1 * ceW1[256 + t] + ceb1[t], 0.f);
      }
      __syncthreads();
      int col = t & 255, g = t >> 8;
      {
        float acc = 0.f;
        #pragma unroll 8
        for (int k = g * 128; k < g * 128 + 128; k++) acc += h[k] * ceW2[k * 256 + col];
        if (g) prf[col] = acc;
        __syncthreads();
        if (!g) c2s[col] = acc + prf[col] + ceb2[col];
      }
      __syncthreads();
      float af = 0.f, av = 0.f;
      #pragma unroll 4
      for (int k = g * 128; k < g * 128 + 128; k++) {
        float cv = c2s[k];
        af += cv * bpW1[(128 + k) * 256 + col];
        av += cv * dW1[(64 + k) * 256 + col];
      }
      if (g) { prf[col] = af; prv[col] = av; }
      __syncthreads();
      if (!g) {
        ctf[b * 256 + col] = af + prf[col] + bpb1[col];
        ctv[b * 256 + col] = av + prv[col] + db1[col];
      }
      return;
    }
    int mb = bid - 64;  // 0..61
    if (mb >= 60) {
      if (t < 256) {
        const float* s = (mb == 60) ? reW2 : bpW3;
        u16* d = WB + ((mb == 60) ? OREW2 : OW3TX);
        #pragma unroll
        for (int c = 0; c < 16; c++) {
          float v = (c < 4) ? s[t * 4 + c] : 0.f;
          d[c * 256 + t] = f2bf(v);
        }
      }
      return;
    }
    const float* src; u16* dst; int sld, dld, tr, tc; float sc = 1.f;
    if (mb < 4)       { src = dW1;           dst = WB + ODW1A; sld = 256; dld = 64;  tr = 0;            tc = mb;          }
    else if (mb < 20) { int e = mb - 4;  src = dW2;  dst = WB + ODW2; sld = 256; dld = 256; tr = e >> 2; tc = e & 3; }
    else if (mb < 24) { int e = mb - 20; src = dW3;  dst = WB + ODW3; sld = 64;  dld = 256; tr = e;      tc = 0;     }
    else if (mb < 28) { int e = mb - 24; src = bpW1; dst = WB + OBPA; sld = 256; dld = 64;  tr = 0;      tc = e; sc = 0.125f; }
    else if (mb < 32) { int e = mb - 28; src = bpW1 + 64 * 256; dst = WB + OBPB; sld = 256; dld = 64; tr = 0; tc = e; sc = 0.125f; }
    else if (mb < 36) { int e = mb - 32; src = reW1; dst = WB + OREW1; sld = 256; dld = 64; tr = 0;      tc = e;     }
    else if (mb < 40) { int e = mb - 36; src = gmuW; dst = WB + OWMU; sld = 64;  dld = 256; tr = e;      tc = 0;     }
    else if (mb < 44) { int e = mb - 40; src = glvW; dst = WB + OWLV; sld = 64;  dld = 256; tr = e;      tc = 0;     }
    else              { int e = mb - 44; src = bpW2; dst = WB + OW2T; sld = 256; dld = 256; tr = e >> 2; tc = e & 3; }
    int rl = t >> 6, cl = t & 63;
    #pragma unroll
    for (int it = 0; it < 8; it++) {
      int r = it * 8 + rl;
      T[r][cl] = src[(tr * 64 + r) * sld + tc * 64 + cl] * sc;
    }
    __syncthreads();
    #pragma unroll
    for (int it = 0; it < 8; it++) {
      int c2_ = it * 8 + rl;
      dst[(tc * 64 + c2_) * dld + tr * 64 + cl] = f2bf(T[cl][c2_]);
    }
    return;
  }
  int e2 = bid - 126;
  int cg = e2 & 3, b = e2 >> 2;
  float* adj_s = (float*)SM;
  float* x_s   = adj_s + 4096;
  float* ax_s  = adj_s + 8192;
  float* h_s   = adj_s + 12288;
  const float* A = adj + b * 4096;
  const float* X = x + b * 4096;
  for (int e = t; e < 4096; e += 512) { adj_s[e] = A[e]; x_s[e] = X[e]; }
  __syncthreads();
  int c = t & 63, rg = t >> 6;
  {
    float acc[8];
    #pragma unroll
    for (int m = 0; m < 8; m++) acc[m] = 0.f;
    #pragma unroll 4
    for (int j4 = 0; j4 < 16; j4++) {
      float xv0 = x_s[(j4 * 4 + 0) * 64 + c];
      float xv1 = x_s[(j4 * 4 + 1) * 64 + c];
      float xv2 = x_s[(j4 * 4 + 2) * 64 + c];
      float xv3 = x_s[(j4 * 4 + 3) * 64 + c];
      #pragma unroll
      for (int m = 0; m < 8; m++) {
        float4 a4 = *(const float4*)&adj_s[(m * 8 + rg) * 64 + j4 * 4];
        acc[m] += a4.x * xv0 + a4.y * xv1 + a4.z * xv2 + a4.w * xv3;
      }
    }
    #pragma unroll
    for (int m = 0; m < 8; m++) ax_s[(m * 8 + rg) * 64 + c] = acc[m];
  }
  __syncthreads();
  {
    float bv = gc1b[cg * 64 + c];
    float acc[8];
    #pragma unroll
    for (int m = 0; m < 8; m++) acc[m] = bv;
    #pragma unroll 4
    for (int k4 = 0; k4 < 16; k4++) {
      float w0 = gc1W[(k4 * 4 + 0) * 256 + cg * 64 + c];
      float w1 = gc1W[(k4 * 4 + 1) * 256 + cg * 64 + c];
      float w2 = gc1W[(k4 * 4 + 2) * 256 + cg * 64 + c];
      float w3 = gc1W[(k4 * 4 + 3) * 256 + cg * 64 + c];
      #pragma unroll
      for (int m = 0; m < 8; m++) {
        float4 a4 = *(const float4*)&ax_s[(m * 8 + rg) * 64 + k4 * 4];
        acc[m] += a4.x * w0 + a4.y * w1 + a4.z * w2 + a4.w * w3;
      }
    }
    #pragma unroll
    for (int m = 0; m < 8; m++) h_s[(m * 8 + rg) * 64 + c] = fmaxf(acc[m], 0.f);
  }
  __syncthreads();
  {
    float acc[8];
    #pragma unroll
    for (int m = 0; m < 8; m++) acc[m] = 0.f;
    #pragma unroll 4
    for (int j4 = 0; j4 < 16; j4++) {
      float h0 = h_s[(j4 * 4 + 0) * 64 + c];
      float h1 = h_s[(j4 * 4 + 1) * 64 + c];
      float h2 = h_s[(j4 * 4 + 2) * 64 + c];
      float h3 = h_s[(j4 * 4 + 3) * 64 + c];
      #pragma unroll
      for (int m = 0; m < 8; m++) {
        float4 a4 = *(const float4*)&adj_s[(m * 8 + rg) * 64 + j4 * 4];
        acc[m] += a4.x * h0 + a4.y * h1 + a4.z * h2 + a4.w * h3;
      }
    }
    float* O = ah1_out + b * 64 * 256 + cg * 64;
    #pragma unroll
    for (int m = 0; m < 8; m++) O[(m * 8 + rg) * 256 + c] = acc[m];
  }
}

// ====== k_linadj v2 (PROVEN r11): fused ah2; float4 LDS reads =========================
__global__ void __launch_bounds__(512) k_linadj(
    const float* __restrict__ adj, const float* __restrict__ in,
    const float* __restrict__ W, const float* __restrict__ bias,
    float* __restrict__ out) {
  __shared__ float adj_s[64 * 64];
  __shared__ float in_s[32 * 256];
  __shared__ float h_s[64 * 64];
  int cg = blockIdx.x, b = blockIdx.y, t = threadIdx.x;
  const float* A = adj + b * 4096;
  for (int e = t; e < 4096; e += 512) adj_s[e] = A[e];
  int c = t & 63, rg = t >> 6;
  float bv = bias[cg * 64 + c];
  #pragma unroll
  for (int half = 0; half < 2; half++) {
    if (half) __syncthreads();
    const float* I = in + (b * 64 + half * 32) * 256;
    for (int e = t; e < 32 * 256; e += 512) in_s[e] = I[e];
    __syncthreads();
    float acc[4];
    #pragma unroll
    for (int m = 0; m < 4; m++) acc[m] = bv;
    #pragma unroll 4
    for (int k4 = 0; k4 < 64; k4++) {
      float w0 = W[(k4 * 4 + 0) * 256 + cg * 64 + c];
      float w1 = W[(k4 * 4 + 1) * 256 + cg * 64 + c];
      float w2 = W[(k4 * 4 + 2) * 256 + cg * 64 + c];
      float w3 = W[(k4 * 4 + 3) * 256 + cg * 64 + c];
      #pragma unroll
      for (int m = 0; m < 4; m++) {
        float4 i4 = *(const float4*)&in_s[(m * 8 + rg) * 256 + k4 * 4];
        acc[m] += i4.x * w0 + i4.y * w1 + i4.z * w2 + i4.w * w3;
      }
    }
    #pragma unroll
    for (int m = 0; m < 4; m++)
      h_s[(half * 32 + m * 8 + rg) * 64 + c] = fmaxf(acc[m], 0.f);
  }
  __syncthreads();
  {
    float acc[8];
    #pragma unroll
    for (int m = 0; m < 8; m++) acc[m] = 0.f;
    #pragma unroll 4
    for (int j4 = 0; j4 < 16; j4++) {
      float h0 = h_s[(j4 * 4 + 0) * 64 + c];
      float h1 = h_s[(j4 * 4 + 1) * 64 + c];
      float h2 = h_s[(j4 * 4 + 2) * 64 + c];
      float h3 = h_s[(j4 * 4 + 3) * 64 + c];
      #pragma unroll
      for (int m = 0; m < 8; m++) {
        float4 a4 = *(const float4*)&adj_s[(m * 8 + rg) * 64 + j4 * 4];
        acc[m] += a4.x * h0 + a4.y * h1 + a4.z * h2 + a4.w * h3;
      }
    }
    float* O = out + b * 64 * 256 + cg * 64;
    #pragma unroll
    for (int m = 0; m < 8; m++) O[(m * 8 + rg) * 256 + c] = acc[m];
  }
}

// =============== NT GEMM core (PROVEN r6-r17) =========================================
template <int KK, int WU, int WV, bool UG, bool VG, int ULEN, int VLEN>
__device__ __forceinline__ void mmrun(const u16* __restrict__ Up, int Uoff,
                                      const u16* __restrict__ Vp, int Voff,
                                      const char* lds, int ut0, int vt0, int lr, int lk,
                                      f32x4 (&acc)[WU][WV]) {
  #pragma unroll
  for (int kk = 0; kk < KK; kk++) {
    short8 uf[WU], vf[WV];
    #pragma unroll
    for (int i = 0; i < WU; i++) {
      int row = (ut0 + i) * 16 + lr;
      if constexpr (UG) {
        uf[i] = *(const short8*)(Up + row * ULEN + kk * 32 + lk * 8);
      } else {
        int byt = Uoff + row * (ULEN * 2) + kk * 64 + lk * 16;
        byt ^= (row & 7) << 4;
        uf[i] = *(const short8*)(lds + byt);
      }
    }
    #pragma unroll
    for (int j = 0; j < WV; j++) {
      int row = (vt0 + j) * 16 + lr;
      if constexpr (VG) {
        vf[j] = *(const short8*)(Vp + row * VLEN + kk * 32 + lk * 8);
      } else {
        int byt = Voff + row * (VLEN * 2) + kk * 64 + lk * 16;
        byt ^= (row & 7) << 4;
        vf[j] = *(const short8*)(lds + byt);
      }
    }
    #pragma unroll
    for (int i = 0; i < WU; i++)
      #pragma unroll
      for (int j = 0; j < WV; j++)
        acc[i][j] = __builtin_amdgcn_mfma_f32_16x16x32_bf16(uf[i], vf[j], acc[i][j], 0, 0, 0);
  }
}

__device__ __forceinline__ void st64(char* lds, int off, int rowlen, int crow, int ccol0,
                                     float a0, float a1, float a2, float a3) {
  uint2 pk; pk.x = cvtpk(a0, a1); pk.y = cvtpk(a2, a3);
  int byt = off + crow * (rowlen * 2) + ccol0 * 2;
  byt ^= (crow & 7) << 4;
  *(uint2*)(lds + byt) = pk;
}

template <int WU, int WV>
__device__ __forceinline__ void zacc(f32x4 (&acc)[WU][WV]) {
  #pragma unroll
  for (int i = 0; i < WU; i++)
    #pragma unroll
    for (int j = 0; j < WV; j++) acc[i][j] = (f32x4){0.f, 0.f, 0.f, 0.f};
}

// ====== k_chain2 v3: 256 blocks x 512 thr, 16 rows each (row-parallel decoder) ========
__global__ void __launch_bounds__(512) k_chain2(
    const u16* __restrict__ WB, const float* __restrict__ ah2_g,
    const float* __restrict__ ctv, const float* __restrict__ ctf,
    const float* __restrict__ gmub, const float* __restrict__ glvb,
    const float* __restrict__ db2, const float* __restrict__ db3,
    const float* __restrict__ reb1, const float* __restrict__ reb2,
    float* __restrict__ mu_out, float* __restrict__ lv_out,
    float* __restrict__ af_out, float* __restrict__ val_out,
    float* __restrict__ P, float* __restrict__ Q) {
  __shared__ char L[16384];
  constexpr int S2 = 0, S3 = 8192;
  int rb = blockIdx.x;
  int b = rb >> 2, r0 = (rb & 3) << 4;
  int gr0 = b * 64 + r0;
  int t = threadIdx.x;
  int w = t >> 6, lane = t & 63, lr = lane & 15, lk = lane >> 4;

  // ---- stage ah2 rows [r0, r0+16) -> S2 bf16 [16][256] swizzled ----
  {
    int r = t >> 5, c0 = (t & 31) * 8;
    const float* src = ah2_g + (gr0 + r) * 256 + c0;
    float4 v0 = *(const float4*)(src);
    float4 v1 = *(const float4*)(src + 4);
    st64(L, S2, 256, r, c0, v0.x, v0.y, v0.z, v0.w);
    st64(L, S2, 256, r, c0 + 4, v1.x, v1.y, v1.z, v1.w);
  }
  __syncthreads();
  // ---- mu/lv = ah2 @ Wmu/Wlv + b -> global fp32; mu also -> S3 bf16 [16][64] ----
  {
    f32x4 a[1][1]; zacc(a);
    int sel = w >> 2, ut = w & 3;
    const u16* Up = WB + (sel ? OWLV : OWMU);
    mmrun<8, 1, 1, true, false, 256, 256>(Up + ut * 16 * 256, 0, WB, S2, L, 0, 0, lr, lk, a);
    const float* bb = sel ? glvb : gmub;
    float* gout = sel ? lv_out : mu_out;
    int cc = ut * 16 + lk * 4;
    float4 bv = *(const float4*)(bb + cc);
    float o0 = a[0][0][0] + bv.x, o1 = a[0][0][1] + bv.y;
    float o2 = a[0][0][2] + bv.z, o3 = a[0][0][3] + bv.w;
    *(float4*)(gout + (gr0 + lr) * 64 + cc) = make_float4(o0, o1, o2, o3);
    if (sel == 0) st64(L, S3, 64, lr, cc, o0, o1, o2, o3);
  }
  __syncthreads();
  // ---- f1 = relu(mu@dW1a + ctv) -> S2 [16][256] ----
  {
    f32x4 a[2][1]; zacc(a);
    int ut0 = w * 2;
    mmrun<2, 2, 1, true, false, 64, 64>(WB + ODW1A, 0, WB, S3, L, ut0, 0, lr, lk, a);
    #pragma unroll
    for (int i = 0; i < 2; i++) {
      int cc = (ut0 + i) * 16 + lk * 4;
      float4 cv = *(const float4*)(ctv + b * 256 + cc);
      st64(L, S2, 256, lr, cc, fmaxf(a[i][0][0] + cv.x, 0.f), fmaxf(a[i][0][1] + cv.y, 0.f),
           fmaxf(a[i][0][2] + cv.z, 0.f), fmaxf(a[i][0][3] + cv.w, 0.f));
    }
  }
  __syncthreads();
  // ---- f2 = relu(f1@dW2 + db2) -> S3 [16][256] ----
  {
    f32x4 a[2][1]; zacc(a);
    int ut0 = w * 2;
    mmrun<8, 2, 1, true, false, 256, 256>(WB + ODW2, 0, WB, S2, L, ut0, 0, lr, lk, a);
    #pragma unroll
    for (int i = 0; i < 2; i++) {
      int cc = (ut0 + i) * 16 + lk * 4;
      float4 bv = *(const float4*)(db2 + cc);
      st64(L, S3, 256, lr, cc, fmaxf(a[i][0][0] + bv.x, 0.f), fmaxf(a[i][0][1] + bv.y, 0.f),
           fmaxf(a[i][0][2] + bv.z, 0.f), fmaxf(a[i][0][3] + bv.w, 0.f));
    }
  }
  __syncthreads();
  // ---- feat = sigmoid(f2@dW3 + db3) -> S2 bf16 [16][64]; af_out = feat*0.125 ----
  if (w < 4) {
    f32x4 a[1][1]; zacc(a);
    int ut = w;
    mmrun<8, 1, 1, true, false, 256, 256>(WB + ODW3 + ut * 16 * 256, 0, WB, S3, L, 0, 0, lr, lk, a);
    int cc = ut * 16 + lk * 4;
    float4 bv = *(const float4*)(db3 + cc);
    float s0 = 1.f / (1.f + expf(-(a[0][0][0] + bv.x)));
    float s1 = 1.f / (1.f + expf(-(a[0][0][1] + bv.y)));
    float s2 = 1.f / (1.f + expf(-(a[0][0][2] + bv.z)));
    float s3 = 1.f / (1.f + expf(-(a[0][0][3] + bv.w)));
    *(float4*)(af_out + (gr0 + lr) * 64 + cc) =
        make_float4(s0 * 0.125f, s1 * 0.125f, s2 * 0.125f, s3 * 0.125f);
    st64(L, S2, 64, lr, cc, s0, s1, s2, s3);
  }
  __syncthreads();
  // ---- P = 0.125*feat@bpW1a + ct ; Q = 0.125*feat@bpW1b -> global fp32 ----
  {
    f32x4 a[4][1]; zacc(a);
    int sel = w >> 2, ut0 = (w & 3) * 4;
    const u16* Up = WB + (sel ? OBPB : OBPA);
    mmrun<2, 4, 1, true, false, 64, 64>(Up, 0, WB, S2, L, ut0, 0, lr, lk, a);
    float* out = sel ? Q : P;
    #pragma unroll
    for (int i = 0; i < 4; i++) {
      int cc = (ut0 + i) * 16 + lk * 4;
      float4 cv = make_float4(0.f, 0.f, 0.f, 0.f);
      if (sel == 0) cv = *(const float4*)(ctf + b * 256 + cc);
      *(float4*)(out + (gr0 + lr) * 256 + cc) =
          make_float4(a[i][0][0] + cv.x, a[i][0][1] + cv.y, a[i][0][2] + cv.z, a[i][0][3] + cv.w);
    }
  }
  // ---- rh = relu(feat@reW1 + reb1) -> S3 [16][256] ----
  {
    f32x4 a[2][1]; zacc(a);
    int ut0 = w * 2;
    mmrun<2, 2, 1, true, false, 64, 64>(WB + OREW1, 0, WB, S2, L, ut0, 0, lr, lk, a);
    #pragma unroll
    for (int i = 0; i < 2; i++) {
      int cc = (ut0 + i) * 16 + lk * 4;
      float4 bv = *(const float4*)(reb1 + cc);
      st64(L, S3, 256, lr, cc, fmaxf(a[i][0][0] + bv.x, 0.f), fmaxf(a[i][0][1] + bv.y, 0.f),
           fmaxf(a[i][0][2] + bv.z, 0.f), fmaxf(a[i][0][3] + bv.w, 0.f));
    }
  }
  __syncthreads();
  // ---- val = 4*sigmoid(rh@reW2 + reb2) -> global fp32 ----
  if (w == 0) {
    f32x4 a[1][1]; zacc(a);
    mmrun<8, 1, 1, true, false, 256, 256>(WB + OREW2, 0, WB, S3, L, 0, 0, lr, lk, a);
    if (lk == 0) {
      float4 rb = *(const float4*)reb2;
      float v0 = 4.f / (1.f + expf(-(a[0][0][0] + rb.x)));
      float v1 = 4.f / (1.f + expf(-(a[0][0][1] + rb.y)));
      float v2 = 4.f / (1.f + expf(-(a[0][0][2] + rb.z)));
      float v3 = 4.f / (1.f + expf(-(a[0][0][3] + rb.w)));
      *(float4*)(val_out + (gr0 + lr) * 4) = make_float4(v0, v1, v2, v3);
    }
  }
}

// =============== fused bond MLP v5 (PROVEN r8/r9/r11/r15/r17, 54us) ===================
__global__ void __launch_bounds__(512, 4) k_bond(
    const float* __restrict__ P, const float* __restrict__ Q,
    const u16* __restrict__ W2T, const float* __restrict__ b2,
    const u16* __restrict__ W3Tx, const float* __restrict__ b3,
    float* __restrict__ bp_out) {
  __shared__ u16 G[2 * 64 * 256];
  int flat = blockIdx.x;
  int xcd = flat & 7, rest = flat >> 3;
  int b = xcd * 8 + (rest >> 5);
  int i0 = (rest & 31) * 2;
  int t = threadIdx.x;
  int lane = t & 63, w = t >> 6;
  int lr = lane & 15, lk = lane >> 4;

  {
    int colg = t & 63, rq = t >> 6;
    const float* Pb = P + (b * 64 + i0) * 256 + colg * 4;
    float4 p0 = *(const float4*)(Pb);
    float4 p1 = *(const float4*)(Pb + 256);
    const float* Qb = Q + b * 64 * 256;
    #pragma unroll
    for (int r = rq * 8; r < rq * 8 + 8; r++) {
      float4 q4 = *(const float4*)(Qb + r * 256 + colg * 4);
      int byt = (r * 512 + colg * 8) ^ ((r & 7) << 4);
      uint2 pk0, pk1;
      pk0.x = cvtpk(fmaxf(p0.x + q4.x, 0.f), fmaxf(p0.y + q4.y, 0.f));
      pk0.y = cvtpk(fmaxf(p0.z + q4.z, 0.f), fmaxf(p0.w + q4.w, 0.f));
      pk1.x = cvtpk(fmaxf(p1.x + q4.x, 0.f), fmaxf(p1.y + q4.y, 0.f));
      pk1.y = cvtpk(fmaxf(p1.z + q4.z, 0.f), fmaxf(p1.w + q4.w, 0.f));
      *(uint2*)((char*)G + byt) = pk0;
      *(uint2*)((char*)G + 32768 + byt) = pk1;
    }
  }
  __syncthreads();

  f32x4 acc[2][2][4];
  #pragma unroll
  for (int tl = 0; tl < 2; tl++)
    #pragma unroll
    for (int ni = 0; ni < 2; ni++)
      #pragma unroll
      for (int mi = 0; mi < 4; mi++) acc[tl][ni][mi] = (f32x4){0.f, 0.f, 0.f, 0.f};

  const u16* Wl = W2T + (w * 32 + lr) * 256 + lk * 8;
  short8 bwc0 = *(const short8*)(Wl);
  short8 bwc1 = *(const short8*)(Wl + 16 * 256);
  for (int kk = 0; kk < 8; kk++) {
    int kn = (kk + 1) & 7;
    short8 bwn0 = *(const short8*)(Wl + kn * 32);
    short8 bwn1 = *(const short8*)(Wl + 16 * 256 + kn * 32);
    __builtin_amdgcn_s_setprio(1);
    #pragma unroll
    for (int mi = 0; mi < 4; mi++) {
      int row = mi * 16 + lr;
      int byt = (row * 512 + kk * 64 + lk * 16) ^ ((row & 7) << 4);
      short8 a0 = *(const short8*)((const char*)G + byt);
      short8 a1 = *(const short8*)((const char*)G + 32768 + byt);
      acc[0][0][mi] = __builtin_amdgcn_mfma_f32_16x16x32_bf16(bwc0, a0, acc[0][0][mi], 0, 0, 0);
      acc[1][0][mi] = __builtin_amdgcn_mfma_f32_16x16x32_bf16(bwc0, a1, acc[1][0][mi], 0, 0, 0);
      acc[0][1][mi] = __builtin_amdgcn_mfma_f32_16x16x32_bf16(bwc1, a0, acc[0][1][mi], 0, 0, 0);
      acc[1][1][mi] = __builtin_amdgcn_mfma_f32_16x16x32_bf16(bwc1, a1, acc[1][1][mi], 0, 0, 0);
    }
    __builtin_amdgcn_s_setprio(0);
    bwc0 = bwn0;
    bwc1 = bwn1;
  }
  __syncthreads();

  #pragma unroll
  for (int tl = 0; tl < 2; tl++)
    #pragma unroll
    for (int ni = 0; ni < 2; ni++) {
      int col0 = w * 32 + ni * 16 + lk * 4;
      float4 bb = *(const float4*)(b2 + col0);
      #pragma unroll
      for (int mi = 0; mi < 4; mi++) {
        int grow = mi * 16 + lr;
        uint2 pk;
        pk.x = cvtpk(fmaxf(acc[tl][ni][mi][0] + bb.x, 0.f), fmaxf(acc[tl][ni][mi][1] + bb.y, 0.f));
        pk.y = cvtpk(fmaxf(acc[tl][ni][mi][2] + bb.z, 0.f), fmaxf(acc[tl][ni][mi][3] + bb.w, 0.f));
        int byt = ((grow * 512 + col0 * 2) ^ ((grow & 7) << 4)) + tl * 32768;
        *(uint2*)((char*)G + byt) = pk;
      }
    }
  __syncthreads();

  f32x4 acc2[2][4];
  #pragma unroll
  for (int tl = 0; tl < 2; tl++)
    #pragma unroll
    for (int mi = 0; mi < 4; mi++) acc2[tl][mi] = (f32x4){0.f, 0.f, 0.f, 0.f};
  {
    short8 bw2 = *(const short8*)(W3Tx + lr * 256 + w * 32 + lk * 8);
    #pragma unroll
    for (int tl = 0; tl < 2; tl++)
      #pragma unroll
      for (int mi = 0; mi < 4; mi++) {
        int row = mi * 16 + lr;
        int byt = ((row * 512 + (w * 32 + lk * 8) * 2) ^ ((row & 7) << 4)) + tl * 32768;
        short8 a = *(const short8*)((const char*)G + byt);
        acc2[tl][mi] = __builtin_amdgcn_mfma_f32_16x16x32_bf16(a, bw2, acc2[tl][mi], 0, 0, 0);
      }
  }
  __syncthreads();
  float* pf = (float*)G;
  if (lr < 4) {
    #pragma unroll
    for (int tl = 0; tl < 2; tl++)
      #pragma unroll
      for (int mi = 0; mi < 4; mi++)
        #pragma unroll
        for (int rg = 0; rg < 4; rg++) {
          int row = mi * 16 + lk * 4 + rg;
          pf[tl * 8192 + (w * 64 + row) * 4 + lr] = acc2[tl][mi][rg];
        }
  }
  __syncthreads();

  {
    int tl = t >> 8, idx = t & 255;
    int r = idx >> 2, c = idx & 3;
    float lv = b3[c];
    #pragma unroll
    for (int wq = 0; wq < 8; wq++) lv += pf[tl * 8192 + (wq * 64 + r) * 4 + c];
    float m = fmaxf(lv, __shfl_xor(lv, 1));
    m = fmaxf(m, __shfl_xor(m, 2));
    float e = expf(lv - m);
    float s = e + __shfl_xor(e, 1);
    s += __shfl_xor(s, 2);
    bp_out[((b * 64 + i0 + tl) * 64 + r) * 4 + c] = e / s;
  }
}

extern "C" void kernel_launch(void* const* d_in, const int* in_sizes, int n_in,
                              void* d_out, int out_size, void* d_ws, size_t ws_size,
                              hipStream_t stream) {
  const float* x    = (const float*)d_in[0];
  const float* adj  = (const float*)d_in[1];
  const float* cnd  = (const float*)d_in[2];
  const float* gc1W = (const float*)d_in[3];
  const float* gc1b = (const float*)d_in[4];
  const float* gc2W = (const float*)d_in[5];
  const float* gc2b = (const float*)d_in[6];
  const float* gmuW = (const float*)d_in[7];
  const float* gmub = (const float*)d_in[8];
  const float* glvW = (const float*)d_in[9];
  const float* glvb = (const float*)d_in[10];
  const float* ceW1 = (const float*)d_in[11];
  const float* ceb1 = (const float*)d_in[12];
  const float* ceW2 = (const float*)d_in[13];
  const float* ceb2 = (const float*)d_in[14];
  const float* dW1  = (const float*)d_in[15];
  const float* db1  = (const float*)d_in[16];
  const float* dW2  = (const float*)d_in[17];
  const float* db2  = (const float*)d_in[18];
  const float* dW3  = (const float*)d_in[19];
  const float* db3  = (const float*)d_in[20];
  // d_in[21..24] (at_*) are dead: mean(softmax) == 1/8 exactly
  const float* bpW1 = (const float*)d_in[25];
  const float* bpb1 = (const float*)d_in[26];
  const float* bpW2 = (const float*)d_in[27];
  const float* bpb2 = (const float*)d_in[28];
  const float* bpW3 = (const float*)d_in[29];
  const float* bpb3 = (const float*)d_in[30];
  const float* reW1 = (const float*)d_in[31];
  const float* reb1 = (const float*)d_in[32];
  const float* reW2 = (const float*)d_in[33];
  const float* reb2 = (const float*)d_in[34];

  float* out = (float*)d_out;
  float* af_out  = out;            // [64,64,64]
  float* bp_out  = out + 262144;   // [64,64,64,4]
  float* val_out = out + 1310720;  // [64,64,4]
  float* mu_out  = out + 1327104;  // [64,64,64]
  float* lv_out  = out + 1589248;  // [64,64,64]

  float* ws   = (float*)d_ws;
  float* ctf  = ws;                 // 16384
  float* ctv  = ws + 16384;         // 16384
  float* buf1 = ws + 49152;         // 1048576  (ah2)
  float* buf2 = buf1 + 1048576;     // 1048576  (P)
  float* buf3 = buf2 + 1048576;     // 1048576  (ah1; later Q)
  u16*   WB   = (u16*)(buf3 + 1048576);  // 253952 u16

  k_pg<<<382, 512, 0, stream>>>(cnd, ceW1, ceb1, ceW2, ceb2, bpW1, bpb1, dW1, db1,
                                dW2, dW3, bpW2, bpW3, reW1, reW2, gmuW, glvW,
                                adj, x, gc1W, gc1b, ctf, ctv, WB, buf3);   // ah1=buf3
  k_linadj<<<dim3(4, 64), 512, 0, stream>>>(adj, buf3, gc2W, gc2b, buf1);  // ah2
  k_chain2<<<256, 512, 0, stream>>>(WB, buf1, ctv, ctf, gmub, glvb, db2, db3,
                                    reb1, reb2, mu_out, lv_out, af_out, val_out,
                                    buf2, buf3);                            // P=buf2 Q=buf3
  k_bond<<<2048, 512, 0, stream>>>(buf2, buf3, WB + OW2T, bpb2, WB + OW3TX, bpb3, bp_out);
}

// Round 20
// 124.964 us; speedup vs baseline: 1.6725x; 1.0001x over previous
//
#include <hip/hip_runtime.h>

typedef short short8 __attribute__((ext_vector_type(8)));
typedef float f32x4 __attribute__((ext_vector_type(4)));
typedef unsigned short u16;
typedef unsigned int u32;

__device__ __forceinline__ u16 f2bf(float f) {
  union { float f; u32 u; } x; x.f = f;
  u32 u = x.u;
  u32 r = (u + 0x7FFFu + ((u >> 16) & 1u)) >> 16;
  return (u16)r;
}

__device__ __forceinline__ u32 cvtpk(float lo, float hi) {
  u32 r;
  asm("v_cvt_pk_bf16_f32 %0, %1, %2" : "=v"(r) : "v"(lo), "v"(hi));
  return r;
}

// ---- WB bf16-region offsets (u16 units) ----
#define OW2T   0        // bond W2^T      [256][256]
#define OW3TX  65536    // bond W3 padT   [16][256]
#define ODW1A  69632    // dW1[0:64]^T    [256][64]
#define ODW2   86016    // dW2^T          [256][256]
#define ODW3   151552   // dW3^T          [64][256]
#define OBPA   167936   // bpW1[0:64]^T   [256][64]  x0.125
#define OBPB   184320   // bpW1[64:128]^T [256][64]  x0.125
#define OREW1  200704   // reW1^T         [256][64]
#define OREW2  217088   // reW2 padT      [16][256]
#define OWMU   221184   // gmuW^T         [64][256]
#define OWLV   237568   // glvW^T         [64][256]
// total 253952 u16

// ====== k_pg (PROVEN r16/r17/r18): merged prep (blocks 0..125) + fused gc1 (126..381) =
__global__ void __launch_bounds__(512) k_pg(
    const float* __restrict__ cnd, const float* __restrict__ ceW1,
    const float* __restrict__ ceb1, const float* __restrict__ ceW2,
    const float* __restrict__ ceb2, const float* __restrict__ bpW1,
    const float* __restrict__ bpb1, const float* __restrict__ dW1,
    const float* __restrict__ db1, const float* __restrict__ dW2,
    const float* __restrict__ dW3, const float* __restrict__ bpW2,
    const float* __restrict__ bpW3, const float* __restrict__ reW1,
    const float* __restrict__ reW2, const float* __restrict__ gmuW,
    const float* __restrict__ glvW, const float* __restrict__ adj,
    const float* __restrict__ x, const float* __restrict__ gc1W,
    const float* __restrict__ gc1b, float* __restrict__ ctf,
    float* __restrict__ ctv, u16* __restrict__ WB, float* __restrict__ ah1_out) {
  __shared__ char SM[65536];
  int bid = blockIdx.x, t = threadIdx.x;
  if (bid < 126) {
    float* h   = (float*)SM;
    float* c2s = h + 256;
    float* prf = h + 512;
    float* prv = h + 768;
    float (*T)[65] = (float(*)[65])(SM + 4096);
    if (bid < 64) {
      int b = bid;
      if (t < 256) {
        float c0 = cnd[b * 2 + 0], c1 = cnd[b * 2 + 1];
        h[t] = fmaxf(c0 * ceW1[t] + c1 * ceW1[256 + t] + ceb1[t], 0.f);
      }
      __syncthreads();
      int col = t & 255, g = t >> 8;
      {
        float acc = 0.f;
        #pragma unroll 8
        for (int k = g * 128; k < g * 128 + 128; k++) acc += h[k] * ceW2[k * 256 + col];
        if (g) prf[col] = acc;
        __syncthreads();
        if (!g) c2s[col] = acc + prf[col] + ceb2[col];
      }
      __syncthreads();
      float af = 0.f, av = 0.f;
      #pragma unroll 4
      for (int k = g * 128; k < g * 128 + 128; k++) {
        float cv = c2s[k];
        af += cv * bpW1[(128 + k) * 256 + col];
        av += cv * dW1[(64 + k) * 256 + col];
      }
      if (g) { prf[col] = af; prv[col] = av; }
      __syncthreads();
      if (!g) {
        ctf[b * 256 + col] = af + prf[col] + bpb1[col];
        ctv[b * 256 + col] = av + prv[col] + db1[col];
      }
      return;
    }
    int mb = bid - 64;  // 0..61
    if (mb >= 60) {
      if (t < 256) {
        const float* s = (mb == 60) ? reW2 : bpW3;
        u16* d = WB + ((mb == 60) ? OREW2 : OW3TX);
        #pragma unroll
        for (int c = 0; c < 16; c++) {
          float v = (c < 4) ? s[t * 4 + c] : 0.f;
          d[c * 256 + t] = f2bf(v);
        }
      }
      return;
    }
    const float* src; u16* dst; int sld, dld, tr, tc; float sc = 1.f;
    if (mb < 4)       { src = dW1;           dst = WB + ODW1A; sld = 256; dld = 64;  tr = 0;            tc = mb;          }
    else if (mb < 20) { int e = mb - 4;  src = dW2;  dst = WB + ODW2; sld = 256; dld = 256; tr = e >> 2; tc = e & 3; }
    else if (mb < 24) { int e = mb - 20; src = dW3;  dst = WB + ODW3; sld = 64;  dld = 256; tr = e;      tc = 0;     }
    else if (mb < 28) { int e = mb - 24; src = bpW1; dst = WB + OBPA; sld = 256; dld = 64;  tr = 0;      tc = e; sc = 0.125f; }
    else if (mb < 32) { int e = mb - 28; src = bpW1 + 64 * 256; dst = WB + OBPB; sld = 256; dld = 64; tr = 0; tc = e; sc = 0.125f; }
    else if (mb < 36) { int e = mb - 32; src = reW1; dst = WB + OREW1; sld = 256; dld = 64; tr = 0;      tc = e;     }
    else if (mb < 40) { int e = mb - 36; src = gmuW; dst = WB + OWMU; sld = 64;  dld = 256; tr = e;      tc = 0;     }
    else if (mb < 44) { int e = mb - 40; src = glvW; dst = WB + OWLV; sld = 64;  dld = 256; tr = e;      tc = 0;     }
    else              { int e = mb - 44; src = bpW2; dst = WB + OW2T; sld = 256; dld = 256; tr = e >> 2; tc = e & 3; }
    int rl = t >> 6, cl = t & 63;
    #pragma unroll
    for (int it = 0; it < 8; it++) {
      int r = it * 8 + rl;
      T[r][cl] = src[(tr * 64 + r) * sld + tc * 64 + cl] * sc;
    }
    __syncthreads();
    #pragma unroll
    for (int it = 0; it < 8; it++) {
      int c2_ = it * 8 + rl;
      dst[(tc * 64 + c2_) * dld + tr * 64 + cl] = f2bf(T[cl][c2_]);
    }
    return;
  }
  // ---------------- gc1 path (PROVEN r11/r16/r17) -------------------------------------
  int e2 = bid - 126;
  int cg = e2 & 3, b = e2 >> 2;
  float* adj_s = (float*)SM;
  float* x_s   = adj_s + 4096;
  float* ax_s  = adj_s + 8192;
  float* h_s   = adj_s + 12288;
  const float* A = adj + b * 4096;
  const float* X = x + b * 4096;
  for (int e = t; e < 4096; e += 512) { adj_s[e] = A[e]; x_s[e] = X[e]; }
  __syncthreads();
  int c = t & 63, rg = t >> 6;
  {
    float acc[8];
    #pragma unroll
    for (int m = 0; m < 8; m++) acc[m] = 0.f;
    #pragma unroll 4
    for (int j4 = 0; j4 < 16; j4++) {
      float xv0 = x_s[(j4 * 4 + 0) * 64 + c];
      float xv1 = x_s[(j4 * 4 + 1) * 64 + c];
      float xv2 = x_s[(j4 * 4 + 2) * 64 + c];
      float xv3 = x_s[(j4 * 4 + 3) * 64 + c];
      #pragma unroll
      for (int m = 0; m < 8; m++) {
        float4 a4 = *(const float4*)&adj_s[(m * 8 + rg) * 64 + j4 * 4];
        acc[m] += a4.x * xv0 + a4.y * xv1 + a4.z * xv2 + a4.w * xv3;
      }
    }
    #pragma unroll
    for (int m = 0; m < 8; m++) ax_s[(m * 8 + rg) * 64 + c] = acc[m];
  }
  __syncthreads();
  {
    float bv = gc1b[cg * 64 + c];
    float acc[8];
    #pragma unroll
    for (int m = 0; m < 8; m++) acc[m] = bv;
    #pragma unroll 4
    for (int k4 = 0; k4 < 16; k4++) {
      float w0 = gc1W[(k4 * 4 + 0) * 256 + cg * 64 + c];
      float w1 = gc1W[(k4 * 4 + 1) * 256 + cg * 64 + c];
      float w2 = gc1W[(k4 * 4 + 2) * 256 + cg * 64 + c];
      float w3 = gc1W[(k4 * 4 + 3) * 256 + cg * 64 + c];
      #pragma unroll
      for (int m = 0; m < 8; m++) {
        float4 a4 = *(const float4*)&ax_s[(m * 8 + rg) * 64 + k4 * 4];
        acc[m] += a4.x * w0 + a4.y * w1 + a4.z * w2 + a4.w * w3;
      }
    }
    #pragma unroll
    for (int m = 0; m < 8; m++) h_s[(m * 8 + rg) * 64 + c] = fmaxf(acc[m], 0.f);
  }
  __syncthreads();
  {
    float acc[8];
    #pragma unroll
    for (int m = 0; m < 8; m++) acc[m] = 0.f;
    #pragma unroll 4
    for (int j4 = 0; j4 < 16; j4++) {
      float h0 = h_s[(j4 * 4 + 0) * 64 + c];
      float h1 = h_s[(j4 * 4 + 1) * 64 + c];
      float h2 = h_s[(j4 * 4 + 2) * 64 + c];
      float h3 = h_s[(j4 * 4 + 3) * 64 + c];
      #pragma unroll
      for (int m = 0; m < 8; m++) {
        float4 a4 = *(const float4*)&adj_s[(m * 8 + rg) * 64 + j4 * 4];
        acc[m] += a4.x * h0 + a4.y * h1 + a4.z * h2 + a4.w * h3;
      }
    }
    float* O = ah1_out + b * 64 * 256 + cg * 64;
    #pragma unroll
    for (int m = 0; m < 8; m++) O[(m * 8 + rg) * 256 + c] = acc[m];
  }
}

// ====== k_linadj v2 (PROVEN r11/r16/r17/r18): fused ah2; float4 LDS reads =============
__global__ void __launch_bounds__(512) k_linadj(
    const float* __restrict__ adj, const float* __restrict__ in,
    const float* __restrict__ W, const float* __restrict__ bias,
    float* __restrict__ out) {
  __shared__ float adj_s[64 * 64];
  __shared__ float in_s[32 * 256];
  __shared__ float h_s[64 * 64];
  int cg = blockIdx.x, b = blockIdx.y, t = threadIdx.x;
  const float* A = adj + b * 4096;
  for (int e = t; e < 4096; e += 512) adj_s[e] = A[e];
  int c = t & 63, rg = t >> 6;
  float bv = bias[cg * 64 + c];
  #pragma unroll
  for (int half = 0; half < 2; half++) {
    if (half) __syncthreads();
    const float* I = in + (b * 64 + half * 32) * 256;
    for (int e = t; e < 32 * 256; e += 512) in_s[e] = I[e];
    __syncthreads();
    float acc[4];
    #pragma unroll
    for (int m = 0; m < 4; m++) acc[m] = bv;
    #pragma unroll 4
    for (int k4 = 0; k4 < 64; k4++) {
      float w0 = W[(k4 * 4 + 0) * 256 + cg * 64 + c];
      float w1 = W[(k4 * 4 + 1) * 256 + cg * 64 + c];
      float w2 = W[(k4 * 4 + 2) * 256 + cg * 64 + c];
      float w3 = W[(k4 * 4 + 3) * 256 + cg * 64 + c];
      #pragma unroll
      for (int m = 0; m < 4; m++) {
        float4 i4 = *(const float4*)&in_s[(m * 8 + rg) * 256 + k4 * 4];
        acc[m] += i4.x * w0 + i4.y * w1 + i4.z * w2 + i4.w * w3;
      }
    }
    #pragma unroll
    for (int m = 0; m < 4; m++)
      h_s[(half * 32 + m * 8 + rg) * 64 + c] = fmaxf(acc[m], 0.f);
  }
  __syncthreads();
  {
    float acc[8];
    #pragma unroll
    for (int m = 0; m < 8; m++) acc[m] = 0.f;
    #pragma unroll 4
    for (int j4 = 0; j4 < 16; j4++) {
      float h0 = h_s[(j4 * 4 + 0) * 64 + c];
      float h1 = h_s[(j4 * 4 + 1) * 64 + c];
      float h2 = h_s[(j4 * 4 + 2) * 64 + c];
      float h3 = h_s[(j4 * 4 + 3) * 64 + c];
      #pragma unroll
      for (int m = 0; m < 8; m++) {
        float4 a4 = *(const float4*)&adj_s[(m * 8 + rg) * 64 + j4 * 4];
        acc[m] += a4.x * h0 + a4.y * h1 + a4.z * h2 + a4.w * h3;
      }
    }
    float* O = out + b * 64 * 256 + cg * 64;
    #pragma unroll
    for (int m = 0; m < 8; m++) O[(m * 8 + rg) * 256 + c] = acc[m];
  }
}

// =============== NT GEMM core (PROVEN r6-r18) =========================================
template <int KK, int WU, int WV, bool UG, bool VG, int ULEN, int VLEN>
__device__ __forceinline__ void mmrun(const u16* __restrict__ Up, int Uoff,
                                      const u16* __restrict__ Vp, int Voff,
                                      const char* lds, int ut0, int vt0, int lr, int lk,
                                      f32x4 (&acc)[WU][WV]) {
  #pragma unroll
  for (int kk = 0; kk < KK; kk++) {
    short8 uf[WU], vf[WV];
    #pragma unroll
    for (int i = 0; i < WU; i++) {
      int row = (ut0 + i) * 16 + lr;
      if constexpr (UG) {
        uf[i] = *(const short8*)(Up + row * ULEN + kk * 32 + lk * 8);
      } else {
        int byt = Uoff + row * (ULEN * 2) + kk * 64 + lk * 16;
        byt ^= (row & 7) << 4;
        uf[i] = *(const short8*)(lds + byt);
      }
    }
    #pragma unroll
    for (int j = 0; j < WV; j++) {
      int row = (vt0 + j) * 16 + lr;
      if constexpr (VG) {
        vf[j] = *(const short8*)(Vp + row * VLEN + kk * 32 + lk * 8);
      } else {
        int byt = Voff + row * (VLEN * 2) + kk * 64 + lk * 16;
        byt ^= (row & 7) << 4;
        vf[j] = *(const short8*)(lds + byt);
      }
    }
    #pragma unroll
    for (int i = 0; i < WU; i++)
      #pragma unroll
      for (int j = 0; j < WV; j++)
        acc[i][j] = __builtin_amdgcn_mfma_f32_16x16x32_bf16(uf[i], vf[j], acc[i][j], 0, 0, 0);
  }
}

__device__ __forceinline__ void st64(char* lds, int off, int rowlen, int crow, int ccol0,
                                     float a0, float a1, float a2, float a3) {
  uint2 pk; pk.x = cvtpk(a0, a1); pk.y = cvtpk(a2, a3);
  int byt = off + crow * (rowlen * 2) + ccol0 * 2;
  byt ^= (crow & 7) << 4;
  *(uint2*)(lds + byt) = pk;
}

template <int WU, int WV>
__device__ __forceinline__ void zacc(f32x4 (&acc)[WU][WV]) {
  #pragma unroll
  for (int i = 0; i < WU; i++)
    #pragma unroll
    for (int j = 0; j < WV; j++) acc[i][j] = (f32x4){0.f, 0.f, 0.f, 0.f};
}

// ====== k_chain2 v3 (PROVEN r18): 256 blocks x 512 thr, 16 rows each ==================
__global__ void __launch_bounds__(512) k_chain2(
    const u16* __restrict__ WB, const float* __restrict__ ah2_g,
    const float* __restrict__ ctv, const float* __restrict__ ctf,
    const float* __restrict__ gmub, const float* __restrict__ glvb,
    const float* __restrict__ db2, const float* __restrict__ db3,
    const float* __restrict__ reb1, const float* __restrict__ reb2,
    float* __restrict__ mu_out, float* __restrict__ lv_out,
    float* __restrict__ af_out, float* __restrict__ val_out,
    float* __restrict__ P, float* __restrict__ Q) {
  __shared__ char L[16384];
  constexpr int S2 = 0, S3 = 8192;
  int rb = blockIdx.x;
  int b = rb >> 2, r0 = (rb & 3) << 4;
  int gr0 = b * 64 + r0;
  int t = threadIdx.x;
  int w = t >> 6, lane = t & 63, lr = lane & 15, lk = lane >> 4;

  // ---- stage ah2 rows [r0, r0+16) -> S2 bf16 [16][256] swizzled ----
  {
    int r = t >> 5, c0 = (t & 31) * 8;
    const float* src = ah2_g + (gr0 + r) * 256 + c0;
    float4 v0 = *(const float4*)(src);
    float4 v1 = *(const float4*)(src + 4);
    st64(L, S2, 256, r, c0, v0.x, v0.y, v0.z, v0.w);
    st64(L, S2, 256, r, c0 + 4, v1.x, v1.y, v1.z, v1.w);
  }
  __syncthreads();
  // ---- mu/lv = ah2 @ Wmu/Wlv + b -> global fp32; mu also -> S3 bf16 [16][64] ----
  {
    f32x4 a[1][1]; zacc(a);
    int sel = w >> 2, ut = w & 3;
    const u16* Up = WB + (sel ? OWLV : OWMU);
    mmrun<8, 1, 1, true, false, 256, 256>(Up + ut * 16 * 256, 0, WB, S2, L, 0, 0, lr, lk, a);
    const float* bb = sel ? glvb : gmub;
    float* gout = sel ? lv_out : mu_out;
    int cc = ut * 16 + lk * 4;
    float4 bv = *(const float4*)(bb + cc);
    float o0 = a[0][0][0] + bv.x, o1 = a[0][0][1] + bv.y;
    float o2 = a[0][0][2] + bv.z, o3 = a[0][0][3] + bv.w;
    *(float4*)(gout + (gr0 + lr) * 64 + cc) = make_float4(o0, o1, o2, o3);
    if (sel == 0) st64(L, S3, 64, lr, cc, o0, o1, o2, o3);
  }
  __syncthreads();
  // ---- f1 = relu(mu@dW1a + ctv) -> S2 [16][256] ----
  {
    f32x4 a[2][1]; zacc(a);
    int ut0 = w * 2;
    mmrun<2, 2, 1, true, false, 64, 64>(WB + ODW1A, 0, WB, S3, L, ut0, 0, lr, lk, a);
    #pragma unroll
    for (int i = 0; i < 2; i++) {
      int cc = (ut0 + i) * 16 + lk * 4;
      float4 cv = *(const float4*)(ctv + b * 256 + cc);
      st64(L, S2, 256, lr, cc, fmaxf(a[i][0][0] + cv.x, 0.f), fmaxf(a[i][0][1] + cv.y, 0.f),
           fmaxf(a[i][0][2] + cv.z, 0.f), fmaxf(a[i][0][3] + cv.w, 0.f));
    }
  }
  __syncthreads();
  // ---- f2 = relu(f1@dW2 + db2) -> S3 [16][256] ----
  {
    f32x4 a[2][1]; zacc(a);
    int ut0 = w * 2;
    mmrun<8, 2, 1, true, false, 256, 256>(WB + ODW2, 0, WB, S2, L, ut0, 0, lr, lk, a);
    #pragma unroll
    for (int i = 0; i < 2; i++) {
      int cc = (ut0 + i) * 16 + lk * 4;
      float4 bv = *(const float4*)(db2 + cc);
      st64(L, S3, 256, lr, cc, fmaxf(a[i][0][0] + bv.x, 0.f), fmaxf(a[i][0][1] + bv.y, 0.f),
           fmaxf(a[i][0][2] + bv.z, 0.f), fmaxf(a[i][0][3] + bv.w, 0.f));
    }
  }
  __syncthreads();
  // ---- feat = sigmoid(f2@dW3 + db3) -> S2 bf16 [16][64]; af_out = feat*0.125 ----
  if (w < 4) {
    f32x4 a[1][1]; zacc(a);
    int ut = w;
    mmrun<8, 1, 1, true, false, 256, 256>(WB + ODW3 + ut * 16 * 256, 0, WB, S3, L, 0, 0, lr, lk, a);
    int cc = ut * 16 + lk * 4;
    float4 bv = *(const float4*)(db3 + cc);
    float s0 = 1.f / (1.f + expf(-(a[0][0][0] + bv.x)));
    float s1 = 1.f / (1.f + expf(-(a[0][0][1] + bv.y)));
    float s2 = 1.f / (1.f + expf(-(a[0][0][2] + bv.z)));
    float s3 = 1.f / (1.f + expf(-(a[0][0][3] + bv.w)));
    *(float4*)(af_out + (gr0 + lr) * 64 + cc) =
        make_float4(s0 * 0.125f, s1 * 0.125f, s2 * 0.125f, s3 * 0.125f);
    st64(L, S2, 64, lr, cc, s0, s1, s2, s3);
  }
  __syncthreads();
  // ---- P = 0.125*feat@bpW1a + ct ; Q = 0.125*feat@bpW1b -> global fp32 ----
  {
    f32x4 a[4][1]; zacc(a);
    int sel = w >> 2, ut0 = (w & 3) * 4;
    const u16* Up = WB + (sel ? OBPB : OBPA);
    mmrun<2, 4, 1, true, false, 64, 64>(Up, 0, WB, S2, L, ut0, 0, lr, lk, a);
    float* out = sel ? Q : P;
    #pragma unroll
    for (int i = 0; i < 4; i++) {
      int cc = (ut0 + i) * 16 + lk * 4;
      float4 cv = make_float4(0.f, 0.f, 0.f, 0.f);
      if (sel == 0) cv = *(const float4*)(ctf + b * 256 + cc);
      *(float4*)(out + (gr0 + lr) * 256 + cc) =
          make_float4(a[i][0][0] + cv.x, a[i][0][1] + cv.y, a[i][0][2] + cv.z, a[i][0][3] + cv.w);
    }
  }
  // ---- rh = relu(feat@reW1 + reb1) -> S3 [16][256] ----
  {
    f32x4 a[2][1]; zacc(a);
    int ut0 = w * 2;
    mmrun<2, 2, 1, true, false, 64, 64>(WB + OREW1, 0, WB, S2, L, ut0, 0, lr, lk, a);
    #pragma unroll
    for (int i = 0; i < 2; i++) {
      int cc = (ut0 + i) * 16 + lk * 4;
      float4 bv = *(const float4*)(reb1 + cc);
      st64(L, S3, 256, lr, cc, fmaxf(a[i][0][0] + bv.x, 0.f), fmaxf(a[i][0][1] + bv.y, 0.f),
           fmaxf(a[i][0][2] + bv.z, 0.f), fmaxf(a[i][0][3] + bv.w, 0.f));
    }
  }
  __syncthreads();
  // ---- val = 4*sigmoid(rh@reW2 + reb2) -> global fp32 ----
  if (w == 0) {
    f32x4 a[1][1]; zacc(a);
    mmrun<8, 1, 1, true, false, 256, 256>(WB + OREW2, 0, WB, S3, L, 0, 0, lr, lk, a);
    if (lk == 0) {
      float4 rb2 = *(const float4*)reb2;
      float v0 = 4.f / (1.f + expf(-(a[0][0][0] + rb2.x)));
      float v1 = 4.f / (1.f + expf(-(a[0][0][1] + rb2.y)));
      float v2 = 4.f / (1.f + expf(-(a[0][0][2] + rb2.z)));
      float v3 = 4.f / (1.f + expf(-(a[0][0][3] + rb2.w)));
      *(float4*)(val_out + (gr0 + lr) * 4) = make_float4(v0, v1, v2, v3);
    }
  }
}

// =============== fused bond MLP v5 (PROVEN r8-r18, 54us) ==============================
__global__ void __launch_bounds__(512, 4) k_bond(
    const float* __restrict__ P, const float* __restrict__ Q,
    const u16* __restrict__ W2T, const float* __restrict__ b2,
    const u16* __restrict__ W3Tx, const float* __restrict__ b3,
    float* __restrict__ bp_out) {
  __shared__ u16 G[2 * 64 * 256];
  int flat = blockIdx.x;
  int xcd = flat & 7, rest = flat >> 3;
  int b = xcd * 8 + (rest >> 5);
  int i0 = (rest & 31) * 2;
  int t = threadIdx.x;
  int lane = t & 63, w = t >> 6;
  int lr = lane & 15, lk = lane >> 4;

  {
    int colg = t & 63, rq = t >> 6;
    const float* Pb = P + (b * 64 + i0) * 256 + colg * 4;
    float4 p0 = *(const float4*)(Pb);
    float4 p1 = *(const float4*)(Pb + 256);
    const float* Qb = Q + b * 64 * 256;
    #pragma unroll
    for (int r = rq * 8; r < rq * 8 + 8; r++) {
      float4 q4 = *(const float4*)(Qb + r * 256 + colg * 4);
      int byt = (r * 512 + colg * 8) ^ ((r & 7) << 4);
      uint2 pk0, pk1;
      pk0.x = cvtpk(fmaxf(p0.x + q4.x, 0.f), fmaxf(p0.y + q4.y, 0.f));
      pk0.y = cvtpk(fmaxf(p0.z + q4.z, 0.f), fmaxf(p0.w + q4.w, 0.f));
      pk1.x = cvtpk(fmaxf(p1.x + q4.x, 0.f), fmaxf(p1.y + q4.y, 0.f));
      pk1.y = cvtpk(fmaxf(p1.z + q4.z, 0.f), fmaxf(p1.w + q4.w, 0.f));
      *(uint2*)((char*)G + byt) = pk0;
      *(uint2*)((char*)G + 32768 + byt) = pk1;
    }
  }
  __syncthreads();

  f32x4 acc[2][2][4];
  #pragma unroll
  for (int tl = 0; tl < 2; tl++)
    #pragma unroll
    for (int ni = 0; ni < 2; ni++)
      #pragma unroll
      for (int mi = 0; mi < 4; mi++) acc[tl][ni][mi] = (f32x4){0.f, 0.f, 0.f, 0.f};

  const u16* Wl = W2T + (w * 32 + lr) * 256 + lk * 8;
  short8 bwc0 = *(const short8*)(Wl);
  short8 bwc1 = *(const short8*)(Wl + 16 * 256);
  for (int kk = 0; kk < 8; kk++) {
    int kn = (kk + 1) & 7;
    short8 bwn0 = *(const short8*)(Wl + kn * 32);
    short8 bwn1 = *(const short8*)(Wl + 16 * 256 + kn * 32);
    __builtin_amdgcn_s_setprio(1);
    #pragma unroll
    for (int mi = 0; mi < 4; mi++) {
      int row = mi * 16 + lr;
      int byt = (row * 512 + kk * 64 + lk * 16) ^ ((row & 7) << 4);
      short8 a0 = *(const short8*)((const char*)G + byt);
      short8 a1 = *(const short8*)((const char*)G + 32768 + byt);
      acc[0][0][mi] = __builtin_amdgcn_mfma_f32_16x16x32_bf16(bwc0, a0, acc[0][0][mi], 0, 0, 0);
      acc[1][0][mi] = __builtin_amdgcn_mfma_f32_16x16x32_bf16(bwc0, a1, acc[1][0][mi], 0, 0, 0);
      acc[0][1][mi] = __builtin_amdgcn_mfma_f32_16x16x32_bf16(bwc1, a0, acc[0][1][mi], 0, 0, 0);
      acc[1][1][mi] = __builtin_amdgcn_mfma_f32_16x16x32_bf16(bwc1, a1, acc[1][1][mi], 0, 0, 0);
    }
    __builtin_amdgcn_s_setprio(0);
    bwc0 = bwn0;
    bwc1 = bwn1;
  }
  __syncthreads();

  #pragma unroll
  for (int tl = 0; tl < 2; tl++)
    #pragma unroll
    for (int ni = 0; ni < 2; ni++) {
      int col0 = w * 32 + ni * 16 + lk * 4;
      float4 bb = *(const float4*)(b2 + col0);
      #pragma unroll
      for (int mi = 0; mi < 4; mi++) {
        int grow = mi * 16 + lr;
        uint2 pk;
        pk.x = cvtpk(fmaxf(acc[tl][ni][mi][0] + bb.x, 0.f), fmaxf(acc[tl][ni][mi][1] + bb.y, 0.f));
        pk.y = cvtpk(fmaxf(acc[tl][ni][mi][2] + bb.z, 0.f), fmaxf(acc[tl][ni][mi][3] + bb.w, 0.f));
        int byt = ((grow * 512 + col0 * 2) ^ ((grow & 7) << 4)) + tl * 32768;
        *(uint2*)((char*)G + byt) = pk;
      }
    }
  __syncthreads();

  f32x4 acc2[2][4];
  #pragma unroll
  for (int tl = 0; tl < 2; tl++)
    #pragma unroll
    for (int mi = 0; mi < 4; mi++) acc2[tl][mi] = (f32x4){0.f, 0.f, 0.f, 0.f};
  {
    short8 bw2 = *(const short8*)(W3Tx + lr * 256 + w * 32 + lk * 8);
    #pragma unroll
    for (int tl = 0; tl < 2; tl++)
      #pragma unroll
      for (int mi = 0; mi < 4; mi++) {
        int row = mi * 16 + lr;
        int byt = ((row * 512 + (w * 32 + lk * 8) * 2) ^ ((row & 7) << 4)) + tl * 32768;
        short8 a = *(const short8*)((const char*)G + byt);
        acc2[tl][mi] = __builtin_amdgcn_mfma_f32_16x16x32_bf16(a, bw2, acc2[tl][mi], 0, 0, 0);
      }
  }
  __syncthreads();
  float* pf = (float*)G;
  if (lr < 4) {
    #pragma unroll
    for (int tl = 0; tl < 2; tl++)
      #pragma unroll
      for (int mi = 0; mi < 4; mi++)
        #pragma unroll
        for (int rg = 0; rg < 4; rg++) {
          int row = mi * 16 + lk * 4 + rg;
          pf[tl * 8192 + (w * 64 + row) * 4 + lr] = acc2[tl][mi][rg];
        }
  }
  __syncthreads();

  {
    int tl = t >> 8, idx = t & 255;
    int r = idx >> 2, c = idx & 3;
    float lv = b3[c];
    #pragma unroll
    for (int wq = 0; wq < 8; wq++) lv += pf[tl * 8192 + (wq * 64 + r) * 4 + c];
    float m = fmaxf(lv, __shfl_xor(lv, 1));
    m = fmaxf(m, __shfl_xor(m, 2));
    float e = expf(lv - m);
    float s = e + __shfl_xor(e, 1);
    s += __shfl_xor(s, 2);
    bp_out[((b * 64 + i0 + tl) * 64 + r) * 4 + c] = e / s;
  }
}

extern "C" void kernel_launch(void* const* d_in, const int* in_sizes, int n_in,
                              void* d_out, int out_size, void* d_ws, size_t ws_size,
                              hipStream_t stream) {
  const float* x    = (const float*)d_in[0];
  const float* adj  = (const float*)d_in[1];
  const float* cnd  = (const float*)d_in[2];
  const float* gc1W = (const float*)d_in[3];
  const float* gc1b = (const float*)d_in[4];
  const float* gc2W = (const float*)d_in[5];
  const float* gc2b = (const float*)d_in[6];
  const float* gmuW = (const float*)d_in[7];
  const float* gmub = (const float*)d_in[8];
  const float* glvW = (const float*)d_in[9];
  const float* glvb = (const float*)d_in[10];
  const float* ceW1 = (const float*)d_in[11];
  const float* ceb1 = (const float*)d_in[12];
  const float* ceW2 = (const float*)d_in[13];
  const float* ceb2 = (const float*)d_in[14];
  const float* dW1  = (const float*)d_in[15];
  const float* db1  = (const float*)d_in[16];
  const float* dW2  = (const float*)d_in[17];
  const float* db2  = (const float*)d_in[18];
  const float* dW3  = (const float*)d_in[19];
  const float* db3  = (const float*)d_in[20];
  // d_in[21..24] (at_*) are dead: mean(softmax) == 1/8 exactly
  const float* bpW1 = (const float*)d_in[25];
  const float* bpb1 = (const float*)d_in[26];
  const float* bpW2 = (const float*)d_in[27];
  const float* bpb2 = (const float*)d_in[28];
  const float* bpW3 = (const float*)d_in[29];
  const float* bpb3 = (const float*)d_in[30];
  const float* reW1 = (const float*)d_in[31];
  const float* reb1 = (const float*)d_in[32];
  const float* reW2 = (const float*)d_in[33];
  const float* reb2 = (const float*)d_in[34];

  float* out = (float*)d_out;
  float* af_out  = out;            // [64,64,64]
  float* bp_out  = out + 262144;   // [64,64,64,4]
  float* val_out = out + 1310720;  // [64,64,4]
  float* mu_out  = out + 1327104;  // [64,64,64]
  float* lv_out  = out + 1589248;  // [64,64,64]

  float* ws   = (float*)d_ws;
  float* ctf  = ws;                 // 16384
  float* ctv  = ws + 16384;         // 16384
  float* buf1 = ws + 49152;         // 1048576  (ah2)
  float* buf2 = buf1 + 1048576;     // 1048576  (P)
  float* buf3 = buf2 + 1048576;     // 1048576  (ah1; later Q)
  u16*   WB   = (u16*)(buf3 + 1048576);  // 253952 u16

  k_pg<<<382, 512, 0, stream>>>(cnd, ceW1, ceb1, ceW2, ceb2, bpW1, bpb1, dW1, db1,
                                dW2, dW3, bpW2, bpW3, reW1, reW2, gmuW, glvW,
                                adj, x, gc1W, gc1b, ctf, ctv, WB, buf3);   // ah1=buf3
  k_linadj<<<dim3(4, 64), 512, 0, stream>>>(adj, buf3, gc2W, gc2b, buf1);  // ah2
  k_chain2<<<256, 512, 0, stream>>>(WB, buf1, ctv, ctf, gmub, glvb, db2, db3,
                                    reb1, reb2, mu_out, lv_out, af_out, val_out,
                                    buf2, buf3);                            // P=buf2 Q=buf3
  k_bond<<<2048, 512, 0, stream>>>(buf2, buf3, WB + OW2T, bpb2, WB + OW3TX, bpb3, bp_out);
}